// Round 2
// baseline (191.266 us; speedup 1.0000x reference)
//
#include <hip/hip_runtime.h>

typedef __attribute__((ext_vector_type(8))) short bf16x8;
typedef __attribute__((ext_vector_type(4))) float f32x4;

#define D_MODEL 1024
#define SEQ 1024
#define NB 4
#define NH 16
#define DH 64
#define BHCOUNT 64
#define MROWS 4096

__device__ __forceinline__ unsigned short f2bf(float f) {
    union { float f; unsigned u; } x; x.f = f;
    unsigned r = x.u + 0x7fffu + ((x.u >> 16) & 1u);
    return (unsigned short)(r >> 16);
}

__device__ __forceinline__ void gload16(const void* g, void* l) {
    __builtin_amdgcn_global_load_lds((const __attribute__((address_space(1))) void*)g,
                                     (__attribute__((address_space(3))) void*)l, 16, 0, 0);
}

// ---------------- convert inp f32 -> bf16 ----------------
__global__ __launch_bounds__(256) void cvt_x(const float* __restrict__ x,
                                             unsigned short* __restrict__ o) {
    int i = blockIdx.x * 256 + threadIdx.x;   // each handles 4 floats
    float4 v = ((const float4*)x)[i];
    ushort4 r;
    r.x = f2bf(v.x); r.y = f2bf(v.y); r.z = f2bf(v.z); r.w = f2bf(v.w);
    ((ushort4*)o)[i] = r;
}

// ---------------- transpose W (f32) -> bf16 W^T ----------------
__global__ __launch_bounds__(256) void transpose_w(const float* __restrict__ Wq,
                                                   const float* __restrict__ Wk,
                                                   const float* __restrict__ Wv,
                                                   const float* __restrict__ Wo,
                                                   unsigned short* __restrict__ Wqkv_t,
                                                   unsigned short* __restrict__ Wo_t) {
    __shared__ float tile[32][33];
    const int mtx = blockIdx.z;
    const float* src = mtx == 0 ? Wq : mtx == 1 ? Wk : mtx == 2 ? Wv : Wo;
    unsigned short* dst = mtx < 3 ? (Wqkv_t + (size_t)mtx * D_MODEL * D_MODEL) : Wo_t;
    const int n0 = blockIdx.x * 32, k0 = blockIdx.y * 32;
    const int tx = threadIdx.x, ty = threadIdx.y;
    #pragma unroll
    for (int i = 0; i < 32; i += 8)
        tile[ty + i][tx] = src[(size_t)(k0 + ty + i) * D_MODEL + n0 + tx];
    __syncthreads();
    #pragma unroll
    for (int i = 0; i < 32; i += 8)
        dst[(size_t)(n0 + ty + i) * D_MODEL + k0 + tx] = f2bf(tile[tx][ty + i]);
}

// ---------------- QKV GEMM: Xb[4096][1024] @ Wqkv_t^T -> Q,K [bh][s][64], V^T [bh][64][s] ----------------
__global__ __launch_bounds__(256) void gemm_qkv(const unsigned short* __restrict__ Xb,
                                                const unsigned short* __restrict__ Wt,
                                                const float* __restrict__ bq,
                                                const float* __restrict__ bk,
                                                const float* __restrict__ bv,
                                                unsigned short* __restrict__ Qb,
                                                unsigned short* __restrict__ Kb,
                                                unsigned short* __restrict__ Vt) {
    __shared__ unsigned short As[128 * 32];
    __shared__ unsigned short Bs[128 * 32];
    const int tid = threadIdx.x;
    const int lane = tid & 63, wid = tid >> 6;
    const int fr = lane & 15, fg = lane >> 4;
    const int wr = wid >> 1, wc = wid & 1;
    const int m0 = blockIdx.x * 128, n0 = blockIdx.y * 128;
    const unsigned short* Ag = Xb + (size_t)m0 * D_MODEL;
    const unsigned short* Bg = Wt + (size_t)n0 * D_MODEL;
    f32x4 acc[4][4] = {};
    for (int kt = 0; kt < D_MODEL; kt += 32) {
        __syncthreads();
        #pragma unroll
        for (int r = 0; r < 2; ++r) {
            int chunk = r * 256 + tid;
            int row = chunk >> 2, col = (chunk & 3) * 8;
            gload16(Ag + (size_t)row * D_MODEL + kt + col, &As[row * 32 + col]);
            gload16(Bg + (size_t)row * D_MODEL + kt + col, &Bs[row * 32 + col]);
        }
        __syncthreads();
        bf16x8 af[4], bfv[4];
        #pragma unroll
        for (int m = 0; m < 4; ++m) af[m] = *(const bf16x8*)&As[(wr * 64 + m * 16 + fr) * 32 + fg * 8];
        #pragma unroll
        for (int n = 0; n < 4; ++n) bfv[n] = *(const bf16x8*)&Bs[(wc * 64 + n * 16 + fr) * 32 + fg * 8];
        #pragma unroll
        for (int m = 0; m < 4; ++m)
            #pragma unroll
            for (int n = 0; n < 4; ++n)
                acc[m][n] = __builtin_amdgcn_mfma_f32_16x16x32_bf16(af[m], bfv[n], acc[m][n], 0, 0, 0);
    }
    #pragma unroll
    for (int n = 0; n < 4; ++n) {
        int gn = n0 + wc * 64 + n * 16 + fr;
        int sel = gn >> 10, np = gn & 1023;
        const float* bp = sel == 0 ? bq : sel == 1 ? bk : bv;
        float bias = bp[np];
        int h = np >> 6, d = np & 63;
        #pragma unroll
        for (int m = 0; m < 4; ++m) {
            int gm0 = m0 + wr * 64 + m * 16 + fg * 4;
            int b = gm0 >> 10, s0 = gm0 & 1023;
            int bh = b * NH + h;
            if (sel < 2) {
                unsigned short* dst = sel == 0 ? Qb : Kb;
                #pragma unroll
                for (int r = 0; r < 4; ++r)
                    dst[((size_t)bh * SEQ + s0 + r) * DH + d] = f2bf(acc[m][n][r] + bias);
            } else {
                ushort4 pk;
                pk.x = f2bf(acc[m][n][0] + bias);
                pk.y = f2bf(acc[m][n][1] + bias);
                pk.z = f2bf(acc[m][n][2] + bias);
                pk.w = f2bf(acc[m][n][3] + bias);
                *(ushort4*)&Vt[((size_t)bh * DH + d) * SEQ + s0] = pk;
            }
        }
    }
}

// ---------------- O-proj GEMM: AF bf16 [4096][1024] @ Wo_t^T -> tmp f32 ----------------
__global__ __launch_bounds__(256) void gemm_o(const unsigned short* __restrict__ Ab,
                                              const unsigned short* __restrict__ Wt,
                                              float* __restrict__ tmp) {
    __shared__ unsigned short As[128 * 32];
    __shared__ unsigned short Bs[128 * 32];
    const int tid = threadIdx.x;
    const int lane = tid & 63, wid = tid >> 6;
    const int fr = lane & 15, fg = lane >> 4;
    const int wr = wid >> 1, wc = wid & 1;
    const int m0 = blockIdx.x * 128, n0 = blockIdx.y * 128;
    const unsigned short* Ag = Ab + (size_t)m0 * D_MODEL;
    const unsigned short* Bg = Wt + (size_t)n0 * D_MODEL;
    f32x4 acc[4][4] = {};
    for (int kt = 0; kt < D_MODEL; kt += 32) {
        __syncthreads();
        #pragma unroll
        for (int r = 0; r < 2; ++r) {
            int chunk = r * 256 + tid;
            int row = chunk >> 2, col = (chunk & 3) * 8;
            gload16(Ag + (size_t)row * D_MODEL + kt + col, &As[row * 32 + col]);
            gload16(Bg + (size_t)row * D_MODEL + kt + col, &Bs[row * 32 + col]);
        }
        __syncthreads();
        bf16x8 af[4], bfv[4];
        #pragma unroll
        for (int m = 0; m < 4; ++m) af[m] = *(const bf16x8*)&As[(wr * 64 + m * 16 + fr) * 32 + fg * 8];
        #pragma unroll
        for (int n = 0; n < 4; ++n) bfv[n] = *(const bf16x8*)&Bs[(wc * 64 + n * 16 + fr) * 32 + fg * 8];
        #pragma unroll
        for (int m = 0; m < 4; ++m)
            #pragma unroll
            for (int n = 0; n < 4; ++n)
                acc[m][n] = __builtin_amdgcn_mfma_f32_16x16x32_bf16(af[m], bfv[n], acc[m][n], 0, 0, 0);
    }
    #pragma unroll
    for (int n = 0; n < 4; ++n) {
        int gn = n0 + wc * 64 + n * 16 + fr;
        #pragma unroll
        for (int m = 0; m < 4; ++m) {
            #pragma unroll
            for (int r = 0; r < 4; ++r) {
                int gm = m0 + wr * 64 + m * 16 + fg * 4 + r;
                tmp[(size_t)gm * D_MODEL + gn] = acc[m][n][r];
            }
        }
    }
}

// ---------------- flash attention (K/V direct from L2, no barriers) ----------------
__global__ __launch_bounds__(256) void attn_kernel(const unsigned short* __restrict__ Qb,
                                                   const unsigned short* __restrict__ Kb,
                                                   const unsigned short* __restrict__ Vt,
                                                   const int* __restrict__ amask,
                                                   unsigned short* __restrict__ AF) {
    __shared__ unsigned short Ps[4][32 * 72];   // per-wave private P staging
    const int tid = threadIdx.x, lane = tid & 63, wid = tid >> 6;
    const int fr = lane & 15, fg = lane >> 4;
    const int bh = blockIdx.y, qt = blockIdx.x;
    const int b = bh >> 4;
    const unsigned short* Qh = Qb + (size_t)bh * SEQ * DH;
    const unsigned short* Kh = Kb + (size_t)bh * SEQ * DH;
    const unsigned short* Vth = Vt + (size_t)bh * DH * SEQ;
    const int* mrow = amask + b * SEQ;
    const int q0 = qt * 128 + wid * 32;
    bf16x8 qf[2][2];
    #pragma unroll
    for (int m = 0; m < 2; ++m)
        #pragma unroll
        for (int c = 0; c < 2; ++c)
            qf[m][c] = *(const bf16x8*)(Qh + (size_t)(q0 + m * 16 + fr) * DH + c * 32 + fg * 8);
    f32x4 oacc[2][4] = {};
    float mrun[2][4], lrun[2][4];
    #pragma unroll
    for (int m = 0; m < 2; ++m)
        #pragma unroll
        for (int r = 0; r < 4; ++r) { mrun[m][r] = -3.0e38f; lrun[m][r] = 0.f; }

    for (int kt = 0; kt < 16; ++kt) {
        const int kv0 = kt * 64;
        // mask bias (additive; exact after row-max subtraction since no row is fully masked)
        float mbias[4];
        #pragma unroll
        for (int n = 0; n < 4; ++n)
            mbias[n] = (mrow[kv0 + n * 16 + fr] != 0) ? -100000.f : 0.f;
        // QK^T : K fragments straight from global (L2-resident)
        f32x4 s[2][4] = {};
        #pragma unroll
        for (int c = 0; c < 2; ++c) {
            bf16x8 kf[4];
            #pragma unroll
            for (int n = 0; n < 4; ++n)
                kf[n] = *(const bf16x8*)(Kh + (size_t)(kv0 + n * 16 + fr) * DH + c * 32 + fg * 8);
            #pragma unroll
            for (int m = 0; m < 2; ++m)
                #pragma unroll
                for (int n = 0; n < 4; ++n)
                    s[m][n] = __builtin_amdgcn_mfma_f32_16x16x32_bf16(qf[m][c], kf[n], s[m][n], 0, 0, 0);
        }
        // scale + mask (one FMA)
        #pragma unroll
        for (int m = 0; m < 2; ++m)
            #pragma unroll
            for (int n = 0; n < 4; ++n)
                #pragma unroll
                for (int r = 0; r < 4; ++r)
                    s[m][n][r] = fmaf(s[m][n][r], 0.125f, mbias[n]);
        // online softmax
        #pragma unroll
        for (int m = 0; m < 2; ++m) {
            #pragma unroll
            for (int r = 0; r < 4; ++r) {
                float pm = fmaxf(fmaxf(s[m][0][r], s[m][1][r]), fmaxf(s[m][2][r], s[m][3][r]));
                pm = fmaxf(pm, __shfl_xor(pm, 1));
                pm = fmaxf(pm, __shfl_xor(pm, 2));
                pm = fmaxf(pm, __shfl_xor(pm, 4));
                pm = fmaxf(pm, __shfl_xor(pm, 8));
                float newm = fmaxf(mrun[m][r], pm);
                float corr = __expf(mrun[m][r] - newm);
                mrun[m][r] = newm;
                float ps = 0.f;
                #pragma unroll
                for (int n = 0; n < 4; ++n) {
                    float p = __expf(s[m][n][r] - newm);
                    s[m][n][r] = p;
                    ps += p;
                }
                ps += __shfl_xor(ps, 1);
                ps += __shfl_xor(ps, 2);
                ps += __shfl_xor(ps, 4);
                ps += __shfl_xor(ps, 8);
                lrun[m][r] = lrun[m][r] * corr + ps;
                #pragma unroll
                for (int dn = 0; dn < 4; ++dn) oacc[m][dn][r] *= corr;
            }
        }
        // P -> per-wave LDS (C/D layout -> A layout), no cross-wave hazard
        #pragma unroll
        for (int m = 0; m < 2; ++m)
            #pragma unroll
            for (int n = 0; n < 4; ++n)
                #pragma unroll
                for (int r = 0; r < 4; ++r)
                    Ps[wid][(m * 16 + fg * 4 + r) * 72 + n * 16 + fr] = f2bf(s[m][n][r]);
        // PV : V^T fragments straight from global (L2-resident)
        #pragma unroll
        for (int c = 0; c < 2; ++c) {
            bf16x8 pf[2], vf[4];
            #pragma unroll
            for (int m = 0; m < 2; ++m)
                pf[m] = *(const bf16x8*)&Ps[wid][(m * 16 + fr) * 72 + c * 32 + fg * 8];
            #pragma unroll
            for (int dn = 0; dn < 4; ++dn)
                vf[dn] = *(const bf16x8*)(Vth + (size_t)(dn * 16 + fr) * SEQ + kv0 + c * 32 + fg * 8);
            #pragma unroll
            for (int m = 0; m < 2; ++m)
                #pragma unroll
                for (int dn = 0; dn < 4; ++dn)
                    oacc[m][dn] = __builtin_amdgcn_mfma_f32_16x16x32_bf16(pf[m], vf[dn], oacc[m][dn], 0, 0, 0);
        }
    }
    // epilogue with faithful-to-torch head scramble: i=b*16+h lands at b2=i&3, h2=i>>2
    const int b2 = bh & 3, h2 = bh >> 2;
    #pragma unroll
    for (int m = 0; m < 2; ++m)
        #pragma unroll
        for (int dn = 0; dn < 4; ++dn)
            #pragma unroll
            for (int r = 0; r < 4; ++r) {
                int q = q0 + m * 16 + fg * 4 + r;
                int d = dn * 16 + fr;
                float o = oacc[m][dn][r] / lrun[m][r];
                AF[((size_t)b2 * SEQ + q) * D_MODEL + h2 * DH + d] = f2bf(o);
            }
}

// ---------------- residual + LayerNorm ----------------
__global__ __launch_bounds__(256) void ln_kernel(const float* __restrict__ tmp,
                                                 const float* __restrict__ inp,
                                                 const float* __restrict__ g,
                                                 const float* __restrict__ bb,
                                                 float* __restrict__ out) {
    __shared__ float red[8];
    const int row = blockIdx.x, tid = threadIdx.x;
    float4 t = ((const float4*)(tmp + (size_t)row * D_MODEL))[tid];
    float4 rr = ((const float4*)(inp + (size_t)row * D_MODEL))[tid];
    float4 y;
    y.x = t.x + rr.x; y.y = t.y + rr.y; y.z = t.z + rr.z; y.w = t.w + rr.w;
    float sum = y.x + y.y + y.z + y.w;
    float sq = y.x * y.x + y.y * y.y + y.z * y.z + y.w * y.w;
    #pragma unroll
    for (int o = 1; o < 64; o <<= 1) { sum += __shfl_xor(sum, o); sq += __shfl_xor(sq, o); }
    int wid = tid >> 6, lane = tid & 63;
    if (lane == 0) { red[wid] = sum; red[4 + wid] = sq; }
    __syncthreads();
    sum = red[0] + red[1] + red[2] + red[3];
    sq = red[4] + red[5] + red[6] + red[7];
    float mu = sum * (1.f / D_MODEL);
    float var = sq * (1.f / D_MODEL) - mu * mu;
    float rs = rsqrtf(var + 1e-5f);
    float4 gg = ((const float4*)g)[tid];
    float4 bv = ((const float4*)bb)[tid];
    float4 o4;
    o4.x = (y.x - mu) * rs * gg.x + bv.x;
    o4.y = (y.y - mu) * rs * gg.y + bv.y;
    o4.z = (y.z - mu) * rs * gg.z + bv.z;
    o4.w = (y.w - mu) * rs * gg.w + bv.w;
    ((float4*)(out + (size_t)row * D_MODEL))[tid] = o4;
}

extern "C" void kernel_launch(void* const* d_in, const int* in_sizes, int n_in,
                              void* d_out, int out_size, void* d_ws, size_t ws_size,
                              hipStream_t stream) {
    const float* inp = (const float*)d_in[0];
    const int* amask = (const int*)d_in[1];
    const float* Wq = (const float*)d_in[2];
    const float* bq = (const float*)d_in[3];
    const float* Wk = (const float*)d_in[4];
    const float* bk = (const float*)d_in[5];
    const float* Wv = (const float*)d_in[6];
    const float* bv = (const float*)d_in[7];
    const float* Wo = (const float*)d_in[8];
    const float* lg = (const float*)d_in[9];
    const float* lb = (const float*)d_in[10];
    float* out = (float*)d_out;
    char* ws = (char*)d_ws;

    unsigned short* Xb     = (unsigned short*)(ws + 0);          //  8.0 MiB
    unsigned short* Wqkv_t = (unsigned short*)(ws + 8388608);    //  6.0 MiB
    unsigned short* Wo_t   = (unsigned short*)(ws + 14680064);   //  2.0 MiB
    unsigned short* Qb     = (unsigned short*)(ws + 16777216);   //  8.0 MiB
    unsigned short* Kb     = (unsigned short*)(ws + 25165824);   //  8.0 MiB
    unsigned short* Vt     = (unsigned short*)(ws + 33554432);   //  8.0 MiB  (V^T: [bh][d][s])
    unsigned short* AF     = (unsigned short*)(ws + 41943040);   //  8.0 MiB
    float*          tmp    = (float*)(ws + 50331648);            // 16.0 MiB  (total 64 MiB)

    cvt_x<<<4096, 256, 0, stream>>>(inp, Xb);
    transpose_w<<<dim3(32, 32, 4), dim3(32, 8), 0, stream>>>(Wq, Wk, Wv, Wo, Wqkv_t, Wo_t);
    gemm_qkv<<<dim3(32, 24), 256, 0, stream>>>(Xb, Wqkv_t, bq, bk, bv, Qb, Kb, Vt);
    attn_kernel<<<dim3(8, 64), 256, 0, stream>>>(Qb, Kb, Vt, amask, AF);
    gemm_o<<<dim3(32, 8), 256, 0, stream>>>(AF, Wo_t, tmp);
    ln_kernel<<<4096, 256, 0, stream>>>(tmp, inp, lg, lb, out);
}

// Round 3
// 169.113 us; speedup vs baseline: 1.1310x; 1.1310x over previous
//
#include <hip/hip_runtime.h>

typedef __attribute__((ext_vector_type(8))) short bf16x8;
typedef __attribute__((ext_vector_type(4))) float f32x4;

#define D_MODEL 1024
#define SEQ 1024
#define NB 4
#define NH 16
#define DH 64
#define BHCOUNT 64
#define MROWS 4096

__device__ __forceinline__ unsigned short f2bf(float f) {
    union { float f; unsigned u; } x; x.f = f;
    unsigned r = x.u + 0x7fffu + ((x.u >> 16) & 1u);
    return (unsigned short)(r >> 16);
}

__device__ __forceinline__ void gload16(const void* g, void* l) {
    __builtin_amdgcn_global_load_lds((const __attribute__((address_space(1))) void*)g,
                                     (__attribute__((address_space(3))) void*)l, 16, 0, 0);
}

// ---------------- convert inp f32 -> bf16 ----------------
__global__ __launch_bounds__(256) void cvt_x(const float* __restrict__ x,
                                             unsigned short* __restrict__ o) {
    int i = blockIdx.x * 256 + threadIdx.x;   // each handles 4 floats
    float4 v = ((const float4*)x)[i];
    ushort4 r;
    r.x = f2bf(v.x); r.y = f2bf(v.y); r.z = f2bf(v.z); r.w = f2bf(v.w);
    ((ushort4*)o)[i] = r;
}

// ---------------- transpose W (f32) -> bf16 W^T ----------------
__global__ __launch_bounds__(256) void transpose_w(const float* __restrict__ Wq,
                                                   const float* __restrict__ Wk,
                                                   const float* __restrict__ Wv,
                                                   const float* __restrict__ Wo,
                                                   unsigned short* __restrict__ Wqkv_t,
                                                   unsigned short* __restrict__ Wo_t) {
    __shared__ float tile[32][33];
    const int mtx = blockIdx.z;
    const float* src = mtx == 0 ? Wq : mtx == 1 ? Wk : mtx == 2 ? Wv : Wo;
    unsigned short* dst = mtx < 3 ? (Wqkv_t + (size_t)mtx * D_MODEL * D_MODEL) : Wo_t;
    const int n0 = blockIdx.x * 32, k0 = blockIdx.y * 32;
    const int tx = threadIdx.x, ty = threadIdx.y;
    #pragma unroll
    for (int i = 0; i < 32; i += 8)
        tile[ty + i][tx] = src[(size_t)(k0 + ty + i) * D_MODEL + n0 + tx];
    __syncthreads();
    #pragma unroll
    for (int i = 0; i < 32; i += 8)
        dst[(size_t)(n0 + ty + i) * D_MODEL + k0 + tx] = f2bf(tile[tx][ty + i]);
}

// ---------------- QKV GEMM: Xb[4096][1024] @ Wqkv_t^T -> Q,K [bh][s][64], V^T [bh][64][s] ----------------
__global__ __launch_bounds__(256) void gemm_qkv(const unsigned short* __restrict__ Xb,
                                                const unsigned short* __restrict__ Wt,
                                                const float* __restrict__ bq,
                                                const float* __restrict__ bk,
                                                const float* __restrict__ bv,
                                                unsigned short* __restrict__ Qb,
                                                unsigned short* __restrict__ Kb,
                                                unsigned short* __restrict__ Vt) {
    __shared__ unsigned short As[128 * 32];
    __shared__ unsigned short Bs[128 * 32];
    const int tid = threadIdx.x;
    const int lane = tid & 63, wid = tid >> 6;
    const int fr = lane & 15, fg = lane >> 4;
    const int wr = wid >> 1, wc = wid & 1;
    const int m0 = blockIdx.x * 128, n0 = blockIdx.y * 128;
    const unsigned short* Ag = Xb + (size_t)m0 * D_MODEL;
    const unsigned short* Bg = Wt + (size_t)n0 * D_MODEL;
    f32x4 acc[4][4] = {};
    for (int kt = 0; kt < D_MODEL; kt += 32) {
        __syncthreads();
        #pragma unroll
        for (int r = 0; r < 2; ++r) {
            int chunk = r * 256 + tid;
            int row = chunk >> 2, col = (chunk & 3) * 8;
            gload16(Ag + (size_t)row * D_MODEL + kt + col, &As[row * 32 + col]);
            gload16(Bg + (size_t)row * D_MODEL + kt + col, &Bs[row * 32 + col]);
        }
        __syncthreads();
        bf16x8 af[4], bfv[4];
        #pragma unroll
        for (int m = 0; m < 4; ++m) af[m] = *(const bf16x8*)&As[(wr * 64 + m * 16 + fr) * 32 + fg * 8];
        #pragma unroll
        for (int n = 0; n < 4; ++n) bfv[n] = *(const bf16x8*)&Bs[(wc * 64 + n * 16 + fr) * 32 + fg * 8];
        #pragma unroll
        for (int m = 0; m < 4; ++m)
            #pragma unroll
            for (int n = 0; n < 4; ++n)
                acc[m][n] = __builtin_amdgcn_mfma_f32_16x16x32_bf16(af[m], bfv[n], acc[m][n], 0, 0, 0);
    }
    #pragma unroll
    for (int n = 0; n < 4; ++n) {
        int gn = n0 + wc * 64 + n * 16 + fr;
        int sel = gn >> 10, np = gn & 1023;
        const float* bp = sel == 0 ? bq : sel == 1 ? bk : bv;
        float bias = bp[np];
        int h = np >> 6, d = np & 63;
        #pragma unroll
        for (int m = 0; m < 4; ++m) {
            int gm0 = m0 + wr * 64 + m * 16 + fg * 4;
            int b = gm0 >> 10, s0 = gm0 & 1023;
            int bh = b * NH + h;
            if (sel < 2) {
                unsigned short* dst = sel == 0 ? Qb : Kb;
                #pragma unroll
                for (int r = 0; r < 4; ++r)
                    dst[((size_t)bh * SEQ + s0 + r) * DH + d] = f2bf(acc[m][n][r] + bias);
            } else {
                ushort4 pk;
                pk.x = f2bf(acc[m][n][0] + bias);
                pk.y = f2bf(acc[m][n][1] + bias);
                pk.z = f2bf(acc[m][n][2] + bias);
                pk.w = f2bf(acc[m][n][3] + bias);
                *(ushort4*)&Vt[((size_t)bh * DH + d) * SEQ + s0] = pk;
            }
        }
    }
}

// ---------------- O-proj GEMM: AF bf16 [4096][1024] @ Wo_t^T -> tmp f32 ----------------
__global__ __launch_bounds__(256) void gemm_o(const unsigned short* __restrict__ Ab,
                                              const unsigned short* __restrict__ Wt,
                                              float* __restrict__ tmp) {
    __shared__ unsigned short As[128 * 32];
    __shared__ unsigned short Bs[128 * 32];
    const int tid = threadIdx.x;
    const int lane = tid & 63, wid = tid >> 6;
    const int fr = lane & 15, fg = lane >> 4;
    const int wr = wid >> 1, wc = wid & 1;
    const int m0 = blockIdx.x * 128, n0 = blockIdx.y * 128;
    const unsigned short* Ag = Ab + (size_t)m0 * D_MODEL;
    const unsigned short* Bg = Wt + (size_t)n0 * D_MODEL;
    f32x4 acc[4][4] = {};
    for (int kt = 0; kt < D_MODEL; kt += 32) {
        __syncthreads();
        #pragma unroll
        for (int r = 0; r < 2; ++r) {
            int chunk = r * 256 + tid;
            int row = chunk >> 2, col = (chunk & 3) * 8;
            gload16(Ag + (size_t)row * D_MODEL + kt + col, &As[row * 32 + col]);
            gload16(Bg + (size_t)row * D_MODEL + kt + col, &Bs[row * 32 + col]);
        }
        __syncthreads();
        bf16x8 af[4], bfv[4];
        #pragma unroll
        for (int m = 0; m < 4; ++m) af[m] = *(const bf16x8*)&As[(wr * 64 + m * 16 + fr) * 32 + fg * 8];
        #pragma unroll
        for (int n = 0; n < 4; ++n) bfv[n] = *(const bf16x8*)&Bs[(wc * 64 + n * 16 + fr) * 32 + fg * 8];
        #pragma unroll
        for (int m = 0; m < 4; ++m)
            #pragma unroll
            for (int n = 0; n < 4; ++n)
                acc[m][n] = __builtin_amdgcn_mfma_f32_16x16x32_bf16(af[m], bfv[n], acc[m][n], 0, 0, 0);
    }
    #pragma unroll
    for (int n = 0; n < 4; ++n) {
        int gn = n0 + wc * 64 + n * 16 + fr;
        #pragma unroll
        for (int m = 0; m < 4; ++m) {
            #pragma unroll
            for (int r = 0; r < 4; ++r) {
                int gm = m0 + wr * 64 + m * 16 + fg * 4 + r;
                tmp[(size_t)gm * D_MODEL + gn] = acc[m][n][r];
            }
        }
    }
}

// ---------------- flash attention: dbuf LDS staging, both-sides XOR swizzle ----------------
// K tile [64 s][64 d], V^T tile [64 d][64 s] staged via global_load_lds (linear dest),
// source pre-swizzled so reads at col^((row&7)<<3) are bank-even.
__global__ __launch_bounds__(256) void attn_kernel(const unsigned short* __restrict__ Qb,
                                                   const unsigned short* __restrict__ Kb,
                                                   const unsigned short* __restrict__ Vt,
                                                   const int* __restrict__ amask,
                                                   unsigned short* __restrict__ AF) {
    __shared__ unsigned short Ks[2][64 * 64];
    __shared__ unsigned short Vts[2][64 * 64];
    __shared__ unsigned short Ps[4][32 * 72];   // per-wave private P staging
    const int tid = threadIdx.x, lane = tid & 63, wid = tid >> 6;
    const int fr = lane & 15, fg = lane >> 4;
    const int bh = blockIdx.y, qt = blockIdx.x;
    const int b = bh >> 4;
    const unsigned short* Qh = Qb + (size_t)bh * SEQ * DH;
    const unsigned short* Kh = Kb + (size_t)bh * SEQ * DH;
    const unsigned short* Vth = Vt + (size_t)bh * DH * SEQ;
    const int* mrow = amask + b * SEQ;
    const int q0 = qt * 128 + wid * 32;

    // staging source coordinates (inverse-swizzled): lane l covers tile row
    // (wid*16 + j*8 + (l>>3)), 16B chunk ((l&7) ^ (l>>3)) of that row.
    const int st_row = wid * 16 + (lane >> 3);          // + j*8
    const int st_col = 8 * ((lane & 7) ^ (lane >> 3));  // shorts

    bf16x8 qf[2][2];
    #pragma unroll
    for (int m = 0; m < 2; ++m)
        #pragma unroll
        for (int c = 0; c < 2; ++c)
            qf[m][c] = *(const bf16x8*)(Qh + (size_t)(q0 + m * 16 + fr) * DH + c * 32 + fg * 8);
    f32x4 oacc[2][4] = {};
    float mrun[2][4], lrun[2][4];
    #pragma unroll
    for (int m = 0; m < 2; ++m)
        #pragma unroll
        for (int r = 0; r < 4; ++r) { mrun[m][r] = -3.0e38f; lrun[m][r] = 0.f; }

#define SWZ(row, colsh) ((row) * 64 + ((colsh) ^ (((row) & 7) << 3)))
#define STAGE(bufi, kt2)                                                                  \
    {                                                                                     \
        const int kv0s = (kt2) * 64;                                                      \
        _Pragma("unroll")                                                                 \
        for (int j = 0; j < 2; ++j) {                                                     \
            gload16(Kh + (size_t)(kv0s + st_row + j * 8) * DH + st_col,                   \
                    &Ks[bufi][wid * 1024 + j * 512]);                                     \
            gload16(Vth + (size_t)(st_row + j * 8) * SEQ + kv0s + st_col,                 \
                    &Vts[bufi][wid * 1024 + j * 512]);                                    \
        }                                                                                 \
    }

    STAGE(0, 0);
    __syncthreads();
    int buf = 0;
    for (int kt = 0; kt < 16; ++kt) {
        const int kv0 = kt * 64;
        if (kt < 15) STAGE(buf ^ 1, kt + 1);   // prefetch next tile; drains at end barrier
        // mask bias (additive; exact after row-max subtraction since no row is fully masked)
        float mbias[4];
        #pragma unroll
        for (int n = 0; n < 4; ++n)
            mbias[n] = (mrow[kv0 + n * 16 + fr] != 0) ? -100000.f : 0.f;
        // QK^T from swizzled LDS
        f32x4 s[2][4] = {};
        #pragma unroll
        for (int c = 0; c < 2; ++c) {
            bf16x8 kf[4];
            #pragma unroll
            for (int n = 0; n < 4; ++n)
                kf[n] = *(const bf16x8*)&Ks[buf][SWZ(n * 16 + fr, c * 32 + fg * 8)];
            #pragma unroll
            for (int m = 0; m < 2; ++m)
                #pragma unroll
                for (int n = 0; n < 4; ++n)
                    s[m][n] = __builtin_amdgcn_mfma_f32_16x16x32_bf16(qf[m][c], kf[n], s[m][n], 0, 0, 0);
        }
        // scale + mask (one FMA)
        #pragma unroll
        for (int m = 0; m < 2; ++m)
            #pragma unroll
            for (int n = 0; n < 4; ++n)
                #pragma unroll
                for (int r = 0; r < 4; ++r)
                    s[m][n][r] = fmaf(s[m][n][r], 0.125f, mbias[n]);
        // online softmax
        #pragma unroll
        for (int m = 0; m < 2; ++m) {
            #pragma unroll
            for (int r = 0; r < 4; ++r) {
                float pm = fmaxf(fmaxf(s[m][0][r], s[m][1][r]), fmaxf(s[m][2][r], s[m][3][r]));
                pm = fmaxf(pm, __shfl_xor(pm, 1));
                pm = fmaxf(pm, __shfl_xor(pm, 2));
                pm = fmaxf(pm, __shfl_xor(pm, 4));
                pm = fmaxf(pm, __shfl_xor(pm, 8));
                float newm = fmaxf(mrun[m][r], pm);
                float corr = __expf(mrun[m][r] - newm);
                mrun[m][r] = newm;
                float ps = 0.f;
                #pragma unroll
                for (int n = 0; n < 4; ++n) {
                    float p = __expf(s[m][n][r] - newm);
                    s[m][n][r] = p;
                    ps += p;
                }
                ps += __shfl_xor(ps, 1);
                ps += __shfl_xor(ps, 2);
                ps += __shfl_xor(ps, 4);
                ps += __shfl_xor(ps, 8);
                lrun[m][r] = lrun[m][r] * corr + ps;
                #pragma unroll
                for (int dn = 0; dn < 4; ++dn) oacc[m][dn][r] *= corr;
            }
        }
        // P -> per-wave LDS (C/D layout -> A layout)
        #pragma unroll
        for (int m = 0; m < 2; ++m)
            #pragma unroll
            for (int n = 0; n < 4; ++n)
                #pragma unroll
                for (int r = 0; r < 4; ++r)
                    Ps[wid][(m * 16 + fg * 4 + r) * 72 + n * 16 + fr] = f2bf(s[m][n][r]);
        // PV from swizzled LDS
        #pragma unroll
        for (int c = 0; c < 2; ++c) {
            bf16x8 pf[2], vf[4];
            #pragma unroll
            for (int m = 0; m < 2; ++m)
                pf[m] = *(const bf16x8*)&Ps[wid][(m * 16 + fr) * 72 + c * 32 + fg * 8];
            #pragma unroll
            for (int dn = 0; dn < 4; ++dn)
                vf[dn] = *(const bf16x8*)&Vts[buf][SWZ(dn * 16 + fr, c * 32 + fg * 8)];
            #pragma unroll
            for (int m = 0; m < 2; ++m)
                #pragma unroll
                for (int dn = 0; dn < 4; ++dn)
                    oacc[m][dn] = __builtin_amdgcn_mfma_f32_16x16x32_bf16(pf[m], vf[dn], oacc[m][dn], 0, 0, 0);
        }
        __syncthreads();   // drains prefetch (vmcnt) + all reads of buf; safe to overwrite
        buf ^= 1;
    }
#undef STAGE
#undef SWZ
    // epilogue with faithful-to-torch head scramble: i=b*16+h lands at b2=i&3, h2=i>>2
    const int b2 = bh & 3, h2 = bh >> 2;
    #pragma unroll
    for (int m = 0; m < 2; ++m)
        #pragma unroll
        for (int dn = 0; dn < 4; ++dn)
            #pragma unroll
            for (int r = 0; r < 4; ++r) {
                int q = q0 + m * 16 + fg * 4 + r;
                int d = dn * 16 + fr;
                float o = oacc[m][dn][r] / lrun[m][r];
                AF[((size_t)b2 * SEQ + q) * D_MODEL + h2 * DH + d] = f2bf(o);
            }
}

// ---------------- residual + LayerNorm ----------------
__global__ __launch_bounds__(256) void ln_kernel(const float* __restrict__ tmp,
                                                 const float* __restrict__ inp,
                                                 const float* __restrict__ g,
                                                 const float* __restrict__ bb,
                                                 float* __restrict__ out) {
    __shared__ float red[8];
    const int row = blockIdx.x, tid = threadIdx.x;
    float4 t = ((const float4*)(tmp + (size_t)row * D_MODEL))[tid];
    float4 rr = ((const float4*)(inp + (size_t)row * D_MODEL))[tid];
    float4 y;
    y.x = t.x + rr.x; y.y = t.y + rr.y; y.z = t.z + rr.z; y.w = t.w + rr.w;
    float sum = y.x + y.y + y.z + y.w;
    float sq = y.x * y.x + y.y * y.y + y.z * y.z + y.w * y.w;
    #pragma unroll
    for (int o = 1; o < 64; o <<= 1) { sum += __shfl_xor(sum, o); sq += __shfl_xor(sq, o); }
    int wid = tid >> 6, lane = tid & 63;
    if (lane == 0) { red[wid] = sum; red[4 + wid] = sq; }
    __syncthreads();
    sum = red[0] + red[1] + red[2] + red[3];
    sq = red[4] + red[5] + red[6] + red[7];
    float mu = sum * (1.f / D_MODEL);
    float var = sq * (1.f / D_MODEL) - mu * mu;
    float rs = rsqrtf(var + 1e-5f);
    float4 gg = ((const float4*)g)[tid];
    float4 bv = ((const float4*)bb)[tid];
    float4 o4;
    o4.x = (y.x - mu) * rs * gg.x + bv.x;
    o4.y = (y.y - mu) * rs * gg.y + bv.y;
    o4.z = (y.z - mu) * rs * gg.z + bv.z;
    o4.w = (y.w - mu) * rs * gg.w + bv.w;
    ((float4*)(out + (size_t)row * D_MODEL))[tid] = o4;
}

extern "C" void kernel_launch(void* const* d_in, const int* in_sizes, int n_in,
                              void* d_out, int out_size, void* d_ws, size_t ws_size,
                              hipStream_t stream) {
    const float* inp = (const float*)d_in[0];
    const int* amask = (const int*)d_in[1];
    const float* Wq = (const float*)d_in[2];
    const float* bq = (const float*)d_in[3];
    const float* Wk = (const float*)d_in[4];
    const float* bk = (const float*)d_in[5];
    const float* Wv = (const float*)d_in[6];
    const float* bv = (const float*)d_in[7];
    const float* Wo = (const float*)d_in[8];
    const float* lg = (const float*)d_in[9];
    const float* lb = (const float*)d_in[10];
    float* out = (float*)d_out;
    char* ws = (char*)d_ws;

    unsigned short* Xb     = (unsigned short*)(ws + 0);          //  8.0 MiB
    unsigned short* Wqkv_t = (unsigned short*)(ws + 8388608);    //  6.0 MiB
    unsigned short* Wo_t   = (unsigned short*)(ws + 14680064);   //  2.0 MiB
    unsigned short* Qb     = (unsigned short*)(ws + 16777216);   //  8.0 MiB
    unsigned short* Kb     = (unsigned short*)(ws + 25165824);   //  8.0 MiB
    unsigned short* Vt     = (unsigned short*)(ws + 33554432);   //  8.0 MiB  (V^T: [bh][d][s])
    unsigned short* AF     = (unsigned short*)(ws + 41943040);   //  8.0 MiB
    float*          tmp    = (float*)(ws + 50331648);            // 16.0 MiB  (total 64 MiB)

    cvt_x<<<4096, 256, 0, stream>>>(inp, Xb);
    transpose_w<<<dim3(32, 32, 4), dim3(32, 8), 0, stream>>>(Wq, Wk, Wv, Wo, Wqkv_t, Wo_t);
    gemm_qkv<<<dim3(32, 24), 256, 0, stream>>>(Xb, Wqkv_t, bq, bk, bv, Qb, Kb, Vt);
    attn_kernel<<<dim3(8, 64), 256, 0, stream>>>(Qb, Kb, Vt, amask, AF);
    gemm_o<<<dim3(32, 8), 256, 0, stream>>>(AF, Wo_t, tmp);
    ln_kernel<<<4096, 256, 0, stream>>>(tmp, inp, lg, lb, out);
}

// Round 4
// 152.244 us; speedup vs baseline: 1.2563x; 1.1108x over previous
//
#include <hip/hip_runtime.h>

typedef __attribute__((ext_vector_type(8))) short bf16x8;
typedef __attribute__((ext_vector_type(4))) float f32x4;

#define D_MODEL 1024
#define SEQ 1024
#define NB 4
#define NH 16
#define DH 64
#define MROWS 4096

__device__ __forceinline__ unsigned short f2bf(float f) {
    union { float f; unsigned u; } x; x.f = f;
    unsigned r = x.u + 0x7fffu + ((x.u >> 16) & 1u);
    return (unsigned short)(r >> 16);
}

__device__ __forceinline__ void gload16(const void* g, void* l) {
    __builtin_amdgcn_global_load_lds((const __attribute__((address_space(1))) void*)g,
                                     (__attribute__((address_space(3))) void*)l, 16, 0, 0);
}

// ---------------- convert inp f32 -> bf16 ----------------
__global__ __launch_bounds__(256) void cvt_x(const float* __restrict__ x,
                                             unsigned short* __restrict__ o) {
    int i = blockIdx.x * 256 + threadIdx.x;
    float4 v = ((const float4*)x)[i];
    ushort4 r;
    r.x = f2bf(v.x); r.y = f2bf(v.y); r.z = f2bf(v.z); r.w = f2bf(v.w);
    ((ushort4*)o)[i] = r;
}

// ---------------- transpose W (f32) -> bf16 W^T ----------------
__global__ __launch_bounds__(256) void transpose_w(const float* __restrict__ Wq,
                                                   const float* __restrict__ Wk,
                                                   const float* __restrict__ Wv,
                                                   const float* __restrict__ Wo,
                                                   unsigned short* __restrict__ Wqkv_t,
                                                   unsigned short* __restrict__ Wo_t) {
    __shared__ float tile[32][33];
    const int mtx = blockIdx.z;
    const float* src = mtx == 0 ? Wq : mtx == 1 ? Wk : mtx == 2 ? Wv : Wo;
    unsigned short* dst = mtx < 3 ? (Wqkv_t + (size_t)mtx * D_MODEL * D_MODEL) : Wo_t;
    const int n0 = blockIdx.x * 32, k0 = blockIdx.y * 32;
    const int tx = threadIdx.x, ty = threadIdx.y;
    #pragma unroll
    for (int i = 0; i < 32; i += 8)
        tile[ty + i][tx] = src[(size_t)(k0 + ty + i) * D_MODEL + n0 + tx];
    __syncthreads();
    #pragma unroll
    for (int i = 0; i < 32; i += 8)
        dst[(size_t)(n0 + ty + i) * D_MODEL + k0 + tx] = f2bf(tile[tx][ty + i]);
}

// ---------------- QKV GEMM: Xb[4096][1024] @ Wqkv_t^T -> Q,K [bh][s][64], V^T [bh][64][s] ----------------
// XCD-chunked block remap + LDS-coalesced epilogue (V panels transposed in LDS).
__global__ __launch_bounds__(256) void gemm_qkv(const unsigned short* __restrict__ Xb,
                                                const unsigned short* __restrict__ Wt,
                                                const float* __restrict__ bq,
                                                const float* __restrict__ bk,
                                                const float* __restrict__ bv,
                                                unsigned short* __restrict__ Qb,
                                                unsigned short* __restrict__ Kb,
                                                unsigned short* __restrict__ Vt) {
    __shared__ unsigned short As[128 * 32];
    __shared__ unsigned short Bs[128 * 32];
    __shared__ unsigned short Cs[128 * 136];   // 136: 16B-aligned rows
    const int tid = threadIdx.x;
    const int lane = tid & 63, wid = tid >> 6;
    const int fr = lane & 15, fg = lane >> 4;
    const int wr = wid >> 1, wc = wid & 1;
    // XCD x (=lin&7) gets an 8(m) x 12(n) rectangle: ~5MB working set per L2
    const int lin = blockIdx.x;
    const int x = lin & 7, i = lin >> 3;           // i in 0..95
    const int bxm = (x & 3) * 8 + (i & 7);         // m-panel 0..31
    const int byn = (x >> 2) * 12 + (i >> 3);      // n-panel 0..23
    const int m0 = bxm * 128, n0 = byn * 128;
    const unsigned short* Ag = Xb + (size_t)m0 * D_MODEL;
    const unsigned short* Bg = Wt + (size_t)n0 * D_MODEL;
    f32x4 acc[4][4] = {};
    for (int kt = 0; kt < D_MODEL; kt += 32) {
        __syncthreads();
        #pragma unroll
        for (int r = 0; r < 2; ++r) {
            int chunk = r * 256 + tid;
            int row = chunk >> 2, col = (chunk & 3) * 8;
            gload16(Ag + (size_t)row * D_MODEL + kt + col, &As[row * 32 + col]);
            gload16(Bg + (size_t)row * D_MODEL + kt + col, &Bs[row * 32 + col]);
        }
        __syncthreads();
        bf16x8 af[4], bfv[4];
        #pragma unroll
        for (int m = 0; m < 4; ++m) af[m] = *(const bf16x8*)&As[(wr * 64 + m * 16 + fr) * 32 + fg * 8];
        #pragma unroll
        for (int n = 0; n < 4; ++n) bfv[n] = *(const bf16x8*)&Bs[(wc * 64 + n * 16 + fr) * 32 + fg * 8];
        #pragma unroll
        for (int m = 0; m < 4; ++m)
            #pragma unroll
            for (int n = 0; n < 4; ++n)
                acc[m][n] = __builtin_amdgcn_mfma_f32_16x16x32_bf16(af[m], bfv[n], acc[m][n], 0, 0, 0);
    }
    const int sel = n0 >> 10;        // block-uniform: 0=Q 1=K 2=V
    const int npb = n0 & 1023;
    if (sel < 2) {
        #pragma unroll
        for (int n = 0; n < 4; ++n) {
            int cn = wc * 64 + n * 16 + fr;
            float bias = (sel == 0 ? bq : bk)[npb + cn];
            #pragma unroll
            for (int m = 0; m < 4; ++m)
                #pragma unroll
                for (int r = 0; r < 4; ++r)
                    Cs[(wr * 64 + m * 16 + fg * 4 + r) * 136 + cn] = f2bf(acc[m][n][r] + bias);
        }
        __syncthreads();
        unsigned short* dst = sel == 0 ? Qb : Kb;
        #pragma unroll
        for (int k = 0; k < 8; ++k) {
            int c = k * 256 + tid;
            int row = c >> 4, cc = c & 15;
            int np = npb + cc * 8;
            int h = np >> 6, d = np & 63;
            int gm = m0 + row, b = gm >> 10, s = gm & 1023;
            bf16x8 v = *(const bf16x8*)&Cs[row * 136 + cc * 8];
            *(bf16x8*)&dst[((size_t)(b * NH + h) * SEQ + s) * DH + d] = v;
        }
    } else {
        // store transposed into Cs: Cs[d][s]
        #pragma unroll
        for (int n = 0; n < 4; ++n) {
            int cn = wc * 64 + n * 16 + fr;
            float bias = bv[npb + cn];
            #pragma unroll
            for (int m = 0; m < 4; ++m)
                #pragma unroll
                for (int r = 0; r < 4; ++r)
                    Cs[cn * 136 + (wr * 64 + m * 16 + fg * 4 + r)] = f2bf(acc[m][n][r] + bias);
        }
        __syncthreads();
        #pragma unroll
        for (int k = 0; k < 8; ++k) {
            int c = k * 256 + tid;
            int dcol = c >> 4, scc = c & 15;
            int np = npb + dcol;
            int h = np >> 6, dd = np & 63;
            int gm0 = m0 + scc * 8, b = gm0 >> 10, s0 = gm0 & 1023;
            bf16x8 v = *(const bf16x8*)&Cs[dcol * 136 + scc * 8];
            *(bf16x8*)&Vt[((size_t)(b * NH + h) * DH + dd) * SEQ + s0] = v;
        }
    }
}

// ---------------- O-proj GEMM: AF bf16 [4096][1024] @ Wo_t^T -> tmp f32 ----------------
__global__ __launch_bounds__(256) void gemm_o(const unsigned short* __restrict__ Ab,
                                              const unsigned short* __restrict__ Wt,
                                              float* __restrict__ tmp) {
    __shared__ unsigned short As[128 * 32];
    __shared__ unsigned short Bs[128 * 32];
    const int tid = threadIdx.x;
    const int lane = tid & 63, wid = tid >> 6;
    const int fr = lane & 15, fg = lane >> 4;
    const int wr = wid >> 1, wc = wid & 1;
    // XCD x gets an 8(m) x 4(n) rectangle: ~3MB per L2
    const int lin = blockIdx.x;
    const int x = lin & 7, i = lin >> 3;           // i in 0..31
    const int bxm = (x & 3) * 8 + (i & 7);         // 0..31
    const int byn = (x >> 2) * 4 + (i >> 3);       // 0..7
    const int m0 = bxm * 128, n0 = byn * 128;
    const unsigned short* Ag = Ab + (size_t)m0 * D_MODEL;
    const unsigned short* Bg = Wt + (size_t)n0 * D_MODEL;
    f32x4 acc[4][4] = {};
    for (int kt = 0; kt < D_MODEL; kt += 32) {
        __syncthreads();
        #pragma unroll
        for (int r = 0; r < 2; ++r) {
            int chunk = r * 256 + tid;
            int row = chunk >> 2, col = (chunk & 3) * 8;
            gload16(Ag + (size_t)row * D_MODEL + kt + col, &As[row * 32 + col]);
            gload16(Bg + (size_t)row * D_MODEL + kt + col, &Bs[row * 32 + col]);
        }
        __syncthreads();
        bf16x8 af[4], bfv[4];
        #pragma unroll
        for (int m = 0; m < 4; ++m) af[m] = *(const bf16x8*)&As[(wr * 64 + m * 16 + fr) * 32 + fg * 8];
        #pragma unroll
        for (int n = 0; n < 4; ++n) bfv[n] = *(const bf16x8*)&Bs[(wc * 64 + n * 16 + fr) * 32 + fg * 8];
        #pragma unroll
        for (int m = 0; m < 4; ++m)
            #pragma unroll
            for (int n = 0; n < 4; ++n)
                acc[m][n] = __builtin_amdgcn_mfma_f32_16x16x32_bf16(af[m], bfv[n], acc[m][n], 0, 0, 0);
    }
    #pragma unroll
    for (int n = 0; n < 4; ++n) {
        int gn = n0 + wc * 64 + n * 16 + fr;
        #pragma unroll
        for (int m = 0; m < 4; ++m) {
            #pragma unroll
            for (int r = 0; r < 4; ++r) {
                int gm = m0 + wr * 64 + m * 16 + fg * 4 + r;
                tmp[(size_t)gm * D_MODEL + gn] = acc[m][n][r];
            }
        }
    }
}

// ---------------- flash attention: dbuf swizzled LDS staging + XCD head-grouping + setprio ----------------
__global__ __launch_bounds__(256) void attn_kernel(const unsigned short* __restrict__ Qb,
                                                   const unsigned short* __restrict__ Kb,
                                                   const unsigned short* __restrict__ Vt,
                                                   const int* __restrict__ amask,
                                                   unsigned short* __restrict__ AF) {
    __shared__ unsigned short Ks[2][64 * 64];
    __shared__ unsigned short Vts[2][64 * 64];
    __shared__ unsigned short Ps[4][32 * 72];
    const int tid = threadIdx.x, lane = tid & 63, wid = tid >> 6;
    const int fr = lane & 15, fg = lane >> 4;
    // XCD x (=lin&7) owns heads bh in [8x, 8x+8): K/V+Q working set ~3MB per L2
    const int lin = blockIdx.x;
    const int x = lin & 7, i = lin >> 3;       // i in 0..63
    const int qt = i & 7, bh = x * 8 + (i >> 3);
    const int b = bh >> 4;
    const unsigned short* Qh = Qb + (size_t)bh * SEQ * DH;
    const unsigned short* Kh = Kb + (size_t)bh * SEQ * DH;
    const unsigned short* Vth = Vt + (size_t)bh * DH * SEQ;
    const int* mrow = amask + b * SEQ;
    const int q0 = qt * 128 + wid * 32;

    const int st_row = wid * 16 + (lane >> 3);          // + j*8
    const int st_col = 8 * ((lane & 7) ^ (lane >> 3));  // inverse-swizzled source chunk

    bf16x8 qf[2][2];
    #pragma unroll
    for (int m = 0; m < 2; ++m)
        #pragma unroll
        for (int c = 0; c < 2; ++c)
            qf[m][c] = *(const bf16x8*)(Qh + (size_t)(q0 + m * 16 + fr) * DH + c * 32 + fg * 8);
    f32x4 oacc[2][4] = {};
    float mrun[2][4], lrun[2][4];
    #pragma unroll
    for (int m = 0; m < 2; ++m)
        #pragma unroll
        for (int r = 0; r < 4; ++r) { mrun[m][r] = -3.0e38f; lrun[m][r] = 0.f; }

#define SWZ(row, colsh) ((row) * 64 + ((colsh) ^ (((row) & 7) << 3)))
#define STAGE(bufi, kt2)                                                                  \
    {                                                                                     \
        const int kv0s = (kt2) * 64;                                                      \
        _Pragma("unroll")                                                                 \
        for (int j = 0; j < 2; ++j) {                                                     \
            gload16(Kh + (size_t)(kv0s + st_row + j * 8) * DH + st_col,                   \
                    &Ks[bufi][wid * 1024 + j * 512]);                                     \
            gload16(Vth + (size_t)(st_row + j * 8) * SEQ + kv0s + st_col,                 \
                    &Vts[bufi][wid * 1024 + j * 512]);                                    \
        }                                                                                 \
    }

    STAGE(0, 0);
    __syncthreads();
    int buf = 0;
    for (int kt = 0; kt < 16; ++kt) {
        const int kv0 = kt * 64;
        if (kt < 15) STAGE(buf ^ 1, kt + 1);
        float mbias[4];
        #pragma unroll
        for (int n = 0; n < 4; ++n)
            mbias[n] = (mrow[kv0 + n * 16 + fr] != 0) ? -100000.f : 0.f;
        f32x4 s[2][4] = {};
        __builtin_amdgcn_s_setprio(1);
        #pragma unroll
        for (int c = 0; c < 2; ++c) {
            bf16x8 kf[4];
            #pragma unroll
            for (int n = 0; n < 4; ++n)
                kf[n] = *(const bf16x8*)&Ks[buf][SWZ(n * 16 + fr, c * 32 + fg * 8)];
            #pragma unroll
            for (int m = 0; m < 2; ++m)
                #pragma unroll
                for (int n = 0; n < 4; ++n)
                    s[m][n] = __builtin_amdgcn_mfma_f32_16x16x32_bf16(qf[m][c], kf[n], s[m][n], 0, 0, 0);
        }
        __builtin_amdgcn_s_setprio(0);
        #pragma unroll
        for (int m = 0; m < 2; ++m)
            #pragma unroll
            for (int n = 0; n < 4; ++n)
                #pragma unroll
                for (int r = 0; r < 4; ++r)
                    s[m][n][r] = fmaf(s[m][n][r], 0.125f, mbias[n]);
        #pragma unroll
        for (int m = 0; m < 2; ++m) {
            #pragma unroll
            for (int r = 0; r < 4; ++r) {
                float pm = fmaxf(fmaxf(s[m][0][r], s[m][1][r]), fmaxf(s[m][2][r], s[m][3][r]));
                pm = fmaxf(pm, __shfl_xor(pm, 1));
                pm = fmaxf(pm, __shfl_xor(pm, 2));
                pm = fmaxf(pm, __shfl_xor(pm, 4));
                pm = fmaxf(pm, __shfl_xor(pm, 8));
                float newm = fmaxf(mrun[m][r], pm);
                float corr = __expf(mrun[m][r] - newm);
                mrun[m][r] = newm;
                float ps = 0.f;
                #pragma unroll
                for (int n = 0; n < 4; ++n) {
                    float p = __expf(s[m][n][r] - newm);
                    s[m][n][r] = p;
                    ps += p;
                }
                ps += __shfl_xor(ps, 1);
                ps += __shfl_xor(ps, 2);
                ps += __shfl_xor(ps, 4);
                ps += __shfl_xor(ps, 8);
                lrun[m][r] = lrun[m][r] * corr + ps;
                #pragma unroll
                for (int dn = 0; dn < 4; ++dn) oacc[m][dn][r] *= corr;
            }
        }
        #pragma unroll
        for (int m = 0; m < 2; ++m)
            #pragma unroll
            for (int n = 0; n < 4; ++n)
                #pragma unroll
                for (int r = 0; r < 4; ++r)
                    Ps[wid][(m * 16 + fg * 4 + r) * 72 + n * 16 + fr] = f2bf(s[m][n][r]);
        __builtin_amdgcn_s_setprio(1);
        #pragma unroll
        for (int c = 0; c < 2; ++c) {
            bf16x8 pf[2], vf[4];
            #pragma unroll
            for (int m = 0; m < 2; ++m)
                pf[m] = *(const bf16x8*)&Ps[wid][(m * 16 + fr) * 72 + c * 32 + fg * 8];
            #pragma unroll
            for (int dn = 0; dn < 4; ++dn)
                vf[dn] = *(const bf16x8*)&Vts[buf][SWZ(dn * 16 + fr, c * 32 + fg * 8)];
            #pragma unroll
            for (int m = 0; m < 2; ++m)
                #pragma unroll
                for (int dn = 0; dn < 4; ++dn)
                    oacc[m][dn] = __builtin_amdgcn_mfma_f32_16x16x32_bf16(pf[m], vf[dn], oacc[m][dn], 0, 0, 0);
        }
        __builtin_amdgcn_s_setprio(0);
        __syncthreads();
        buf ^= 1;
    }
#undef STAGE
#undef SWZ
    const int b2 = bh & 3, h2 = bh >> 2;   // faithful-to-torch head scramble
    #pragma unroll
    for (int m = 0; m < 2; ++m)
        #pragma unroll
        for (int dn = 0; dn < 4; ++dn)
            #pragma unroll
            for (int r = 0; r < 4; ++r) {
                int q = q0 + m * 16 + fg * 4 + r;
                int d = dn * 16 + fr;
                float o = oacc[m][dn][r] / lrun[m][r];
                AF[((size_t)b2 * SEQ + q) * D_MODEL + h2 * DH + d] = f2bf(o);
            }
}

// ---------------- residual + LayerNorm ----------------
__global__ __launch_bounds__(256) void ln_kernel(const float* __restrict__ tmp,
                                                 const float* __restrict__ inp,
                                                 const float* __restrict__ g,
                                                 const float* __restrict__ bb,
                                                 float* __restrict__ out) {
    __shared__ float red[8];
    const int row = blockIdx.x, tid = threadIdx.x;
    float4 t = ((const float4*)(tmp + (size_t)row * D_MODEL))[tid];
    float4 rr = ((const float4*)(inp + (size_t)row * D_MODEL))[tid];
    float4 y;
    y.x = t.x + rr.x; y.y = t.y + rr.y; y.z = t.z + rr.z; y.w = t.w + rr.w;
    float sum = y.x + y.y + y.z + y.w;
    float sq = y.x * y.x + y.y * y.y + y.z * y.z + y.w * y.w;
    #pragma unroll
    for (int o = 1; o < 64; o <<= 1) { sum += __shfl_xor(sum, o); sq += __shfl_xor(sq, o); }
    int wid = tid >> 6, lane = tid & 63;
    if (lane == 0) { red[wid] = sum; red[4 + wid] = sq; }
    __syncthreads();
    sum = red[0] + red[1] + red[2] + red[3];
    sq = red[4] + red[5] + red[6] + red[7];
    float mu = sum * (1.f / D_MODEL);
    float var = sq * (1.f / D_MODEL) - mu * mu;
    float rs = rsqrtf(var + 1e-5f);
    float4 gg = ((const float4*)g)[tid];
    float4 bv = ((const float4*)bb)[tid];
    float4 o4;
    o4.x = (y.x - mu) * rs * gg.x + bv.x;
    o4.y = (y.y - mu) * rs * gg.y + bv.y;
    o4.z = (y.z - mu) * rs * gg.z + bv.z;
    o4.w = (y.w - mu) * rs * gg.w + bv.w;
    ((float4*)(out + (size_t)row * D_MODEL))[tid] = o4;
}

extern "C" void kernel_launch(void* const* d_in, const int* in_sizes, int n_in,
                              void* d_out, int out_size, void* d_ws, size_t ws_size,
                              hipStream_t stream) {
    const float* inp = (const float*)d_in[0];
    const int* amask = (const int*)d_in[1];
    const float* Wq = (const float*)d_in[2];
    const float* bq = (const float*)d_in[3];
    const float* Wk = (const float*)d_in[4];
    const float* bk = (const float*)d_in[5];
    const float* Wv = (const float*)d_in[6];
    const float* bv = (const float*)d_in[7];
    const float* Wo = (const float*)d_in[8];
    const float* lg = (const float*)d_in[9];
    const float* lb = (const float*)d_in[10];
    float* out = (float*)d_out;
    char* ws = (char*)d_ws;

    unsigned short* Xb     = (unsigned short*)(ws + 0);          //  8.0 MiB
    unsigned short* Wqkv_t = (unsigned short*)(ws + 8388608);    //  6.0 MiB
    unsigned short* Wo_t   = (unsigned short*)(ws + 14680064);   //  2.0 MiB
    unsigned short* Qb     = (unsigned short*)(ws + 16777216);   //  8.0 MiB
    unsigned short* Kb     = (unsigned short*)(ws + 25165824);   //  8.0 MiB
    unsigned short* Vt     = (unsigned short*)(ws + 33554432);   //  8.0 MiB  (V^T: [bh][d][s])
    unsigned short* AF     = (unsigned short*)(ws + 41943040);   //  8.0 MiB
    float*          tmp    = (float*)(ws + 50331648);            // 16.0 MiB  (total 64 MiB)

    cvt_x<<<4096, 256, 0, stream>>>(inp, Xb);
    transpose_w<<<dim3(32, 32, 4), dim3(32, 8), 0, stream>>>(Wq, Wk, Wv, Wo, Wqkv_t, Wo_t);
    gemm_qkv<<<768, 256, 0, stream>>>(Xb, Wqkv_t, bq, bk, bv, Qb, Kb, Vt);
    attn_kernel<<<512, 256, 0, stream>>>(Qb, Kb, Vt, amask, AF);
    gemm_o<<<256, 256, 0, stream>>>(AF, Wo_t, tmp);
    ln_kernel<<<4096, 256, 0, stream>>>(tmp, inp, lg, lb, out);
}

// Round 5
// 140.530 us; speedup vs baseline: 1.3610x; 1.0834x over previous
//
#include <hip/hip_runtime.h>

typedef __attribute__((ext_vector_type(8))) short bf16x8;
typedef __attribute__((ext_vector_type(4))) float f32x4;
typedef __attribute__((ext_vector_type(16))) float f32x16;

#define D_MODEL 1024
#define SEQ 1024
#define NB 4
#define NH 16
#define DH 64
#define MROWS 4096

__device__ __forceinline__ unsigned short f2bf(float f) {
    union { float f; unsigned u; } x; x.f = f;
    unsigned r = x.u + 0x7fffu + ((x.u >> 16) & 1u);
    return (unsigned short)(r >> 16);
}

__device__ __forceinline__ void gload16(const void* g, void* l) {
    __builtin_amdgcn_global_load_lds((const __attribute__((address_space(1))) void*)g,
                                     (__attribute__((address_space(3))) void*)l, 16, 0, 0);
}

// ---------------- convert inp f32 -> bf16 ----------------
__global__ __launch_bounds__(256) void cvt_x(const float* __restrict__ x,
                                             unsigned short* __restrict__ o) {
    int i = blockIdx.x * 256 + threadIdx.x;
    float4 v = ((const float4*)x)[i];
    ushort4 r;
    r.x = f2bf(v.x); r.y = f2bf(v.y); r.z = f2bf(v.z); r.w = f2bf(v.w);
    ((ushort4*)o)[i] = r;
}

// ---------------- pack attn_mask -> 64-bit words per (b, kv-tile) ----------------
__global__ __launch_bounds__(64) void pack_mask(const int* __restrict__ amask,
                                                unsigned long long* __restrict__ mwords) {
    int t = threadIdx.x;           // 0..63
    int b = t >> 4, kt = t & 15;
    const int* src = amask + b * SEQ + kt * 64;
    unsigned long long w = 0;
    for (int j = 0; j < 64; ++j)
        w |= (unsigned long long)(src[j] != 0 ? 1 : 0) << j;
    mwords[t] = w;
}

// ---------------- transpose W (f32) -> bf16 W^T ----------------
__global__ __launch_bounds__(256) void transpose_w(const float* __restrict__ Wq,
                                                   const float* __restrict__ Wk,
                                                   const float* __restrict__ Wv,
                                                   const float* __restrict__ Wo,
                                                   unsigned short* __restrict__ Wqkv_t,
                                                   unsigned short* __restrict__ Wo_t) {
    __shared__ float tile[32][33];
    const int mtx = blockIdx.z;
    const float* src = mtx == 0 ? Wq : mtx == 1 ? Wk : mtx == 2 ? Wv : Wo;
    unsigned short* dst = mtx < 3 ? (Wqkv_t + (size_t)mtx * D_MODEL * D_MODEL) : Wo_t;
    const int n0 = blockIdx.x * 32, k0 = blockIdx.y * 32;
    const int tx = threadIdx.x, ty = threadIdx.y;
    #pragma unroll
    for (int i = 0; i < 32; i += 8)
        tile[ty + i][tx] = src[(size_t)(k0 + ty + i) * D_MODEL + n0 + tx];
    __syncthreads();
    #pragma unroll
    for (int i = 0; i < 32; i += 8)
        dst[(size_t)(n0 + ty + i) * D_MODEL + k0 + tx] = f2bf(tile[tx][ty + i]);
}

// ---------------- QKV GEMM: Xb[4096][1024] @ Wqkv_t^T -> Q,K [bh][s][64], V^T [bh][64][s] ----------------
__global__ __launch_bounds__(256) void gemm_qkv(const unsigned short* __restrict__ Xb,
                                                const unsigned short* __restrict__ Wt,
                                                const float* __restrict__ bq,
                                                const float* __restrict__ bk,
                                                const float* __restrict__ bv,
                                                unsigned short* __restrict__ Qb,
                                                unsigned short* __restrict__ Kb,
                                                unsigned short* __restrict__ Vt) {
    __shared__ unsigned short As[128 * 32];
    __shared__ unsigned short Bs[128 * 32];
    __shared__ unsigned short Cs[128 * 136];
    const int tid = threadIdx.x;
    const int lane = tid & 63, wid = tid >> 6;
    const int fr = lane & 15, fg = lane >> 4;
    const int wr = wid >> 1, wc = wid & 1;
    const int lin = blockIdx.x;
    const int x = lin & 7, i = lin >> 3;
    const int bxm = (x & 3) * 8 + (i & 7);
    const int byn = (x >> 2) * 12 + (i >> 3);
    const int m0 = bxm * 128, n0 = byn * 128;
    const unsigned short* Ag = Xb + (size_t)m0 * D_MODEL;
    const unsigned short* Bg = Wt + (size_t)n0 * D_MODEL;
    f32x4 acc[4][4] = {};
    for (int kt = 0; kt < D_MODEL; kt += 32) {
        __syncthreads();
        #pragma unroll
        for (int r = 0; r < 2; ++r) {
            int chunk = r * 256 + tid;
            int row = chunk >> 2, col = (chunk & 3) * 8;
            gload16(Ag + (size_t)row * D_MODEL + kt + col, &As[row * 32 + col]);
            gload16(Bg + (size_t)row * D_MODEL + kt + col, &Bs[row * 32 + col]);
        }
        __syncthreads();
        bf16x8 af[4], bfv[4];
        #pragma unroll
        for (int m = 0; m < 4; ++m) af[m] = *(const bf16x8*)&As[(wr * 64 + m * 16 + fr) * 32 + fg * 8];
        #pragma unroll
        for (int n = 0; n < 4; ++n) bfv[n] = *(const bf16x8*)&Bs[(wc * 64 + n * 16 + fr) * 32 + fg * 8];
        #pragma unroll
        for (int m = 0; m < 4; ++m)
            #pragma unroll
            for (int n = 0; n < 4; ++n)
                acc[m][n] = __builtin_amdgcn_mfma_f32_16x16x32_bf16(af[m], bfv[n], acc[m][n], 0, 0, 0);
    }
    const int sel = n0 >> 10;
    const int npb = n0 & 1023;
    if (sel < 2) {
        #pragma unroll
        for (int n = 0; n < 4; ++n) {
            int cn = wc * 64 + n * 16 + fr;
            float bias = (sel == 0 ? bq : bk)[npb + cn];
            #pragma unroll
            for (int m = 0; m < 4; ++m)
                #pragma unroll
                for (int r = 0; r < 4; ++r)
                    Cs[(wr * 64 + m * 16 + fg * 4 + r) * 136 + cn] = f2bf(acc[m][n][r] + bias);
        }
        __syncthreads();
        unsigned short* dst = sel == 0 ? Qb : Kb;
        #pragma unroll
        for (int k = 0; k < 8; ++k) {
            int c = k * 256 + tid;
            int row = c >> 4, cc = c & 15;
            int np = npb + cc * 8;
            int h = np >> 6, d = np & 63;
            int gm = m0 + row, b = gm >> 10, s = gm & 1023;
            bf16x8 v = *(const bf16x8*)&Cs[row * 136 + cc * 8];
            *(bf16x8*)&dst[((size_t)(b * NH + h) * SEQ + s) * DH + d] = v;
        }
    } else {
        #pragma unroll
        for (int n = 0; n < 4; ++n) {
            int cn = wc * 64 + n * 16 + fr;
            float bias = bv[npb + cn];
            #pragma unroll
            for (int m = 0; m < 4; ++m)
                #pragma unroll
                for (int r = 0; r < 4; ++r)
                    Cs[cn * 136 + (wr * 64 + m * 16 + fg * 4 + r)] = f2bf(acc[m][n][r] + bias);
        }
        __syncthreads();
        #pragma unroll
        for (int k = 0; k < 8; ++k) {
            int c = k * 256 + tid;
            int dcol = c >> 4, scc = c & 15;
            int np = npb + dcol;
            int h = np >> 6, dd = np & 63;
            int gm0 = m0 + scc * 8, b = gm0 >> 10, s0 = gm0 & 1023;
            bf16x8 v = *(const bf16x8*)&Cs[dcol * 136 + scc * 8];
            *(bf16x8*)&Vt[((size_t)(b * NH + h) * DH + dd) * SEQ + s0] = v;
        }
    }
}

// ---------------- O-proj GEMM ----------------
__global__ __launch_bounds__(256) void gemm_o(const unsigned short* __restrict__ Ab,
                                              const unsigned short* __restrict__ Wt,
                                              float* __restrict__ tmp) {
    __shared__ unsigned short As[128 * 32];
    __shared__ unsigned short Bs[128 * 32];
    const int tid = threadIdx.x;
    const int lane = tid & 63, wid = tid >> 6;
    const int fr = lane & 15, fg = lane >> 4;
    const int wr = wid >> 1, wc = wid & 1;
    const int lin = blockIdx.x;
    const int x = lin & 7, i = lin >> 3;
    const int bxm = (x & 3) * 8 + (i & 7);
    const int byn = (x >> 2) * 4 + (i >> 3);
    const int m0 = bxm * 128, n0 = byn * 128;
    const unsigned short* Ag = Ab + (size_t)m0 * D_MODEL;
    const unsigned short* Bg = Wt + (size_t)n0 * D_MODEL;
    f32x4 acc[4][4] = {};
    for (int kt = 0; kt < D_MODEL; kt += 32) {
        __syncthreads();
        #pragma unroll
        for (int r = 0; r < 2; ++r) {
            int chunk = r * 256 + tid;
            int row = chunk >> 2, col = (chunk & 3) * 8;
            gload16(Ag + (size_t)row * D_MODEL + kt + col, &As[row * 32 + col]);
            gload16(Bg + (size_t)row * D_MODEL + kt + col, &Bs[row * 32 + col]);
        }
        __syncthreads();
        bf16x8 af[4], bfv[4];
        #pragma unroll
        for (int m = 0; m < 4; ++m) af[m] = *(const bf16x8*)&As[(wr * 64 + m * 16 + fr) * 32 + fg * 8];
        #pragma unroll
        for (int n = 0; n < 4; ++n) bfv[n] = *(const bf16x8*)&Bs[(wc * 64 + n * 16 + fr) * 32 + fg * 8];
        #pragma unroll
        for (int m = 0; m < 4; ++m)
            #pragma unroll
            for (int n = 0; n < 4; ++n)
                acc[m][n] = __builtin_amdgcn_mfma_f32_16x16x32_bf16(af[m], bfv[n], acc[m][n], 0, 0, 0);
    }
    #pragma unroll
    for (int n = 0; n < 4; ++n) {
        int gn = n0 + wc * 64 + n * 16 + fr;
        #pragma unroll
        for (int m = 0; m < 4; ++m) {
            #pragma unroll
            for (int r = 0; r < 4; ++r) {
                int gm = m0 + wr * 64 + m * 16 + fg * 4 + r;
                tmp[(size_t)gm * D_MODEL + gn] = acc[m][n][r];
            }
        }
    }
}

// ---------------- flash attention: swapped QK^T (32x32 MFMA), in-register softmax ----------------
// St = mfma(K, Q): lane owns q-col = lane&31; kv rows split across lane halves.
// Row-reduce = 31 local fmax/add + one shfl_xor(32). P stays in registers:
// cvt_pk_bf16 + permlane32_swap rebuild the PV B-operand. O^T = mfma(V^T, P).
__global__ __launch_bounds__(256) void attn_kernel(const unsigned short* __restrict__ Qb,
                                                   const unsigned short* __restrict__ Kb,
                                                   const unsigned short* __restrict__ Vt,
                                                   const unsigned long long* __restrict__ mwords,
                                                   unsigned short* __restrict__ AF) {
    __shared__ unsigned short Ks[2][64 * 64];
    __shared__ unsigned short Vts[2][64 * 64];
    const int tid = threadIdx.x, lane = tid & 63, wid = tid >> 6;
    const int l31 = lane & 31, hi = lane >> 5;
    const int lin = blockIdx.x;
    const int x = lin & 7, i = lin >> 3;
    const int qt = i & 7, bh = x * 8 + (i >> 3);
    const int b = bh >> 4;
    const unsigned short* Qh = Qb + (size_t)bh * SEQ * DH;
    const unsigned short* Kh = Kb + (size_t)bh * SEQ * DH;
    const unsigned short* Vth = Vt + (size_t)bh * DH * SEQ;
    const unsigned long long* mwb = mwords + b * 16;
    const int q0 = qt * 128 + wid * 32;

    const int st_row = wid * 16 + (lane >> 3);
    const int st_col = 8 * ((lane & 7) ^ (lane >> 3));

    // Q B-fragments: lane holds Q[q0+l31][ks*16 + hi*8 + j]
    bf16x8 qf[4];
    #pragma unroll
    for (int ks = 0; ks < 4; ++ks)
        qf[ks] = *(const bf16x8*)(Qh + (size_t)(q0 + l31) * DH + ks * 16 + hi * 8);

    f32x16 oacc0 = {}, oacc1 = {};   // O^T: col q=l31, rows d=(reg&3)+8*(reg>>2)+4*hi (+32 for oacc1)
    float mrun = -3.0e38f, lrun = 0.f;
    const float C2 = 0.18033688f;    // 0.125 * log2(e)

#define SWZ(row, colsh) ((row) * 64 + ((colsh) ^ (((row) & 7) << 3)))
#define STAGE(bufi, kt2)                                                                  \
    {                                                                                     \
        const int kv0s = (kt2) * 64;                                                      \
        _Pragma("unroll")                                                                 \
        for (int j = 0; j < 2; ++j) {                                                     \
            gload16(Kh + (size_t)(kv0s + st_row + j * 8) * DH + st_col,                   \
                    &Ks[bufi][wid * 1024 + j * 512]);                                     \
            gload16(Vth + (size_t)(st_row + j * 8) * SEQ + kv0s + st_col,                 \
                    &Vts[bufi][wid * 1024 + j * 512]);                                    \
        }                                                                                 \
    }

    STAGE(0, 0);
    __syncthreads();
    int buf = 0;
    for (int kt = 0; kt < 16; ++kt) {
        if (kt < 15) STAGE(buf ^ 1, kt + 1);
        const unsigned long long mw = mwb[kt];
        const unsigned mfl0 = (unsigned)(mw >> (4 * hi));
        const unsigned mfl1 = (unsigned)(mw >> (32 + 4 * hi));
        // QK^T
        f32x16 s0 = {}, s1 = {};
        __builtin_amdgcn_s_setprio(1);
        #pragma unroll
        for (int ks = 0; ks < 4; ++ks) {
            bf16x8 kf0 = *(const bf16x8*)&Ks[buf][SWZ(l31, ks * 16 + hi * 8)];
            bf16x8 kf1 = *(const bf16x8*)&Ks[buf][SWZ(32 + l31, ks * 16 + hi * 8)];
            s0 = __builtin_amdgcn_mfma_f32_32x32x16_bf16(kf0, qf[ks], s0, 0, 0, 0);
            s1 = __builtin_amdgcn_mfma_f32_32x32x16_bf16(kf1, qf[ks], s1, 0, 0, 0);
        }
        __builtin_amdgcn_s_setprio(0);
        // row max (lane-local 31 fmax + one cross-half shfl)
        float m = fmaxf(s0[0], s1[0]);
        #pragma unroll
        for (int r2 = 1; r2 < 16; ++r2) m = fmaxf(m, fmaxf(s0[r2], s1[r2]));
        m = fmaxf(m, __shfl_xor(m, 32));
        float mt = m * C2;
        if (!__all(mt <= mrun + 11.5f)) {   // defer-max (T13)
            float newm = fmaxf(mrun, mt);
            float corr = exp2f(mrun - newm);
            lrun *= corr;
            #pragma unroll
            for (int r2 = 0; r2 < 16; ++r2) { oacc0[r2] *= corr; oacc1[r2] *= corr; }
            mrun = newm;
        }
        // P = exp2(s*C2 - mrun), masked entries zeroed; sum
        float ps = 0.f;
        #pragma unroll
        for (int r2 = 0; r2 < 16; ++r2) {
            const int kvb = (r2 & 3) + 8 * (r2 >> 2);
            float p0 = exp2f(fmaf(s0[r2], C2, -mrun));
            float p1 = exp2f(fmaf(s1[r2], C2, -mrun));
            p0 = ((mfl0 >> kvb) & 1) ? 0.f : p0;
            p1 = ((mfl1 >> kvb) & 1) ? 0.f : p1;
            s0[r2] = p0; s1[r2] = p1;
            ps += p0 + p1;
        }
        ps += __shfl_xor(ps, 32);
        lrun += ps;
        // P (f32, C/D layout) -> bf16 B-operand fragments via cvt_pk + permlane32_swap
        unsigned c0[8], c1[8];
        #pragma unroll
        for (int ii = 0; ii < 8; ++ii) {
            asm volatile("v_cvt_pk_bf16_f32 %0, %1, %2" : "=v"(c0[ii]) : "v"(s0[2 * ii]), "v"(s0[2 * ii + 1]));
            asm volatile("v_cvt_pk_bf16_f32 %0, %1, %2" : "=v"(c1[ii]) : "v"(s1[2 * ii]), "v"(s1[2 * ii + 1]));
        }
        #pragma unroll
        for (int g = 0; g < 8; g += 4) {
            asm volatile("v_permlane32_swap_b32 %0, %1" : "+v"(c0[g + 0]), "+v"(c0[g + 2]));
            asm volatile("v_permlane32_swap_b32 %0, %1" : "+v"(c0[g + 1]), "+v"(c0[g + 3]));
            asm volatile("v_permlane32_swap_b32 %0, %1" : "+v"(c1[g + 0]), "+v"(c1[g + 2]));
            asm volatile("v_permlane32_swap_b32 %0, %1" : "+v"(c1[g + 1]), "+v"(c1[g + 3]));
        }
        // PV: oacc_df = mfma(V^T rows, P) ; B-frag ks: {c[4*(ks&1)] .. +3} of c0 (ks<2) / c1
        __builtin_amdgcn_s_setprio(1);
        #pragma unroll
        for (int ks = 0; ks < 4; ++ks) {
            union { unsigned u[4]; bf16x8 v; } pb;
            if (ks < 2) {
                pb.u[0] = c0[(ks & 1) * 4 + 0]; pb.u[1] = c0[(ks & 1) * 4 + 1];
                pb.u[2] = c0[(ks & 1) * 4 + 2]; pb.u[3] = c0[(ks & 1) * 4 + 3];
            } else {
                pb.u[0] = c1[(ks & 1) * 4 + 0]; pb.u[1] = c1[(ks & 1) * 4 + 1];
                pb.u[2] = c1[(ks & 1) * 4 + 2]; pb.u[3] = c1[(ks & 1) * 4 + 3];
            }
            bf16x8 vf0 = *(const bf16x8*)&Vts[buf][SWZ(l31, ks * 16 + hi * 8)];
            bf16x8 vf1 = *(const bf16x8*)&Vts[buf][SWZ(32 + l31, ks * 16 + hi * 8)];
            oacc0 = __builtin_amdgcn_mfma_f32_32x32x16_bf16(vf0, pb.v, oacc0, 0, 0, 0);
            oacc1 = __builtin_amdgcn_mfma_f32_32x32x16_bf16(vf1, pb.v, oacc1, 0, 0, 0);
        }
        __builtin_amdgcn_s_setprio(0);
        __syncthreads();
        buf ^= 1;
    }
#undef STAGE
#undef SWZ
    // epilogue: O^T[d][q], lane q = l31; faithful-to-torch head scramble
    const float rl = 1.f / lrun;
    const int b2 = bh & 3, h2 = bh >> 2;
    const size_t rowbase = ((size_t)b2 * SEQ + q0 + l31) * D_MODEL + h2 * 64 + 4 * hi;
    #pragma unroll
    for (int df = 0; df < 2; ++df) {
        const f32x16& oa = df ? oacc1 : oacc0;
        #pragma unroll
        for (int rg = 0; rg < 4; ++rg) {
            ushort4 pk;
            pk.x = f2bf(oa[rg * 4 + 0] * rl);
            pk.y = f2bf(oa[rg * 4 + 1] * rl);
            pk.z = f2bf(oa[rg * 4 + 2] * rl);
            pk.w = f2bf(oa[rg * 4 + 3] * rl);
            *(ushort4*)&AF[rowbase + 32 * df + 8 * rg] = pk;
        }
    }
}

// ---------------- residual + LayerNorm ----------------
__global__ __launch_bounds__(256) void ln_kernel(const float* __restrict__ tmp,
                                                 const float* __restrict__ inp,
                                                 const float* __restrict__ g,
                                                 const float* __restrict__ bb,
                                                 float* __restrict__ out) {
    __shared__ float red[8];
    const int row = blockIdx.x, tid = threadIdx.x;
    float4 t = ((const float4*)(tmp + (size_t)row * D_MODEL))[tid];
    float4 rr = ((const float4*)(inp + (size_t)row * D_MODEL))[tid];
    float4 y;
    y.x = t.x + rr.x; y.y = t.y + rr.y; y.z = t.z + rr.z; y.w = t.w + rr.w;
    float sum = y.x + y.y + y.z + y.w;
    float sq = y.x * y.x + y.y * y.y + y.z * y.z + y.w * y.w;
    #pragma unroll
    for (int o = 1; o < 64; o <<= 1) { sum += __shfl_xor(sum, o); sq += __shfl_xor(sq, o); }
    int wid = tid >> 6, lane = tid & 63;
    if (lane == 0) { red[wid] = sum; red[4 + wid] = sq; }
    __syncthreads();
    sum = red[0] + red[1] + red[2] + red[3];
    sq = red[4] + red[5] + red[6] + red[7];
    float mu = sum * (1.f / D_MODEL);
    float var = sq * (1.f / D_MODEL) - mu * mu;
    float rs = rsqrtf(var + 1e-5f);
    float4 gg = ((const float4*)g)[tid];
    float4 bv = ((const float4*)bb)[tid];
    float4 o4;
    o4.x = (y.x - mu) * rs * gg.x + bv.x;
    o4.y = (y.y - mu) * rs * gg.y + bv.y;
    o4.z = (y.z - mu) * rs * gg.z + bv.z;
    o4.w = (y.w - mu) * rs * gg.w + bv.w;
    ((float4*)(out + (size_t)row * D_MODEL))[tid] = o4;
}

extern "C" void kernel_launch(void* const* d_in, const int* in_sizes, int n_in,
                              void* d_out, int out_size, void* d_ws, size_t ws_size,
                              hipStream_t stream) {
    const float* inp = (const float*)d_in[0];
    const int* amask = (const int*)d_in[1];
    const float* Wq = (const float*)d_in[2];
    const float* bq = (const float*)d_in[3];
    const float* Wk = (const float*)d_in[4];
    const float* bk = (const float*)d_in[5];
    const float* Wv = (const float*)d_in[6];
    const float* bv = (const float*)d_in[7];
    const float* Wo = (const float*)d_in[8];
    const float* lg = (const float*)d_in[9];
    const float* lb = (const float*)d_in[10];
    float* out = (float*)d_out;
    char* ws = (char*)d_ws;

    unsigned short* Xb     = (unsigned short*)(ws + 0);          //  8.0 MiB
    unsigned short* Wqkv_t = (unsigned short*)(ws + 8388608);    //  6.0 MiB
    unsigned short* Wo_t   = (unsigned short*)(ws + 14680064);   //  2.0 MiB
    unsigned short* Qb     = (unsigned short*)(ws + 16777216);   //  8.0 MiB
    unsigned short* Kb     = (unsigned short*)(ws + 25165824);   //  8.0 MiB
    unsigned short* Vt     = (unsigned short*)(ws + 33554432);   //  8.0 MiB  (V^T: [bh][d][s])
    unsigned short* AF     = (unsigned short*)(ws + 41943040);   //  8.0 MiB
    float*          tmp    = (float*)(ws + 50331648);            // 16.0 MiB
    // mwords aliases the tmp region (dead until gemm_o, which runs after attn)
    unsigned long long* mwords = (unsigned long long*)(ws + 50331648);

    cvt_x<<<4096, 256, 0, stream>>>(inp, Xb);
    pack_mask<<<1, 64, 0, stream>>>(amask, mwords);
    transpose_w<<<dim3(32, 32, 4), dim3(32, 8), 0, stream>>>(Wq, Wk, Wv, Wo, Wqkv_t, Wo_t);
    gemm_qkv<<<768, 256, 0, stream>>>(Xb, Wqkv_t, bq, bk, bv, Qb, Kb, Vt);
    attn_kernel<<<512, 256, 0, stream>>>(Qb, Kb, Vt, mwords, AF);
    gemm_o<<<256, 256, 0, stream>>>(AF, Wo_t, tmp);
    ln_kernel<<<4096, 256, 0, stream>>>(tmp, inp, lg, lb, out);
}

// Round 6
// 137.685 us; speedup vs baseline: 1.3892x; 1.0207x over previous
//
#include <hip/hip_runtime.h>

typedef __attribute__((ext_vector_type(8))) short bf16x8;
typedef __attribute__((ext_vector_type(4))) float f32x4;
typedef __attribute__((ext_vector_type(16))) float f32x16;

#define D_MODEL 1024
#define SEQ 1024
#define NB 4
#define NH 16
#define DH 64
#define MROWS 4096

__device__ __forceinline__ unsigned short f2bf(float f) {
    union { float f; unsigned u; } x; x.f = f;
    unsigned r = x.u + 0x7fffu + ((x.u >> 16) & 1u);
    return (unsigned short)(r >> 16);
}

__device__ __forceinline__ void gload16(const void* g, void* l) {
    __builtin_amdgcn_global_load_lds((const __attribute__((address_space(1))) void*)g,
                                     (__attribute__((address_space(3))) void*)l, 16, 0, 0);
}

// exchange value with lane^32 via permlane32_swap (VALU-only, no LDS)
__device__ __forceinline__ float xhalf(float x, int hi) {
    float a = x, b = x;
    asm volatile("v_permlane32_swap_b32 %0, %1" : "+v"(a), "+v"(b));
    return hi ? b : a;   // lanes<32: other half in a; lanes>=32: in b
}

// ---------------- convert inp f32 -> bf16 ----------------
__global__ __launch_bounds__(256) void cvt_x(const float* __restrict__ x,
                                             unsigned short* __restrict__ o) {
    int i = blockIdx.x * 256 + threadIdx.x;
    float4 v = ((const float4*)x)[i];
    ushort4 r;
    r.x = f2bf(v.x); r.y = f2bf(v.y); r.z = f2bf(v.z); r.w = f2bf(v.w);
    ((ushort4*)o)[i] = r;
}

// ---------------- pack attn_mask -> 64-bit words per (b, 64-kv tile) ----------------
__global__ __launch_bounds__(64) void pack_mask(const int* __restrict__ amask,
                                                unsigned long long* __restrict__ mwords) {
    int t = threadIdx.x;           // 0..63
    int b = t >> 4, kt = t & 15;
    const int* src = amask + b * SEQ + kt * 64;
    unsigned long long w = 0;
    for (int j = 0; j < 64; ++j)
        w |= (unsigned long long)(src[j] != 0 ? 1 : 0) << j;
    mwords[t] = w;
}

// ---------------- transpose W (f32) -> bf16 W^T ----------------
__global__ __launch_bounds__(256) void transpose_w(const float* __restrict__ Wq,
                                                   const float* __restrict__ Wk,
                                                   const float* __restrict__ Wv,
                                                   const float* __restrict__ Wo,
                                                   unsigned short* __restrict__ Wqkv_t,
                                                   unsigned short* __restrict__ Wo_t) {
    __shared__ float tile[32][33];
    const int mtx = blockIdx.z;
    const float* src = mtx == 0 ? Wq : mtx == 1 ? Wk : mtx == 2 ? Wv : Wo;
    unsigned short* dst = mtx < 3 ? (Wqkv_t + (size_t)mtx * D_MODEL * D_MODEL) : Wo_t;
    const int n0 = blockIdx.x * 32, k0 = blockIdx.y * 32;
    const int tx = threadIdx.x, ty = threadIdx.y;
    #pragma unroll
    for (int i = 0; i < 32; i += 8)
        tile[ty + i][tx] = src[(size_t)(k0 + ty + i) * D_MODEL + n0 + tx];
    __syncthreads();
    #pragma unroll
    for (int i = 0; i < 32; i += 8)
        dst[(size_t)(n0 + ty + i) * D_MODEL + k0 + tx] = f2bf(tile[tx][ty + i]);
}

// ---------------- QKV GEMM: Xb[4096][1024] @ Wqkv_t^T -> Q,K [bh][s][64], V^T [bh][64][s] ----------------
__global__ __launch_bounds__(256) void gemm_qkv(const unsigned short* __restrict__ Xb,
                                                const unsigned short* __restrict__ Wt,
                                                const float* __restrict__ bq,
                                                const float* __restrict__ bk,
                                                const float* __restrict__ bv,
                                                unsigned short* __restrict__ Qb,
                                                unsigned short* __restrict__ Kb,
                                                unsigned short* __restrict__ Vt) {
    __shared__ unsigned short As[128 * 32];
    __shared__ unsigned short Bs[128 * 32];
    __shared__ unsigned short Cs[128 * 136];
    const int tid = threadIdx.x;
    const int lane = tid & 63, wid = tid >> 6;
    const int fr = lane & 15, fg = lane >> 4;
    const int wr = wid >> 1, wc = wid & 1;
    const int lin = blockIdx.x;
    const int x = lin & 7, i = lin >> 3;
    const int bxm = (x & 3) * 8 + (i & 7);
    const int byn = (x >> 2) * 12 + (i >> 3);
    const int m0 = bxm * 128, n0 = byn * 128;
    const unsigned short* Ag = Xb + (size_t)m0 * D_MODEL;
    const unsigned short* Bg = Wt + (size_t)n0 * D_MODEL;
    f32x4 acc[4][4] = {};
    for (int kt = 0; kt < D_MODEL; kt += 32) {
        __syncthreads();
        #pragma unroll
        for (int r = 0; r < 2; ++r) {
            int chunk = r * 256 + tid;
            int row = chunk >> 2, col = (chunk & 3) * 8;
            gload16(Ag + (size_t)row * D_MODEL + kt + col, &As[row * 32 + col]);
            gload16(Bg + (size_t)row * D_MODEL + kt + col, &Bs[row * 32 + col]);
        }
        __syncthreads();
        bf16x8 af[4], bfv[4];
        #pragma unroll
        for (int m = 0; m < 4; ++m) af[m] = *(const bf16x8*)&As[(wr * 64 + m * 16 + fr) * 32 + fg * 8];
        #pragma unroll
        for (int n = 0; n < 4; ++n) bfv[n] = *(const bf16x8*)&Bs[(wc * 64 + n * 16 + fr) * 32 + fg * 8];
        #pragma unroll
        for (int m = 0; m < 4; ++m)
            #pragma unroll
            for (int n = 0; n < 4; ++n)
                acc[m][n] = __builtin_amdgcn_mfma_f32_16x16x32_bf16(af[m], bfv[n], acc[m][n], 0, 0, 0);
    }
    const int sel = n0 >> 10;
    const int npb = n0 & 1023;
    if (sel < 2) {
        #pragma unroll
        for (int n = 0; n < 4; ++n) {
            int cn = wc * 64 + n * 16 + fr;
            float bias = (sel == 0 ? bq : bk)[npb + cn];
            #pragma unroll
            for (int m = 0; m < 4; ++m)
                #pragma unroll
                for (int r = 0; r < 4; ++r)
                    Cs[(wr * 64 + m * 16 + fg * 4 + r) * 136 + cn] = f2bf(acc[m][n][r] + bias);
        }
        __syncthreads();
        unsigned short* dst = sel == 0 ? Qb : Kb;
        #pragma unroll
        for (int k = 0; k < 8; ++k) {
            int c = k * 256 + tid;
            int row = c >> 4, cc = c & 15;
            int np = npb + cc * 8;
            int h = np >> 6, d = np & 63;
            int gm = m0 + row, b = gm >> 10, s = gm & 1023;
            bf16x8 v = *(const bf16x8*)&Cs[row * 136 + cc * 8];
            *(bf16x8*)&dst[((size_t)(b * NH + h) * SEQ + s) * DH + d] = v;
        }
    } else {
        #pragma unroll
        for (int n = 0; n < 4; ++n) {
            int cn = wc * 64 + n * 16 + fr;
            float bias = bv[npb + cn];
            #pragma unroll
            for (int m = 0; m < 4; ++m)
                #pragma unroll
                for (int r = 0; r < 4; ++r)
                    Cs[cn * 136 + (wr * 64 + m * 16 + fg * 4 + r)] = f2bf(acc[m][n][r] + bias);
        }
        __syncthreads();
        #pragma unroll
        for (int k = 0; k < 8; ++k) {
            int c = k * 256 + tid;
            int dcol = c >> 4, scc = c & 15;
            int np = npb + dcol;
            int h = np >> 6, dd = np & 63;
            int gm0 = m0 + scc * 8, b = gm0 >> 10, s0 = gm0 & 1023;
            bf16x8 v = *(const bf16x8*)&Cs[dcol * 136 + scc * 8];
            *(bf16x8*)&Vt[((size_t)(b * NH + h) * DH + dd) * SEQ + s0] = v;
        }
    }
}

// ---------------- O-proj GEMM ----------------
__global__ __launch_bounds__(256) void gemm_o(const unsigned short* __restrict__ Ab,
                                              const unsigned short* __restrict__ Wt,
                                              float* __restrict__ tmp) {
    __shared__ unsigned short As[128 * 32];
    __shared__ unsigned short Bs[128 * 32];
    const int tid = threadIdx.x;
    const int lane = tid & 63, wid = tid >> 6;
    const int fr = lane & 15, fg = lane >> 4;
    const int wr = wid >> 1, wc = wid & 1;
    const int lin = blockIdx.x;
    const int x = lin & 7, i = lin >> 3;
    const int bxm = (x & 3) * 8 + (i & 7);
    const int byn = (x >> 2) * 4 + (i >> 3);
    const int m0 = bxm * 128, n0 = byn * 128;
    const unsigned short* Ag = Ab + (size_t)m0 * D_MODEL;
    const unsigned short* Bg = Wt + (size_t)n0 * D_MODEL;
    f32x4 acc[4][4] = {};
    for (int kt = 0; kt < D_MODEL; kt += 32) {
        __syncthreads();
        #pragma unroll
        for (int r = 0; r < 2; ++r) {
            int chunk = r * 256 + tid;
            int row = chunk >> 2, col = (chunk & 3) * 8;
            gload16(Ag + (size_t)row * D_MODEL + kt + col, &As[row * 32 + col]);
            gload16(Bg + (size_t)row * D_MODEL + kt + col, &Bs[row * 32 + col]);
        }
        __syncthreads();
        bf16x8 af[4], bfv[4];
        #pragma unroll
        for (int m = 0; m < 4; ++m) af[m] = *(const bf16x8*)&As[(wr * 64 + m * 16 + fr) * 32 + fg * 8];
        #pragma unroll
        for (int n = 0; n < 4; ++n) bfv[n] = *(const bf16x8*)&Bs[(wc * 64 + n * 16 + fr) * 32 + fg * 8];
        #pragma unroll
        for (int m = 0; m < 4; ++m)
            #pragma unroll
            for (int n = 0; n < 4; ++n)
                acc[m][n] = __builtin_amdgcn_mfma_f32_16x16x32_bf16(af[m], bfv[n], acc[m][n], 0, 0, 0);
    }
    #pragma unroll
    for (int n = 0; n < 4; ++n) {
        int gn = n0 + wc * 64 + n * 16 + fr;
        #pragma unroll
        for (int m = 0; m < 4; ++m) {
            #pragma unroll
            for (int r = 0; r < 4; ++r) {
                int gm = m0 + wr * 64 + m * 16 + fg * 4 + r;
                tmp[(size_t)gm * D_MODEL + gn] = acc[m][n][r];
            }
        }
    }
}

// ---------------- flash attention: KVBLK=128, joint in-register softmax, tree reductions ----------------
// St = mfma(K, Q) (32x32x16): lane owns q-col l31; 128 kv rows in 4 frags (A0,A1,B0,B1).
// One joint softmax per 128 kv: tree max/sum + permlane32 cross-half exchange.
// P stays in regs (cvt_pk + permlane32_swap); O^T = mfma(V^T, P).
__global__ __launch_bounds__(256, 2) void attn_kernel(const unsigned short* __restrict__ Qb,
                                                      const unsigned short* __restrict__ Kb,
                                                      const unsigned short* __restrict__ Vt,
                                                      const unsigned long long* __restrict__ mwords,
                                                      unsigned short* __restrict__ AF) {
    __shared__ unsigned short Ks[2][128 * 64];   // [kv][d]
    __shared__ unsigned short Vts[2][64 * 128];  // [d][kv]
    const int tid = threadIdx.x, lane = tid & 63, wid = tid >> 6;
    const int l31 = lane & 31, hi = lane >> 5;
    const int lin = blockIdx.x;
    const int x = lin & 7, i = lin >> 3;
    const int qt = i & 7, bh = x * 8 + (i >> 3);
    const int b = bh >> 4;
    const unsigned short* Qh = Qb + (size_t)bh * SEQ * DH;
    const unsigned short* Kh = Kb + (size_t)bh * SEQ * DH;
    const unsigned short* Vth = Vt + (size_t)bh * DH * SEQ;
    const unsigned long long* mwb = mwords + b * 16;
    const int q0 = qt * 128 + wid * 32;

    // staging coords (inverse-swizzled sources, linear LDS dests)
    const int k_row = wid * 32 + (lane >> 3);                 // + j*8   (K rows: kv)
    const int k_col = 8 * ((lane & 7) ^ ((lane >> 3) & 7));
    const int v_rowb = wid * 16 + (lane >> 4);                // + j*4   (V rows: d)

    bf16x8 qf[4];
    #pragma unroll
    for (int ks = 0; ks < 4; ++ks)
        qf[ks] = *(const bf16x8*)(Qh + (size_t)(q0 + l31) * DH + ks * 16 + hi * 8);

    f32x16 oacc0 = {}, oacc1 = {};   // O^T: col q=l31, rows d=(reg&3)+8*(reg>>2)+4*hi (+32 for oacc1)
    float mrun = -3.0e38f, lrun = 0.f;
    const float C2 = 0.18033688f;    // 0.125 * log2(e)

#define KSWZ(row, colsh) ((row) * 64 + ((colsh) ^ (((row) & 7) << 3)))
#define VSWZ(row, colsh) ((row) * 128 + ((colsh) ^ (((row) & 7) << 3)))
#define STAGE(bufi, kt2)                                                                  \
    {                                                                                     \
        const int kv0s = (kt2) * 128;                                                     \
        _Pragma("unroll")                                                                 \
        for (int j = 0; j < 4; ++j)                                                       \
            gload16(Kh + (size_t)(kv0s + k_row + j * 8) * DH + k_col,                     \
                    &Ks[bufi][wid * 2048 + j * 512]);                                     \
        _Pragma("unroll")                                                                 \
        for (int j = 0; j < 4; ++j) {                                                     \
            const int vr = v_rowb + j * 4;                                                \
            gload16(Vth + (size_t)vr * SEQ + kv0s + 8 * ((lane & 15) ^ (vr & 7)),         \
                    &Vts[bufi][wid * 2048 + j * 512]);                                    \
        }                                                                                 \
    }

    STAGE(0, 0);
    __syncthreads();
    int buf = 0;
    for (int kt = 0; kt < 8; ++kt) {
        if (kt < 7) STAGE(buf ^ 1, kt + 1);
        const unsigned long long mwA = mwb[2 * kt], mwB = mwb[2 * kt + 1];
        const unsigned mflA0 = (unsigned)(mwA >> (4 * hi));
        const unsigned mflA1 = (unsigned)(mwA >> (32 + 4 * hi));
        const unsigned mflB0 = (unsigned)(mwB >> (4 * hi));
        const unsigned mflB1 = (unsigned)(mwB >> (32 + 4 * hi));
        // QK^T over 128 kv rows
        f32x16 sA0 = {}, sA1 = {}, sB0 = {}, sB1 = {};
        __builtin_amdgcn_s_setprio(1);
        #pragma unroll
        for (int ks = 0; ks < 4; ++ks) {
            const int ch = ks * 16 + hi * 8;
            bf16x8 k0 = *(const bf16x8*)&Ks[buf][KSWZ(l31, ch)];
            bf16x8 k1 = *(const bf16x8*)&Ks[buf][KSWZ(32 + l31, ch)];
            bf16x8 k2 = *(const bf16x8*)&Ks[buf][KSWZ(64 + l31, ch)];
            bf16x8 k3 = *(const bf16x8*)&Ks[buf][KSWZ(96 + l31, ch)];
            sA0 = __builtin_amdgcn_mfma_f32_32x32x16_bf16(k0, qf[ks], sA0, 0, 0, 0);
            sA1 = __builtin_amdgcn_mfma_f32_32x32x16_bf16(k1, qf[ks], sA1, 0, 0, 0);
            sB0 = __builtin_amdgcn_mfma_f32_32x32x16_bf16(k2, qf[ks], sB0, 0, 0, 0);
            sB1 = __builtin_amdgcn_mfma_f32_32x32x16_bf16(k3, qf[ks], sB1, 0, 0, 0);
        }
        __builtin_amdgcn_s_setprio(0);
        // joint row-max over 128 kv: pairwise tree + one cross-half exchange
        float tm[16];
        #pragma unroll
        for (int r2 = 0; r2 < 16; ++r2)
            tm[r2] = fmaxf(fmaxf(sA0[r2], sA1[r2]), fmaxf(sB0[r2], sB1[r2]));
        #pragma unroll
        for (int st = 8; st; st >>= 1)
            #pragma unroll
            for (int r2 = 0; r2 < st; ++r2)
                tm[r2] = fmaxf(tm[r2], tm[r2 + st]);
        float m = tm[0];
        m = fmaxf(m, xhalf(m, hi));
        float mt = m * C2;
        if (!__all(mt <= mrun + 11.5f)) {   // defer-max (T13)
            float newm = fmaxf(mrun, mt);
            float corr = exp2f(mrun - newm);
            lrun *= corr;
            #pragma unroll
            for (int r2 = 0; r2 < 16; ++r2) { oacc0[r2] *= corr; oacc1[r2] *= corr; }
            mrun = newm;
        }
        // P = exp2(s*C2 - mrun), masked -> 0; tree sum
        float ts[16];
        #pragma unroll
        for (int r2 = 0; r2 < 16; ++r2) {
            const int kvb = (r2 & 3) + 8 * (r2 >> 2);
            float pA0 = exp2f(fmaf(sA0[r2], C2, -mrun));
            float pA1 = exp2f(fmaf(sA1[r2], C2, -mrun));
            float pB0 = exp2f(fmaf(sB0[r2], C2, -mrun));
            float pB1 = exp2f(fmaf(sB1[r2], C2, -mrun));
            pA0 = ((mflA0 >> kvb) & 1) ? 0.f : pA0;
            pA1 = ((mflA1 >> kvb) & 1) ? 0.f : pA1;
            pB0 = ((mflB0 >> kvb) & 1) ? 0.f : pB0;
            pB1 = ((mflB1 >> kvb) & 1) ? 0.f : pB1;
            sA0[r2] = pA0; sA1[r2] = pA1; sB0[r2] = pB0; sB1[r2] = pB1;
            ts[r2] = (pA0 + pA1) + (pB0 + pB1);
        }
        #pragma unroll
        for (int st = 8; st; st >>= 1)
            #pragma unroll
            for (int r2 = 0; r2 < st; ++r2)
                ts[r2] += ts[r2 + st];
        float ps = ts[0];
        ps += xhalf(ps, hi);
        lrun += ps;
        // P -> bf16 B-operand fragments (cvt_pk + permlane32_swap), per 32-kv group
        unsigned cA0[8], cA1[8], cB0[8], cB1[8];
        #pragma unroll
        for (int ii = 0; ii < 8; ++ii) {
            asm volatile("v_cvt_pk_bf16_f32 %0, %1, %2" : "=v"(cA0[ii]) : "v"(sA0[2 * ii]), "v"(sA0[2 * ii + 1]));
            asm volatile("v_cvt_pk_bf16_f32 %0, %1, %2" : "=v"(cA1[ii]) : "v"(sA1[2 * ii]), "v"(sA1[2 * ii + 1]));
            asm volatile("v_cvt_pk_bf16_f32 %0, %1, %2" : "=v"(cB0[ii]) : "v"(sB0[2 * ii]), "v"(sB0[2 * ii + 1]));
            asm volatile("v_cvt_pk_bf16_f32 %0, %1, %2" : "=v"(cB1[ii]) : "v"(sB1[2 * ii]), "v"(sB1[2 * ii + 1]));
        }
        #pragma unroll
        for (int g = 0; g < 8; g += 4) {
            asm volatile("v_permlane32_swap_b32 %0, %1" : "+v"(cA0[g + 0]), "+v"(cA0[g + 2]));
            asm volatile("v_permlane32_swap_b32 %0, %1" : "+v"(cA0[g + 1]), "+v"(cA0[g + 3]));
            asm volatile("v_permlane32_swap_b32 %0, %1" : "+v"(cA1[g + 0]), "+v"(cA1[g + 2]));
            asm volatile("v_permlane32_swap_b32 %0, %1" : "+v"(cA1[g + 1]), "+v"(cA1[g + 3]));
            asm volatile("v_permlane32_swap_b32 %0, %1" : "+v"(cB0[g + 0]), "+v"(cB0[g + 2]));
            asm volatile("v_permlane32_swap_b32 %0, %1" : "+v"(cB0[g + 1]), "+v"(cB0[g + 3]));
            asm volatile("v_permlane32_swap_b32 %0, %1" : "+v"(cB1[g + 0]), "+v"(cB1[g + 2]));
            asm volatile("v_permlane32_swap_b32 %0, %1" : "+v"(cB1[g + 1]), "+v"(cB1[g + 3]));
        }
        // PV: 8 k-steps of 16 kv; frag t from {cA0,cA0+4,cA1,cA1+4,cB0,cB0+4,cB1,cB1+4}
        __builtin_amdgcn_s_setprio(1);
        #pragma unroll
        for (int t = 0; t < 8; ++t) {
            const unsigned* cp = (t < 2) ? cA0 : (t < 4) ? cA1 : (t < 6) ? cB0 : cB1;
            const int g = (t & 1) * 4;
            union { unsigned u[4]; bf16x8 v; } pb;
            pb.u[0] = cp[g + 0]; pb.u[1] = cp[g + 1]; pb.u[2] = cp[g + 2]; pb.u[3] = cp[g + 3];
            const int ch = t * 16 + hi * 8;
            bf16x8 vf0 = *(const bf16x8*)&Vts[buf][VSWZ(l31, ch)];
            bf16x8 vf1 = *(const bf16x8*)&Vts[buf][VSWZ(32 + l31, ch)];
            oacc0 = __builtin_amdgcn_mfma_f32_32x32x16_bf16(vf0, pb.v, oacc0, 0, 0, 0);
            oacc1 = __builtin_amdgcn_mfma_f32_32x32x16_bf16(vf1, pb.v, oacc1, 0, 0, 0);
        }
        __builtin_amdgcn_s_setprio(0);
        __syncthreads();
        buf ^= 1;
    }
#undef STAGE
#undef KSWZ
#undef VSWZ
    // epilogue: O^T[d][q], lane q = l31; faithful-to-torch head scramble
    const float rl = 1.f / lrun;
    const int b2 = bh & 3, h2 = bh >> 2;
    const size_t rowbase = ((size_t)b2 * SEQ + q0 + l31) * D_MODEL + h2 * 64 + 4 * hi;
    #pragma unroll
    for (int df = 0; df < 2; ++df) {
        const f32x16& oa = df ? oacc1 : oacc0;
        #pragma unroll
        for (int rg = 0; rg < 4; ++rg) {
            ushort4 pk;
            pk.x = f2bf(oa[rg * 4 + 0] * rl);
            pk.y = f2bf(oa[rg * 4 + 1] * rl);
            pk.z = f2bf(oa[rg * 4 + 2] * rl);
            pk.w = f2bf(oa[rg * 4 + 3] * rl);
            *(ushort4*)&AF[rowbase + 32 * df + 8 * rg] = pk;
        }
    }
}

// ---------------- residual + LayerNorm ----------------
__global__ __launch_bounds__(256) void ln_kernel(const float* __restrict__ tmp,
                                                 const float* __restrict__ inp,
                                                 const float* __restrict__ g,
                                                 const float* __restrict__ bb,
                                                 float* __restrict__ out) {
    __shared__ float red[8];
    const int row = blockIdx.x, tid = threadIdx.x;
    float4 t = ((const float4*)(tmp + (size_t)row * D_MODEL))[tid];
    float4 rr = ((const float4*)(inp + (size_t)row * D_MODEL))[tid];
    float4 y;
    y.x = t.x + rr.x; y.y = t.y + rr.y; y.z = t.z + rr.z; y.w = t.w + rr.w;
    float sum = y.x + y.y + y.z + y.w;
    float sq = y.x * y.x + y.y * y.y + y.z * y.z + y.w * y.w;
    #pragma unroll
    for (int o = 1; o < 64; o <<= 1) { sum += __shfl_xor(sum, o); sq += __shfl_xor(sq, o); }
    int wid = tid >> 6, lane = tid & 63;
    if (lane == 0) { red[wid] = sum; red[4 + wid] = sq; }
    __syncthreads();
    sum = red[0] + red[1] + red[2] + red[3];
    sq = red[4] + red[5] + red[6] + red[7];
    float mu = sum * (1.f / D_MODEL);
    float var = sq * (1.f / D_MODEL) - mu * mu;
    float rs = rsqrtf(var + 1e-5f);
    float4 gg = ((const float4*)g)[tid];
    float4 bv = ((const float4*)bb)[tid];
    float4 o4;
    o4.x = (y.x - mu) * rs * gg.x + bv.x;
    o4.y = (y.y - mu) * rs * gg.y + bv.y;
    o4.z = (y.z - mu) * rs * gg.z + bv.z;
    o4.w = (y.w - mu) * rs * gg.w + bv.w;
    ((float4*)(out + (size_t)row * D_MODEL))[tid] = o4;
}

extern "C" void kernel_launch(void* const* d_in, const int* in_sizes, int n_in,
                              void* d_out, int out_size, void* d_ws, size_t ws_size,
                              hipStream_t stream) {
    const float* inp = (const float*)d_in[0];
    const int* amask = (const int*)d_in[1];
    const float* Wq = (const float*)d_in[2];
    const float* bq = (const float*)d_in[3];
    const float* Wk = (const float*)d_in[4];
    const float* bk = (const float*)d_in[5];
    const float* Wv = (const float*)d_in[6];
    const float* bv = (const float*)d_in[7];
    const float* Wo = (const float*)d_in[8];
    const float* lg = (const float*)d_in[9];
    const float* lb = (const float*)d_in[10];
    float* out = (float*)d_out;
    char* ws = (char*)d_ws;

    unsigned short* Xb     = (unsigned short*)(ws + 0);          //  8.0 MiB
    unsigned short* Wqkv_t = (unsigned short*)(ws + 8388608);    //  6.0 MiB
    unsigned short* Wo_t   = (unsigned short*)(ws + 14680064);   //  2.0 MiB
    unsigned short* Qb     = (unsigned short*)(ws + 16777216);   //  8.0 MiB
    unsigned short* Kb     = (unsigned short*)(ws + 25165824);   //  8.0 MiB
    unsigned short* Vt     = (unsigned short*)(ws + 33554432);   //  8.0 MiB  (V^T: [bh][d][s])
    unsigned short* AF     = (unsigned short*)(ws + 41943040);   //  8.0 MiB
    float*          tmp    = (float*)(ws + 50331648);            // 16.0 MiB
    unsigned long long* mwords = (unsigned long long*)(ws + 50331648);  // aliases tmp (dead until gemm_o)

    cvt_x<<<4096, 256, 0, stream>>>(inp, Xb);
    pack_mask<<<1, 64, 0, stream>>>(amask, mwords);
    transpose_w<<<dim3(32, 32, 4), dim3(32, 8), 0, stream>>>(Wq, Wk, Wv, Wo, Wqkv_t, Wo_t);
    gemm_qkv<<<768, 256, 0, stream>>>(Xb, Wqkv_t, bq, bk, bv, Qb, Kb, Vt);
    attn_kernel<<<512, 256, 0, stream>>>(Qb, Kb, Vt, mwords, AF);
    gemm_o<<<256, 256, 0, stream>>>(AF, Wo_t, tmp);
    ln_kernel<<<4096, 256, 0, stream>>>(tmp, inp, lg, lb, out);
}

// Round 7
// 131.971 us; speedup vs baseline: 1.4493x; 1.0433x over previous
//
#include <hip/hip_runtime.h>

typedef __attribute__((ext_vector_type(8))) short bf16x8;
typedef __attribute__((ext_vector_type(4))) float f32x4;
typedef __attribute__((ext_vector_type(16))) float f32x16;

#define D_MODEL 1024
#define SEQ 1024
#define NB 4
#define NH 16
#define DH 64
#define MROWS 4096

__device__ __forceinline__ unsigned short f2bf(float f) {
    union { float f; unsigned u; } x; x.f = f;
    unsigned r = x.u + 0x7fffu + ((x.u >> 16) & 1u);
    return (unsigned short)(r >> 16);
}

__device__ __forceinline__ void gload16(const void* g, void* l) {
    __builtin_amdgcn_global_load_lds((const __attribute__((address_space(1))) void*)g,
                                     (__attribute__((address_space(3))) void*)l, 16, 0, 0);
}

// exchange value with lane^32 via permlane32_swap (VALU-only, no LDS)
__device__ __forceinline__ float xhalf(float x, int hi) {
    float a = x, b = x;
    asm volatile("v_permlane32_swap_b32 %0, %1" : "+v"(a), "+v"(b));
    return hi ? b : a;
}

// ---------------- convert inp f32 -> bf16 ----------------
__global__ __launch_bounds__(256) void cvt_x(const float* __restrict__ x,
                                             unsigned short* __restrict__ o) {
    int i = blockIdx.x * 256 + threadIdx.x;
    float4 v = ((const float4*)x)[i];
    ushort4 r;
    r.x = f2bf(v.x); r.y = f2bf(v.y); r.z = f2bf(v.z); r.w = f2bf(v.w);
    ((ushort4*)o)[i] = r;
}

// ---------------- pack attn_mask -> 64-bit words per (b, 64-kv tile) via ballot ----------------
__global__ __launch_bounds__(256) void pack_mask(const int* __restrict__ amask,
                                                 unsigned long long* __restrict__ mwords) {
    int word = blockIdx.x * 4 + (threadIdx.x >> 6);   // grid 16 -> words 0..63
    int lane = threadIdx.x & 63;
    unsigned long long m = __ballot(amask[word * 64 + lane] != 0);
    if (lane == 0) mwords[word] = m;
}

// ---------------- transpose W (f32) -> bf16 W^T ----------------
__global__ __launch_bounds__(256) void transpose_w(const float* __restrict__ Wq,
                                                   const float* __restrict__ Wk,
                                                   const float* __restrict__ Wv,
                                                   const float* __restrict__ Wo,
                                                   unsigned short* __restrict__ Wqkv_t,
                                                   unsigned short* __restrict__ Wo_t) {
    __shared__ float tile[32][33];
    const int mtx = blockIdx.z;
    const float* src = mtx == 0 ? Wq : mtx == 1 ? Wk : mtx == 2 ? Wv : Wo;
    unsigned short* dst = mtx < 3 ? (Wqkv_t + (size_t)mtx * D_MODEL * D_MODEL) : Wo_t;
    const int n0 = blockIdx.x * 32, k0 = blockIdx.y * 32;
    const int tx = threadIdx.x, ty = threadIdx.y;
    #pragma unroll
    for (int i = 0; i < 32; i += 8)
        tile[ty + i][tx] = src[(size_t)(k0 + ty + i) * D_MODEL + n0 + tx];
    __syncthreads();
    #pragma unroll
    for (int i = 0; i < 32; i += 8)
        dst[(size_t)(n0 + ty + i) * D_MODEL + k0 + tx] = f2bf(tile[tx][ty + i]);
}

// Cs swizzled addressing: stride 128 shorts, XOR bits 3..5 of col with row&7
#define CSW(r, c) ((r) * 128 + ((c) ^ (((r) & 7) << 3)))

// ---------------- QKV GEMM: BK=64, swizzled LDS, Cs aliased on As/Bs ----------------
__global__ __launch_bounds__(256) void gemm_qkv(const unsigned short* __restrict__ Xb,
                                                const unsigned short* __restrict__ Wt,
                                                const float* __restrict__ bq,
                                                const float* __restrict__ bk,
                                                const float* __restrict__ bv,
                                                unsigned short* __restrict__ Qb,
                                                unsigned short* __restrict__ Kb,
                                                unsigned short* __restrict__ Vt) {
    __shared__ unsigned short SM[16384];   // 32 KB: As[0..8191] | Bs[8192..16383]; Cs aliases all
    unsigned short* As = SM;
    unsigned short* Bs = SM + 8192;
    unsigned short* Cs = SM;
    const int tid = threadIdx.x;
    const int lane = tid & 63, wid = tid >> 6;
    const int fr = lane & 15, fg = lane >> 4;
    const int wr = wid >> 1, wc = wid & 1;
    const int lin = blockIdx.x;
    const int x = lin & 7, i = lin >> 3;
    const int bxm = (x & 3) * 8 + (i & 7);
    const int byn = (x >> 2) * 12 + (i >> 3);
    const int m0 = bxm * 128, n0 = byn * 128;
    const unsigned short* Ag = Xb + (size_t)m0 * D_MODEL;
    const unsigned short* Bg = Wt + (size_t)n0 * D_MODEL;
    // staging: load j covers rows j*32 + tid/8, col slot (tid&7) ^ ((tid>>3)&7) (inverse swizzle)
    const int srow = tid >> 3;
    const int scol = 8 * ((tid & 7) ^ ((tid >> 3) & 7));
    f32x4 acc[4][4] = {};
    for (int kt = 0; kt < D_MODEL; kt += 64) {
        __syncthreads();
        #pragma unroll
        for (int j = 0; j < 4; ++j) {
            int row = j * 32 + srow;
            gload16(Ag + (size_t)row * D_MODEL + kt + scol, &As[(j * 256 + tid) * 8]);
            gload16(Bg + (size_t)row * D_MODEL + kt + scol, &Bs[(j * 256 + tid) * 8]);
        }
        __syncthreads();
        #pragma unroll
        for (int ks = 0; ks < 2; ++ks) {
            bf16x8 af[4], bfv[4];
            #pragma unroll
            for (int m = 0; m < 4; ++m) {
                int row = wr * 64 + m * 16 + fr;
                af[m] = *(const bf16x8*)&As[row * 64 + ((ks * 32 + fg * 8) ^ ((row & 7) * 8))];
            }
            #pragma unroll
            for (int n = 0; n < 4; ++n) {
                int row = wc * 64 + n * 16 + fr;
                bfv[n] = *(const bf16x8*)&Bs[row * 64 + ((ks * 32 + fg * 8) ^ ((row & 7) * 8))];
            }
            #pragma unroll
            for (int m = 0; m < 4; ++m)
                #pragma unroll
                for (int n = 0; n < 4; ++n)
                    acc[m][n] = __builtin_amdgcn_mfma_f32_16x16x32_bf16(af[m], bfv[n], acc[m][n], 0, 0, 0);
        }
    }
    __syncthreads();   // all waves done reading As/Bs before Cs overwrites them
    const int sel = n0 >> 10;
    const int npb = n0 & 1023;
    if (sel < 2) {
        #pragma unroll
        for (int n = 0; n < 4; ++n) {
            int cn = wc * 64 + n * 16 + fr;
            float bias = (sel == 0 ? bq : bk)[npb + cn];
            #pragma unroll
            for (int m = 0; m < 4; ++m)
                #pragma unroll
                for (int r = 0; r < 4; ++r) {
                    int row = wr * 64 + m * 16 + fg * 4 + r;
                    Cs[CSW(row, cn)] = f2bf(acc[m][n][r] + bias);
                }
        }
        __syncthreads();
        unsigned short* dst = sel == 0 ? Qb : Kb;
        #pragma unroll
        for (int k = 0; k < 8; ++k) {
            int c = k * 256 + tid;
            int row = c >> 4, cc = c & 15;
            int np = npb + cc * 8;
            int h = np >> 6, d = np & 63;
            int gm = m0 + row, b = gm >> 10, s = gm & 1023;
            bf16x8 v = *(const bf16x8*)&Cs[CSW(row, cc * 8)];
            *(bf16x8*)&dst[((size_t)(b * NH + h) * SEQ + s) * DH + d] = v;
        }
    } else {
        #pragma unroll
        for (int n = 0; n < 4; ++n) {
            int cn = wc * 64 + n * 16 + fr;
            float bias = bv[npb + cn];
            #pragma unroll
            for (int m = 0; m < 4; ++m)
                #pragma unroll
                for (int r = 0; r < 4; ++r) {
                    int row = wr * 64 + m * 16 + fg * 4 + r;   // s index
                    Cs[CSW(cn, row)] = f2bf(acc[m][n][r] + bias);
                }
        }
        __syncthreads();
        #pragma unroll
        for (int k = 0; k < 8; ++k) {
            int c = k * 256 + tid;
            int dcol = c >> 4, scc = c & 15;
            int np = npb + dcol;
            int h = np >> 6, dd = np & 63;
            int gm0 = m0 + scc * 8, b = gm0 >> 10, s0 = gm0 & 1023;
            bf16x8 v = *(const bf16x8*)&Cs[CSW(dcol, scc * 8)];
            *(bf16x8*)&Vt[((size_t)(b * NH + h) * DH + dd) * SEQ + s0] = v;
        }
    }
}

// ---------------- O-proj GEMM: BK=64, swizzled LDS ----------------
__global__ __launch_bounds__(256) void gemm_o(const unsigned short* __restrict__ Ab,
                                              const unsigned short* __restrict__ Wt,
                                              float* __restrict__ tmp) {
    __shared__ unsigned short As[128 * 64];
    __shared__ unsigned short Bs[128 * 64];
    const int tid = threadIdx.x;
    const int lane = tid & 63, wid = tid >> 6;
    const int fr = lane & 15, fg = lane >> 4;
    const int wr = wid >> 1, wc = wid & 1;
    const int lin = blockIdx.x;
    const int x = lin & 7, i = lin >> 3;
    const int bxm = (x & 3) * 8 + (i & 7);
    const int byn = (x >> 2) * 4 + (i >> 3);
    const int m0 = bxm * 128, n0 = byn * 128;
    const unsigned short* Ag = Ab + (size_t)m0 * D_MODEL;
    const unsigned short* Bg = Wt + (size_t)n0 * D_MODEL;
    const int srow = tid >> 3;
    const int scol = 8 * ((tid & 7) ^ ((tid >> 3) & 7));
    f32x4 acc[4][4] = {};
    for (int kt = 0; kt < D_MODEL; kt += 64) {
        __syncthreads();
        #pragma unroll
        for (int j = 0; j < 4; ++j) {
            int row = j * 32 + srow;
            gload16(Ag + (size_t)row * D_MODEL + kt + scol, &As[(j * 256 + tid) * 8]);
            gload16(Bg + (size_t)row * D_MODEL + kt + scol, &Bs[(j * 256 + tid) * 8]);
        }
        __syncthreads();
        #pragma unroll
        for (int ks = 0; ks < 2; ++ks) {
            bf16x8 af[4], bfv[4];
            #pragma unroll
            for (int m = 0; m < 4; ++m) {
                int row = wr * 64 + m * 16 + fr;
                af[m] = *(const bf16x8*)&As[row * 64 + ((ks * 32 + fg * 8) ^ ((row & 7) * 8))];
            }
            #pragma unroll
            for (int n = 0; n < 4; ++n) {
                int row = wc * 64 + n * 16 + fr;
                bfv[n] = *(const bf16x8*)&Bs[row * 64 + ((ks * 32 + fg * 8) ^ ((row & 7) * 8))];
            }
            #pragma unroll
            for (int m = 0; m < 4; ++m)
                #pragma unroll
                for (int n = 0; n < 4; ++n)
                    acc[m][n] = __builtin_amdgcn_mfma_f32_16x16x32_bf16(af[m], bfv[n], acc[m][n], 0, 0, 0);
        }
    }
    #pragma unroll
    for (int n = 0; n < 4; ++n) {
        int gn = n0 + wc * 64 + n * 16 + fr;
        #pragma unroll
        for (int m = 0; m < 4; ++m) {
            #pragma unroll
            for (int r = 0; r < 4; ++r) {
                int gm = m0 + wr * 64 + m * 16 + fg * 4 + r;
                tmp[(size_t)gm * D_MODEL + gn] = acc[m][n][r];
            }
        }
    }
}

// ---------------- flash attention: KVBLK=128, joint in-register softmax, tree reductions ----------------
__global__ __launch_bounds__(256, 2) void attn_kernel(const unsigned short* __restrict__ Qb,
                                                      const unsigned short* __restrict__ Kb,
                                                      const unsigned short* __restrict__ Vt,
                                                      const unsigned long long* __restrict__ mwords,
                                                      unsigned short* __restrict__ AF) {
    __shared__ unsigned short Ks[2][128 * 64];   // [kv][d]
    __shared__ unsigned short Vts[2][64 * 128];  // [d][kv]
    const int tid = threadIdx.x, lane = tid & 63, wid = tid >> 6;
    const int l31 = lane & 31, hi = lane >> 5;
    const int lin = blockIdx.x;
    const int x = lin & 7, i = lin >> 3;
    const int qt = i & 7, bh = x * 8 + (i >> 3);
    const int b = bh >> 4;
    const unsigned short* Qh = Qb + (size_t)bh * SEQ * DH;
    const unsigned short* Kh = Kb + (size_t)bh * SEQ * DH;
    const unsigned short* Vth = Vt + (size_t)bh * DH * SEQ;
    const unsigned long long* mwb = mwords + b * 16;
    const int q0 = qt * 128 + wid * 32;

    const int k_row = wid * 32 + (lane >> 3);
    const int k_col = 8 * ((lane & 7) ^ ((lane >> 3) & 7));
    const int v_rowb = wid * 16 + (lane >> 4);

    bf16x8 qf[4];
    #pragma unroll
    for (int ks = 0; ks < 4; ++ks)
        qf[ks] = *(const bf16x8*)(Qh + (size_t)(q0 + l31) * DH + ks * 16 + hi * 8);

    f32x16 oacc0 = {}, oacc1 = {};
    float mrun = -3.0e38f, lrun = 0.f;
    const float C2 = 0.18033688f;    // 0.125 * log2(e)

#define KSWZ(row, colsh) ((row) * 64 + ((colsh) ^ (((row) & 7) << 3)))
#define VSWZ(row, colsh) ((row) * 128 + ((colsh) ^ (((row) & 7) << 3)))
#define STAGE(bufi, kt2)                                                                  \
    {                                                                                     \
        const int kv0s = (kt2) * 128;                                                     \
        _Pragma("unroll")                                                                 \
        for (int j = 0; j < 4; ++j)                                                       \
            gload16(Kh + (size_t)(kv0s + k_row + j * 8) * DH + k_col,                     \
                    &Ks[bufi][wid * 2048 + j * 512]);                                     \
        _Pragma("unroll")                                                                 \
        for (int j = 0; j < 4; ++j) {                                                     \
            const int vr = v_rowb + j * 4;                                                \
            gload16(Vth + (size_t)vr * SEQ + kv0s + 8 * ((lane & 15) ^ (vr & 7)),         \
                    &Vts[bufi][wid * 2048 + j * 512]);                                    \
        }                                                                                 \
    }

    STAGE(0, 0);
    __syncthreads();
    int buf = 0;
    for (int kt = 0; kt < 8; ++kt) {
        if (kt < 7) STAGE(buf ^ 1, kt + 1);
        const unsigned long long mwA = mwb[2 * kt], mwB = mwb[2 * kt + 1];
        const unsigned mflA0 = (unsigned)(mwA >> (4 * hi));
        const unsigned mflA1 = (unsigned)(mwA >> (32 + 4 * hi));
        const unsigned mflB0 = (unsigned)(mwB >> (4 * hi));
        const unsigned mflB1 = (unsigned)(mwB >> (32 + 4 * hi));
        f32x16 sA0 = {}, sA1 = {}, sB0 = {}, sB1 = {};
        __builtin_amdgcn_s_setprio(1);
        #pragma unroll
        for (int ks = 0; ks < 4; ++ks) {
            const int ch = ks * 16 + hi * 8;
            bf16x8 k0 = *(const bf16x8*)&Ks[buf][KSWZ(l31, ch)];
            bf16x8 k1 = *(const bf16x8*)&Ks[buf][KSWZ(32 + l31, ch)];
            bf16x8 k2 = *(const bf16x8*)&Ks[buf][KSWZ(64 + l31, ch)];
            bf16x8 k3 = *(const bf16x8*)&Ks[buf][KSWZ(96 + l31, ch)];
            sA0 = __builtin_amdgcn_mfma_f32_32x32x16_bf16(k0, qf[ks], sA0, 0, 0, 0);
            sA1 = __builtin_amdgcn_mfma_f32_32x32x16_bf16(k1, qf[ks], sA1, 0, 0, 0);
            sB0 = __builtin_amdgcn_mfma_f32_32x32x16_bf16(k2, qf[ks], sB0, 0, 0, 0);
            sB1 = __builtin_amdgcn_mfma_f32_32x32x16_bf16(k3, qf[ks], sB1, 0, 0, 0);
        }
        __builtin_amdgcn_s_setprio(0);
        float tm[16];
        #pragma unroll
        for (int r2 = 0; r2 < 16; ++r2)
            tm[r2] = fmaxf(fmaxf(sA0[r2], sA1[r2]), fmaxf(sB0[r2], sB1[r2]));
        #pragma unroll
        for (int st = 8; st; st >>= 1)
            #pragma unroll
            for (int r2 = 0; r2 < st; ++r2)
                tm[r2] = fmaxf(tm[r2], tm[r2 + st]);
        float m = tm[0];
        m = fmaxf(m, xhalf(m, hi));
        float mt = m * C2;
        if (!__all(mt <= mrun + 11.5f)) {
            float newm = fmaxf(mrun, mt);
            float corr = exp2f(mrun - newm);
            lrun *= corr;
            #pragma unroll
            for (int r2 = 0; r2 < 16; ++r2) { oacc0[r2] *= corr; oacc1[r2] *= corr; }
            mrun = newm;
        }
        float ts[16];
        #pragma unroll
        for (int r2 = 0; r2 < 16; ++r2) {
            const int kvb = (r2 & 3) + 8 * (r2 >> 2);
            float pA0 = exp2f(fmaf(sA0[r2], C2, -mrun));
            float pA1 = exp2f(fmaf(sA1[r2], C2, -mrun));
            float pB0 = exp2f(fmaf(sB0[r2], C2, -mrun));
            float pB1 = exp2f(fmaf(sB1[r2], C2, -mrun));
            pA0 = ((mflA0 >> kvb) & 1) ? 0.f : pA0;
            pA1 = ((mflA1 >> kvb) & 1) ? 0.f : pA1;
            pB0 = ((mflB0 >> kvb) & 1) ? 0.f : pB0;
            pB1 = ((mflB1 >> kvb) & 1) ? 0.f : pB1;
            sA0[r2] = pA0; sA1[r2] = pA1; sB0[r2] = pB0; sB1[r2] = pB1;
            ts[r2] = (pA0 + pA1) + (pB0 + pB1);
        }
        #pragma unroll
        for (int st = 8; st; st >>= 1)
            #pragma unroll
            for (int r2 = 0; r2 < st; ++r2)
                ts[r2] += ts[r2 + st];
        float ps = ts[0];
        ps += xhalf(ps, hi);
        lrun += ps;
        unsigned cA0[8], cA1[8], cB0[8], cB1[8];
        #pragma unroll
        for (int ii = 0; ii < 8; ++ii) {
            asm volatile("v_cvt_pk_bf16_f32 %0, %1, %2" : "=v"(cA0[ii]) : "v"(sA0[2 * ii]), "v"(sA0[2 * ii + 1]));
            asm volatile("v_cvt_pk_bf16_f32 %0, %1, %2" : "=v"(cA1[ii]) : "v"(sA1[2 * ii]), "v"(sA1[2 * ii + 1]));
            asm volatile("v_cvt_pk_bf16_f32 %0, %1, %2" : "=v"(cB0[ii]) : "v"(sB0[2 * ii]), "v"(sB0[2 * ii + 1]));
            asm volatile("v_cvt_pk_bf16_f32 %0, %1, %2" : "=v"(cB1[ii]) : "v"(sB1[2 * ii]), "v"(sB1[2 * ii + 1]));
        }
        #pragma unroll
        for (int g = 0; g < 8; g += 4) {
            asm volatile("v_permlane32_swap_b32 %0, %1" : "+v"(cA0[g + 0]), "+v"(cA0[g + 2]));
            asm volatile("v_permlane32_swap_b32 %0, %1" : "+v"(cA0[g + 1]), "+v"(cA0[g + 3]));
            asm volatile("v_permlane32_swap_b32 %0, %1" : "+v"(cA1[g + 0]), "+v"(cA1[g + 2]));
            asm volatile("v_permlane32_swap_b32 %0, %1" : "+v"(cA1[g + 1]), "+v"(cA1[g + 3]));
            asm volatile("v_permlane32_swap_b32 %0, %1" : "+v"(cB0[g + 0]), "+v"(cB0[g + 2]));
            asm volatile("v_permlane32_swap_b32 %0, %1" : "+v"(cB0[g + 1]), "+v"(cB0[g + 3]));
            asm volatile("v_permlane32_swap_b32 %0, %1" : "+v"(cB1[g + 0]), "+v"(cB1[g + 2]));
            asm volatile("v_permlane32_swap_b32 %0, %1" : "+v"(cB1[g + 1]), "+v"(cB1[g + 3]));
        }
        __builtin_amdgcn_s_setprio(1);
        #pragma unroll
        for (int t = 0; t < 8; ++t) {
            const unsigned* cp = (t < 2) ? cA0 : (t < 4) ? cA1 : (t < 6) ? cB0 : cB1;
            const int g = (t & 1) * 4;
            union { unsigned u[4]; bf16x8 v; } pb;
            pb.u[0] = cp[g + 0]; pb.u[1] = cp[g + 1]; pb.u[2] = cp[g + 2]; pb.u[3] = cp[g + 3];
            const int ch = t * 16 + hi * 8;
            bf16x8 vf0 = *(const bf16x8*)&Vts[buf][VSWZ(l31, ch)];
            bf16x8 vf1 = *(const bf16x8*)&Vts[buf][VSWZ(32 + l31, ch)];
            oacc0 = __builtin_amdgcn_mfma_f32_32x32x16_bf16(vf0, pb.v, oacc0, 0, 0, 0);
            oacc1 = __builtin_amdgcn_mfma_f32_32x32x16_bf16(vf1, pb.v, oacc1, 0, 0, 0);
        }
        __builtin_amdgcn_s_setprio(0);
        __syncthreads();
        buf ^= 1;
    }
#undef STAGE
#undef KSWZ
#undef VSWZ
    const float rl = 1.f / lrun;
    const int b2 = bh & 3, h2 = bh >> 2;
    const size_t rowbase = ((size_t)b2 * SEQ + q0 + l31) * D_MODEL + h2 * 64 + 4 * hi;
    #pragma unroll
    for (int df = 0; df < 2; ++df) {
        const f32x16& oa = df ? oacc1 : oacc0;
        #pragma unroll
        for (int rg = 0; rg < 4; ++rg) {
            ushort4 pk;
            pk.x = f2bf(oa[rg * 4 + 0] * rl);
            pk.y = f2bf(oa[rg * 4 + 1] * rl);
            pk.z = f2bf(oa[rg * 4 + 2] * rl);
            pk.w = f2bf(oa[rg * 4 + 3] * rl);
            *(ushort4*)&AF[rowbase + 32 * df + 8 * rg] = pk;
        }
    }
}

// ---------------- residual + LayerNorm ----------------
__global__ __launch_bounds__(256) void ln_kernel(const float* __restrict__ tmp,
                                                 const float* __restrict__ inp,
                                                 const float* __restrict__ g,
                                                 const float* __restrict__ bb,
                                                 float* __restrict__ out) {
    __shared__ float red[8];
    const int row = blockIdx.x, tid = threadIdx.x;
    float4 t = ((const float4*)(tmp + (size_t)row * D_MODEL))[tid];
    float4 rr = ((const float4*)(inp + (size_t)row * D_MODEL))[tid];
    float4 y;
    y.x = t.x + rr.x; y.y = t.y + rr.y; y.z = t.z + rr.z; y.w = t.w + rr.w;
    float sum = y.x + y.y + y.z + y.w;
    float sq = y.x * y.x + y.y * y.y + y.z * y.z + y.w * y.w;
    #pragma unroll
    for (int o = 1; o < 64; o <<= 1) { sum += __shfl_xor(sum, o); sq += __shfl_xor(sq, o); }
    int wid = tid >> 6, lane = tid & 63;
    if (lane == 0) { red[wid] = sum; red[4 + wid] = sq; }
    __syncthreads();
    sum = red[0] + red[1] + red[2] + red[3];
    sq = red[4] + red[5] + red[6] + red[7];
    float mu = sum * (1.f / D_MODEL);
    float var = sq * (1.f / D_MODEL) - mu * mu;
    float rs = rsqrtf(var + 1e-5f);
    float4 gg = ((const float4*)g)[tid];
    float4 bv = ((const float4*)bb)[tid];
    float4 o4;
    o4.x = (y.x - mu) * rs * gg.x + bv.x;
    o4.y = (y.y - mu) * rs * gg.y + bv.y;
    o4.z = (y.z - mu) * rs * gg.z + bv.z;
    o4.w = (y.w - mu) * rs * gg.w + bv.w;
    ((float4*)(out + (size_t)row * D_MODEL))[tid] = o4;
}

extern "C" void kernel_launch(void* const* d_in, const int* in_sizes, int n_in,
                              void* d_out, int out_size, void* d_ws, size_t ws_size,
                              hipStream_t stream) {
    const float* inp = (const float*)d_in[0];
    const int* amask = (const int*)d_in[1];
    const float* Wq = (const float*)d_in[2];
    const float* bq = (const float*)d_in[3];
    const float* Wk = (const float*)d_in[4];
    const float* bk = (const float*)d_in[5];
    const float* Wv = (const float*)d_in[6];
    const float* bv = (const float*)d_in[7];
    const float* Wo = (const float*)d_in[8];
    const float* lg = (const float*)d_in[9];
    const float* lb = (const float*)d_in[10];
    float* out = (float*)d_out;
    char* ws = (char*)d_ws;

    unsigned short* Xb     = (unsigned short*)(ws + 0);          //  8.0 MiB
    unsigned short* Wqkv_t = (unsigned short*)(ws + 8388608);    //  6.0 MiB
    unsigned short* Wo_t   = (unsigned short*)(ws + 14680064);   //  2.0 MiB
    unsigned short* Qb     = (unsigned short*)(ws + 16777216);   //  8.0 MiB
    unsigned short* Kb     = (unsigned short*)(ws + 25165824);   //  8.0 MiB
    unsigned short* Vt     = (unsigned short*)(ws + 33554432);   //  8.0 MiB  (V^T: [bh][d][s])
    unsigned short* AF     = (unsigned short*)(ws + 41943040);   //  8.0 MiB
    float*          tmp    = (float*)(ws + 50331648);            // 16.0 MiB
    unsigned long long* mwords = (unsigned long long*)(ws + 50331648);  // aliases tmp (dead until gemm_o)

    cvt_x<<<4096, 256, 0, stream>>>(inp, Xb);
    pack_mask<<<16, 256, 0, stream>>>(amask, mwords);
    transpose_w<<<dim3(32, 32, 4), dim3(32, 8), 0, stream>>>(Wq, Wk, Wv, Wo, Wqkv_t, Wo_t);
    gemm_qkv<<<768, 256, 0, stream>>>(Xb, Wqkv_t, bq, bk, bv, Qb, Kb, Vt);
    attn_kernel<<<512, 256, 0, stream>>>(Qb, Kb, Vt, mwords, AF);
    gemm_o<<<256, 256, 0, stream>>>(AF, Wo_t, tmp);
    ln_kernel<<<4096, 256, 0, stream>>>(tmp, inp, lg, lb, out);
}

// Round 8
// 115.275 us; speedup vs baseline: 1.6592x; 1.1448x over previous
//
#include <hip/hip_runtime.h>

typedef __attribute__((ext_vector_type(8))) short bf16x8;
typedef __attribute__((ext_vector_type(4))) float f32x4;
typedef __attribute__((ext_vector_type(16))) float f32x16;

#define D_MODEL 1024
#define SEQ 1024
#define NB 4
#define NH 16
#define DH 64
#define MROWS 4096

__device__ __forceinline__ unsigned short f2bf(float f) {
    union { float f; unsigned u; } x; x.f = f;
    unsigned r = x.u + 0x7fffu + ((x.u >> 16) & 1u);
    return (unsigned short)(r >> 16);
}

__device__ __forceinline__ void gload16(const void* g, void* l) {
    __builtin_amdgcn_global_load_lds((const __attribute__((address_space(1))) void*)g,
                                     (__attribute__((address_space(3))) void*)l, 16, 0, 0);
}

// exchange value with lane^32 via permlane32_swap (VALU-only, no LDS)
__device__ __forceinline__ float xhalf(float x, int hi) {
    float a = x, b = x;
    asm volatile("v_permlane32_swap_b32 %0, %1" : "+v"(a), "+v"(b));
    return hi ? b : a;
}

// ---------------- convert inp f32 -> bf16 ----------------
__global__ __launch_bounds__(256) void cvt_x(const float* __restrict__ x,
                                             unsigned short* __restrict__ o) {
    int i = blockIdx.x * 256 + threadIdx.x;
    float4 v = ((const float4*)x)[i];
    ushort4 r;
    r.x = f2bf(v.x); r.y = f2bf(v.y); r.z = f2bf(v.z); r.w = f2bf(v.w);
    ((ushort4*)o)[i] = r;
}

// ---------------- pack attn_mask -> 64-bit words per (b, 64-kv tile) via ballot ----------------
__global__ __launch_bounds__(256) void pack_mask(const int* __restrict__ amask,
                                                 unsigned long long* __restrict__ mwords) {
    int word = blockIdx.x * 4 + (threadIdx.x >> 6);   // grid 16 -> words 0..63
    int lane = threadIdx.x & 63;
    unsigned long long m = __ballot(amask[word * 64 + lane] != 0);
    if (lane == 0) mwords[word] = m;
}

// ---------------- transpose W (f32) -> bf16 W^T ----------------
__global__ __launch_bounds__(256) void transpose_w(const float* __restrict__ Wq,
                                                   const float* __restrict__ Wk,
                                                   const float* __restrict__ Wv,
                                                   const float* __restrict__ Wo,
                                                   unsigned short* __restrict__ Wqkv_t,
                                                   unsigned short* __restrict__ Wo_t) {
    __shared__ float tile[32][33];
    const int mtx = blockIdx.z;
    const float* src = mtx == 0 ? Wq : mtx == 1 ? Wk : mtx == 2 ? Wv : Wo;
    unsigned short* dst = mtx < 3 ? (Wqkv_t + (size_t)mtx * D_MODEL * D_MODEL) : Wo_t;
    const int n0 = blockIdx.x * 32, k0 = blockIdx.y * 32;
    const int tx = threadIdx.x, ty = threadIdx.y;
    #pragma unroll
    for (int i = 0; i < 32; i += 8)
        tile[ty + i][tx] = src[(size_t)(k0 + ty + i) * D_MODEL + n0 + tx];
    __syncthreads();
    #pragma unroll
    for (int i = 0; i < 32; i += 8)
        dst[(size_t)(n0 + ty + i) * D_MODEL + k0 + tx] = f2bf(tile[tx][ty + i]);
}

// Cs swizzled addressing: stride 128 shorts, XOR bits 3..5 of col with row&7
#define CSW(r, c) ((r) * 128 + ((c) ^ (((r) & 7) << 3)))

// ---------------- QKV GEMM: BK=64, double-buffered (prefetch t+1 during compute t) ----------------
__global__ __launch_bounds__(256) void gemm_qkv(const unsigned short* __restrict__ Xb,
                                                const unsigned short* __restrict__ Wt,
                                                const float* __restrict__ bq,
                                                const float* __restrict__ bk,
                                                const float* __restrict__ bv,
                                                unsigned short* __restrict__ Qb,
                                                unsigned short* __restrict__ Kb,
                                                unsigned short* __restrict__ Vt) {
    __shared__ unsigned short SM[32768];   // 64 KB: [buf][A 8192 | B 8192]; Cs aliases first 32 KB
    const int tid = threadIdx.x;
    const int lane = tid & 63, wid = tid >> 6;
    const int fr = lane & 15, fg = lane >> 4;
    const int wr = wid >> 1, wc = wid & 1;
    const int lin = blockIdx.x;
    const int x = lin & 7, i = lin >> 3;
    const int bxm = (x & 3) * 8 + (i & 7);
    const int byn = (x >> 2) * 12 + (i >> 3);
    const int m0 = bxm * 128, n0 = byn * 128;
    const unsigned short* Ag = Xb + (size_t)m0 * D_MODEL;
    const unsigned short* Bg = Wt + (size_t)n0 * D_MODEL;
    const int srow = tid >> 3;
    const int scol = 8 * ((tid & 7) ^ ((tid >> 3) & 7));
    f32x4 acc[4][4] = {};

#define QSTAGE(bf, kt2)                                                                   \
    {                                                                                     \
        const int kb = (kt2) * 64;                                                        \
        _Pragma("unroll")                                                                 \
        for (int j = 0; j < 4; ++j) {                                                     \
            int row = j * 32 + srow;                                                      \
            gload16(Ag + (size_t)row * D_MODEL + kb + scol, &SM[(bf) * 16384 + (j * 256 + tid) * 8]); \
            gload16(Bg + (size_t)row * D_MODEL + kb + scol, &SM[(bf) * 16384 + 8192 + (j * 256 + tid) * 8]); \
        }                                                                                 \
    }

    QSTAGE(0, 0);
    __syncthreads();
    int buf = 0;
    for (int kt = 0; kt < 16; ++kt) {
        if (kt < 15) QSTAGE(buf ^ 1, kt + 1);
        const unsigned short* As = &SM[buf * 16384];
        const unsigned short* Bs = &SM[buf * 16384 + 8192];
        #pragma unroll
        for (int ks = 0; ks < 2; ++ks) {
            bf16x8 af[4], bfv[4];
            #pragma unroll
            for (int m = 0; m < 4; ++m) {
                int row = wr * 64 + m * 16 + fr;
                af[m] = *(const bf16x8*)&As[row * 64 + ((ks * 32 + fg * 8) ^ ((row & 7) * 8))];
            }
            #pragma unroll
            for (int n = 0; n < 4; ++n) {
                int row = wc * 64 + n * 16 + fr;
                bfv[n] = *(const bf16x8*)&Bs[row * 64 + ((ks * 32 + fg * 8) ^ ((row & 7) * 8))];
            }
            __builtin_amdgcn_s_setprio(1);
            #pragma unroll
            for (int m = 0; m < 4; ++m)
                #pragma unroll
                for (int n = 0; n < 4; ++n)
                    acc[m][n] = __builtin_amdgcn_mfma_f32_16x16x32_bf16(af[m], bfv[n], acc[m][n], 0, 0, 0);
            __builtin_amdgcn_s_setprio(0);
        }
        __syncthreads();   // drains prefetch + orders reads before buf reuse
        buf ^= 1;
    }
#undef QSTAGE
    unsigned short* Cs = SM;
    const int sel = n0 >> 10;
    const int npb = n0 & 1023;
    if (sel < 2) {
        #pragma unroll
        for (int n = 0; n < 4; ++n) {
            int cn = wc * 64 + n * 16 + fr;
            float bias = (sel == 0 ? bq : bk)[npb + cn];
            #pragma unroll
            for (int m = 0; m < 4; ++m)
                #pragma unroll
                for (int r = 0; r < 4; ++r) {
                    int row = wr * 64 + m * 16 + fg * 4 + r;
                    Cs[CSW(row, cn)] = f2bf(acc[m][n][r] + bias);
                }
        }
        __syncthreads();
        unsigned short* dst = sel == 0 ? Qb : Kb;
        #pragma unroll
        for (int k = 0; k < 8; ++k) {
            int c = k * 256 + tid;
            int row = c >> 4, cc = c & 15;
            int np = npb + cc * 8;
            int h = np >> 6, d = np & 63;
            int gm = m0 + row, b = gm >> 10, s = gm & 1023;
            bf16x8 v = *(const bf16x8*)&Cs[CSW(row, cc * 8)];
            *(bf16x8*)&dst[((size_t)(b * NH + h) * SEQ + s) * DH + d] = v;
        }
    } else {
        #pragma unroll
        for (int n = 0; n < 4; ++n) {
            int cn = wc * 64 + n * 16 + fr;
            float bias = bv[npb + cn];
            #pragma unroll
            for (int m = 0; m < 4; ++m)
                #pragma unroll
                for (int r = 0; r < 4; ++r) {
                    int row = wr * 64 + m * 16 + fg * 4 + r;   // s index
                    Cs[CSW(cn, row)] = f2bf(acc[m][n][r] + bias);
                }
        }
        __syncthreads();
        #pragma unroll
        for (int k = 0; k < 8; ++k) {
            int c = k * 256 + tid;
            int dcol = c >> 4, scc = c & 15;
            int np = npb + dcol;
            int h = np >> 6, dd = np & 63;
            int gm0 = m0 + scc * 8, b = gm0 >> 10, s0 = gm0 & 1023;
            bf16x8 v = *(const bf16x8*)&Cs[CSW(dcol, scc * 8)];
            *(bf16x8*)&Vt[((size_t)(b * NH + h) * DH + dd) * SEQ + s0] = v;
        }
    }
}

// ---------------- O-proj GEMM: BK=64, double-buffered ----------------
__global__ __launch_bounds__(256) void gemm_o(const unsigned short* __restrict__ Ab,
                                              const unsigned short* __restrict__ Wt,
                                              float* __restrict__ tmp) {
    __shared__ unsigned short SM[32768];   // 64 KB dbuf
    const int tid = threadIdx.x;
    const int lane = tid & 63, wid = tid >> 6;
    const int fr = lane & 15, fg = lane >> 4;
    const int wr = wid >> 1, wc = wid & 1;
    const int lin = blockIdx.x;
    const int x = lin & 7, i = lin >> 3;
    const int bxm = (x & 3) * 8 + (i & 7);
    const int byn = (x >> 2) * 4 + (i >> 3);
    const int m0 = bxm * 128, n0 = byn * 128;
    const unsigned short* Ag = Ab + (size_t)m0 * D_MODEL;
    const unsigned short* Bg = Wt + (size_t)n0 * D_MODEL;
    const int srow = tid >> 3;
    const int scol = 8 * ((tid & 7) ^ ((tid >> 3) & 7));
    f32x4 acc[4][4] = {};

#define OSTAGE(bf, kt2)                                                                   \
    {                                                                                     \
        const int kb = (kt2) * 64;                                                        \
        _Pragma("unroll")                                                                 \
        for (int j = 0; j < 4; ++j) {                                                     \
            int row = j * 32 + srow;                                                      \
            gload16(Ag + (size_t)row * D_MODEL + kb + scol, &SM[(bf) * 16384 + (j * 256 + tid) * 8]); \
            gload16(Bg + (size_t)row * D_MODEL + kb + scol, &SM[(bf) * 16384 + 8192 + (j * 256 + tid) * 8]); \
        }                                                                                 \
    }

    OSTAGE(0, 0);
    __syncthreads();
    int buf = 0;
    for (int kt = 0; kt < 16; ++kt) {
        if (kt < 15) OSTAGE(buf ^ 1, kt + 1);
        const unsigned short* As = &SM[buf * 16384];
        const unsigned short* Bs = &SM[buf * 16384 + 8192];
        #pragma unroll
        for (int ks = 0; ks < 2; ++ks) {
            bf16x8 af[4], bfv[4];
            #pragma unroll
            for (int m = 0; m < 4; ++m) {
                int row = wr * 64 + m * 16 + fr;
                af[m] = *(const bf16x8*)&As[row * 64 + ((ks * 32 + fg * 8) ^ ((row & 7) * 8))];
            }
            #pragma unroll
            for (int n = 0; n < 4; ++n) {
                int row = wc * 64 + n * 16 + fr;
                bfv[n] = *(const bf16x8*)&Bs[row * 64 + ((ks * 32 + fg * 8) ^ ((row & 7) * 8))];
            }
            __builtin_amdgcn_s_setprio(1);
            #pragma unroll
            for (int m = 0; m < 4; ++m)
                #pragma unroll
                for (int n = 0; n < 4; ++n)
                    acc[m][n] = __builtin_amdgcn_mfma_f32_16x16x32_bf16(af[m], bfv[n], acc[m][n], 0, 0, 0);
            __builtin_amdgcn_s_setprio(0);
        }
        __syncthreads();
        buf ^= 1;
    }
#undef OSTAGE
    #pragma unroll
    for (int n = 0; n < 4; ++n) {
        int gn = n0 + wc * 64 + n * 16 + fr;
        #pragma unroll
        for (int m = 0; m < 4; ++m) {
            #pragma unroll
            for (int r = 0; r < 4; ++r) {
                int gm = m0 + wr * 64 + m * 16 + fg * 4 + r;
                tmp[(size_t)gm * D_MODEL + gn] = acc[m][n][r];
            }
        }
    }
}

// ---------------- flash attention: KVBLK=128, joint in-register softmax, tree reductions ----------------
__global__ __launch_bounds__(256, 2) void attn_kernel(const unsigned short* __restrict__ Qb,
                                                      const unsigned short* __restrict__ Kb,
                                                      const unsigned short* __restrict__ Vt,
                                                      const unsigned long long* __restrict__ mwords,
                                                      unsigned short* __restrict__ AF) {
    __shared__ unsigned short Ks[2][128 * 64];   // [kv][d]
    __shared__ unsigned short Vts[2][64 * 128];  // [d][kv]
    const int tid = threadIdx.x, lane = tid & 63, wid = tid >> 6;
    const int l31 = lane & 31, hi = lane >> 5;
    const int lin = blockIdx.x;
    const int x = lin & 7, i = lin >> 3;
    const int qt = i & 7, bh = x * 8 + (i >> 3);
    const int b = bh >> 4;
    const unsigned short* Qh = Qb + (size_t)bh * SEQ * DH;
    const unsigned short* Kh = Kb + (size_t)bh * SEQ * DH;
    const unsigned short* Vth = Vt + (size_t)bh * DH * SEQ;
    const unsigned long long* mwb = mwords + b * 16;
    const int q0 = qt * 128 + wid * 32;

    const int k_row = wid * 32 + (lane >> 3);
    const int k_col = 8 * ((lane & 7) ^ ((lane >> 3) & 7));
    const int v_rowb = wid * 16 + (lane >> 4);

    bf16x8 qf[4];
    #pragma unroll
    for (int ks = 0; ks < 4; ++ks)
        qf[ks] = *(const bf16x8*)(Qh + (size_t)(q0 + l31) * DH + ks * 16 + hi * 8);

    f32x16 oacc0 = {}, oacc1 = {};
    float mrun = -3.0e38f, lrun = 0.f;
    const float C2 = 0.18033688f;    // 0.125 * log2(e)

#define KSWZ(row, colsh) ((row) * 64 + ((colsh) ^ (((row) & 7) << 3)))
#define VSWZ(row, colsh) ((row) * 128 + ((colsh) ^ (((row) & 7) << 3)))
#define STAGE(bufi, kt2)                                                                  \
    {                                                                                     \
        const int kv0s = (kt2) * 128;                                                     \
        _Pragma("unroll")                                                                 \
        for (int j = 0; j < 4; ++j)                                                       \
            gload16(Kh + (size_t)(kv0s + k_row + j * 8) * DH + k_col,                     \
                    &Ks[bufi][wid * 2048 + j * 512]);                                     \
        _Pragma("unroll")                                                                 \
        for (int j = 0; j < 4; ++j) {                                                     \
            const int vr = v_rowb + j * 4;                                                \
            gload16(Vth + (size_t)vr * SEQ + kv0s + 8 * ((lane & 15) ^ (vr & 7)),         \
                    &Vts[bufi][wid * 2048 + j * 512]);                                    \
        }                                                                                 \
    }

    STAGE(0, 0);
    __syncthreads();
    int buf = 0;
    for (int kt = 0; kt < 8; ++kt) {
        if (kt < 7) STAGE(buf ^ 1, kt + 1);
        const unsigned long long mwA = mwb[2 * kt], mwB = mwb[2 * kt + 1];
        const unsigned mflA0 = (unsigned)(mwA >> (4 * hi));
        const unsigned mflA1 = (unsigned)(mwA >> (32 + 4 * hi));
        const unsigned mflB0 = (unsigned)(mwB >> (4 * hi));
        const unsigned mflB1 = (unsigned)(mwB >> (32 + 4 * hi));
        f32x16 sA0 = {}, sA1 = {}, sB0 = {}, sB1 = {};
        __builtin_amdgcn_s_setprio(1);
        #pragma unroll
        for (int ks = 0; ks < 4; ++ks) {
            const int ch = ks * 16 + hi * 8;
            bf16x8 k0 = *(const bf16x8*)&Ks[buf][KSWZ(l31, ch)];
            bf16x8 k1 = *(const bf16x8*)&Ks[buf][KSWZ(32 + l31, ch)];
            bf16x8 k2 = *(const bf16x8*)&Ks[buf][KSWZ(64 + l31, ch)];
            bf16x8 k3 = *(const bf16x8*)&Ks[buf][KSWZ(96 + l31, ch)];
            sA0 = __builtin_amdgcn_mfma_f32_32x32x16_bf16(k0, qf[ks], sA0, 0, 0, 0);
            sA1 = __builtin_amdgcn_mfma_f32_32x32x16_bf16(k1, qf[ks], sA1, 0, 0, 0);
            sB0 = __builtin_amdgcn_mfma_f32_32x32x16_bf16(k2, qf[ks], sB0, 0, 0, 0);
            sB1 = __builtin_amdgcn_mfma_f32_32x32x16_bf16(k3, qf[ks], sB1, 0, 0, 0);
        }
        __builtin_amdgcn_s_setprio(0);
        float tm[16];
        #pragma unroll
        for (int r2 = 0; r2 < 16; ++r2)
            tm[r2] = fmaxf(fmaxf(sA0[r2], sA1[r2]), fmaxf(sB0[r2], sB1[r2]));
        #pragma unroll
        for (int st = 8; st; st >>= 1)
            #pragma unroll
            for (int r2 = 0; r2 < st; ++r2)
                tm[r2] = fmaxf(tm[r2], tm[r2 + st]);
        float m = tm[0];
        m = fmaxf(m, xhalf(m, hi));
        float mt = m * C2;
        if (!__all(mt <= mrun + 11.5f)) {
            float newm = fmaxf(mrun, mt);
            float corr = exp2f(mrun - newm);
            lrun *= corr;
            #pragma unroll
            for (int r2 = 0; r2 < 16; ++r2) { oacc0[r2] *= corr; oacc1[r2] *= corr; }
            mrun = newm;
        }
        float ts[16];
        #pragma unroll
        for (int r2 = 0; r2 < 16; ++r2) {
            const int kvb = (r2 & 3) + 8 * (r2 >> 2);
            float pA0 = exp2f(fmaf(sA0[r2], C2, -mrun));
            float pA1 = exp2f(fmaf(sA1[r2], C2, -mrun));
            float pB0 = exp2f(fmaf(sB0[r2], C2, -mrun));
            float pB1 = exp2f(fmaf(sB1[r2], C2, -mrun));
            pA0 = ((mflA0 >> kvb) & 1) ? 0.f : pA0;
            pA1 = ((mflA1 >> kvb) & 1) ? 0.f : pA1;
            pB0 = ((mflB0 >> kvb) & 1) ? 0.f : pB0;
            pB1 = ((mflB1 >> kvb) & 1) ? 0.f : pB1;
            sA0[r2] = pA0; sA1[r2] = pA1; sB0[r2] = pB0; sB1[r2] = pB1;
            ts[r2] = (pA0 + pA1) + (pB0 + pB1);
        }
        #pragma unroll
        for (int st = 8; st; st >>= 1)
            #pragma unroll
            for (int r2 = 0; r2 < st; ++r2)
                ts[r2] += ts[r2 + st];
        float ps = ts[0];
        ps += xhalf(ps, hi);
        lrun += ps;
        unsigned cA0[8], cA1[8], cB0[8], cB1[8];
        #pragma unroll
        for (int ii = 0; ii < 8; ++ii) {
            asm volatile("v_cvt_pk_bf16_f32 %0, %1, %2" : "=v"(cA0[ii]) : "v"(sA0[2 * ii]), "v"(sA0[2 * ii + 1]));
            asm volatile("v_cvt_pk_bf16_f32 %0, %1, %2" : "=v"(cA1[ii]) : "v"(sA1[2 * ii]), "v"(sA1[2 * ii + 1]));
            asm volatile("v_cvt_pk_bf16_f32 %0, %1, %2" : "=v"(cB0[ii]) : "v"(sB0[2 * ii]), "v"(sB0[2 * ii + 1]));
            asm volatile("v_cvt_pk_bf16_f32 %0, %1, %2" : "=v"(cB1[ii]) : "v"(sB1[2 * ii]), "v"(sB1[2 * ii + 1]));
        }
        #pragma unroll
        for (int g = 0; g < 8; g += 4) {
            asm volatile("v_permlane32_swap_b32 %0, %1" : "+v"(cA0[g + 0]), "+v"(cA0[g + 2]));
            asm volatile("v_permlane32_swap_b32 %0, %1" : "+v"(cA0[g + 1]), "+v"(cA0[g + 3]));
            asm volatile("v_permlane32_swap_b32 %0, %1" : "+v"(cA1[g + 0]), "+v"(cA1[g + 2]));
            asm volatile("v_permlane32_swap_b32 %0, %1" : "+v"(cA1[g + 1]), "+v"(cA1[g + 3]));
            asm volatile("v_permlane32_swap_b32 %0, %1" : "+v"(cB0[g + 0]), "+v"(cB0[g + 2]));
            asm volatile("v_permlane32_swap_b32 %0, %1" : "+v"(cB0[g + 1]), "+v"(cB0[g + 3]));
            asm volatile("v_permlane32_swap_b32 %0, %1" : "+v"(cB1[g + 0]), "+v"(cB1[g + 2]));
            asm volatile("v_permlane32_swap_b32 %0, %1" : "+v"(cB1[g + 1]), "+v"(cB1[g + 3]));
        }
        __builtin_amdgcn_s_setprio(1);
        #pragma unroll
        for (int t = 0; t < 8; ++t) {
            const unsigned* cp = (t < 2) ? cA0 : (t < 4) ? cA1 : (t < 6) ? cB0 : cB1;
            const int g = (t & 1) * 4;
            union { unsigned u[4]; bf16x8 v; } pb;
            pb.u[0] = cp[g + 0]; pb.u[1] = cp[g + 1]; pb.u[2] = cp[g + 2]; pb.u[3] = cp[g + 3];
            const int ch = t * 16 + hi * 8;
            bf16x8 vf0 = *(const bf16x8*)&Vts[buf][VSWZ(l31, ch)];
            bf16x8 vf1 = *(const bf16x8*)&Vts[buf][VSWZ(32 + l31, ch)];
            oacc0 = __builtin_amdgcn_mfma_f32_32x32x16_bf16(vf0, pb.v, oacc0, 0, 0, 0);
            oacc1 = __builtin_amdgcn_mfma_f32_32x32x16_bf16(vf1, pb.v, oacc1, 0, 0, 0);
        }
        __builtin_amdgcn_s_setprio(0);
        __syncthreads();
        buf ^= 1;
    }
#undef STAGE
#undef KSWZ
#undef VSWZ
    const float rl = 1.f / lrun;
    const int b2 = bh & 3, h2 = bh >> 2;
    const size_t rowbase = ((size_t)b2 * SEQ + q0 + l31) * D_MODEL + h2 * 64 + 4 * hi;
    #pragma unroll
    for (int df = 0; df < 2; ++df) {
        const f32x16& oa = df ? oacc1 : oacc0;
        #pragma unroll
        for (int rg = 0; rg < 4; ++rg) {
            ushort4 pk;
            pk.x = f2bf(oa[rg * 4 + 0] * rl);
            pk.y = f2bf(oa[rg * 4 + 1] * rl);
            pk.z = f2bf(oa[rg * 4 + 2] * rl);
            pk.w = f2bf(oa[rg * 4 + 3] * rl);
            *(ushort4*)&AF[rowbase + 32 * df + 8 * rg] = pk;
        }
    }
}

// ---------------- residual + LayerNorm ----------------
__global__ __launch_bounds__(256) void ln_kernel(const float* __restrict__ tmp,
                                                 const float* __restrict__ inp,
                                                 const float* __restrict__ g,
                                                 const float* __restrict__ bb,
                                                 float* __restrict__ out) {
    __shared__ float red[8];
    const int row = blockIdx.x, tid = threadIdx.x;
    float4 t = ((const float4*)(tmp + (size_t)row * D_MODEL))[tid];
    float4 rr = ((const float4*)(inp + (size_t)row * D_MODEL))[tid];
    float4 y;
    y.x = t.x + rr.x; y.y = t.y + rr.y; y.z = t.z + rr.z; y.w = t.w + rr.w;
    float sum = y.x + y.y + y.z + y.w;
    float sq = y.x * y.x + y.y * y.y + y.z * y.z + y.w * y.w;
    #pragma unroll
    for (int o = 1; o < 64; o <<= 1) { sum += __shfl_xor(sum, o); sq += __shfl_xor(sq, o); }
    int wid = tid >> 6, lane = tid & 63;
    if (lane == 0) { red[wid] = sum; red[4 + wid] = sq; }
    __syncthreads();
    sum = red[0] + red[1] + red[2] + red[3];
    sq = red[4] + red[5] + red[6] + red[7];
    float mu = sum * (1.f / D_MODEL);
    float var = sq * (1.f / D_MODEL) - mu * mu;
    float rs = rsqrtf(var + 1e-5f);
    float4 gg = ((const float4*)g)[tid];
    float4 bv = ((const float4*)bb)[tid];
    float4 o4;
    o4.x = (y.x - mu) * rs * gg.x + bv.x;
    o4.y = (y.y - mu) * rs * gg.y + bv.y;
    o4.z = (y.z - mu) * rs * gg.z + bv.z;
    o4.w = (y.w - mu) * rs * gg.w + bv.w;
    ((float4*)(out + (size_t)row * D_MODEL))[tid] = o4;
}

extern "C" void kernel_launch(void* const* d_in, const int* in_sizes, int n_in,
                              void* d_out, int out_size, void* d_ws, size_t ws_size,
                              hipStream_t stream) {
    const float* inp = (const float*)d_in[0];
    const int* amask = (const int*)d_in[1];
    const float* Wq = (const float*)d_in[2];
    const float* bq = (const float*)d_in[3];
    const float* Wk = (const float*)d_in[4];
    const float* bk = (const float*)d_in[5];
    const float* Wv = (const float*)d_in[6];
    const float* bv = (const float*)d_in[7];
    const float* Wo = (const float*)d_in[8];
    const float* lg = (const float*)d_in[9];
    const float* lb = (const float*)d_in[10];
    float* out = (float*)d_out;
    char* ws = (char*)d_ws;

    unsigned short* Xb     = (unsigned short*)(ws + 0);          //  8.0 MiB
    unsigned short* Wqkv_t = (unsigned short*)(ws + 8388608);    //  6.0 MiB
    unsigned short* Wo_t   = (unsigned short*)(ws + 14680064);   //  2.0 MiB
    unsigned short* Qb     = (unsigned short*)(ws + 16777216);   //  8.0 MiB
    unsigned short* Kb     = (unsigned short*)(ws + 25165824);   //  8.0 MiB
    unsigned short* Vt     = (unsigned short*)(ws + 33554432);   //  8.0 MiB  (V^T: [bh][d][s])
    unsigned short* AF     = (unsigned short*)(ws + 41943040);   //  8.0 MiB
    float*          tmp    = (float*)(ws + 50331648);            // 16.0 MiB
    unsigned long long* mwords = (unsigned long long*)(ws + 50331648);  // aliases tmp (dead until gemm_o)

    cvt_x<<<4096, 256, 0, stream>>>(inp, Xb);
    pack_mask<<<16, 256, 0, stream>>>(amask, mwords);
    transpose_w<<<dim3(32, 32, 4), dim3(32, 8), 0, stream>>>(Wq, Wk, Wv, Wo, Wqkv_t, Wo_t);
    gemm_qkv<<<768, 256, 0, stream>>>(Xb, Wqkv_t, bq, bk, bv, Qb, Kb, Vt);
    attn_kernel<<<512, 256, 0, stream>>>(Qb, Kb, Vt, mwords, AF);
    gemm_o<<<256, 256, 0, stream>>>(AF, Wo_t, tmp);
    ln_kernel<<<4096, 256, 0, stream>>>(tmp, inp, lg, lb, out);
}

// Round 9
// 108.156 us; speedup vs baseline: 1.7684x; 1.0658x over previous
//
#include <hip/hip_runtime.h>

typedef __attribute__((ext_vector_type(8))) short bf16x8;
typedef __attribute__((ext_vector_type(4))) float f32x4;
typedef __attribute__((ext_vector_type(16))) float f32x16;

#define D_MODEL 1024
#define SEQ 1024
#define NB 4
#define NH 16
#define DH 64
#define MROWS 4096

__device__ __forceinline__ unsigned short f2bf(float f) {
    union { float f; unsigned u; } x; x.f = f;
    unsigned r = x.u + 0x7fffu + ((x.u >> 16) & 1u);
    return (unsigned short)(r >> 16);
}

__device__ __forceinline__ void gload16(const void* g, void* l) {
    __builtin_amdgcn_global_load_lds((const __attribute__((address_space(1))) void*)g,
                                     (__attribute__((address_space(3))) void*)l, 16, 0, 0);
}

// exchange value with lane^32 via permlane32_swap (VALU-only, no LDS)
__device__ __forceinline__ float xhalf(float x, int hi) {
    float a = x, b = x;
    asm volatile("v_permlane32_swap_b32 %0, %1" : "+v"(a), "+v"(b));
    return hi ? b : a;
}

// ---------------- convert inp f32 -> bf16 ----------------
__global__ __launch_bounds__(256) void cvt_x(const float* __restrict__ x,
                                             unsigned short* __restrict__ o) {
    int i = blockIdx.x * 256 + threadIdx.x;
    float4 v = ((const float4*)x)[i];
    ushort4 r;
    r.x = f2bf(v.x); r.y = f2bf(v.y); r.z = f2bf(v.z); r.w = f2bf(v.w);
    ((ushort4*)o)[i] = r;
}

// ---------------- pack attn_mask -> 64-bit words per (b, 64-kv tile) via ballot ----------------
__global__ __launch_bounds__(256) void pack_mask(const int* __restrict__ amask,
                                                 unsigned long long* __restrict__ mwords) {
    int word = blockIdx.x * 4 + (threadIdx.x >> 6);   // grid 16 -> words 0..63
    int lane = threadIdx.x & 63;
    unsigned long long m = __ballot(amask[word * 64 + lane] != 0);
    if (lane == 0) mwords[word] = m;
}

// ---------------- transpose W (f32) -> bf16 W^T ----------------
__global__ __launch_bounds__(256) void transpose_w(const float* __restrict__ Wq,
                                                   const float* __restrict__ Wk,
                                                   const float* __restrict__ Wv,
                                                   const float* __restrict__ Wo,
                                                   unsigned short* __restrict__ Wqkv_t,
                                                   unsigned short* __restrict__ Wo_t) {
    __shared__ float tile[32][33];
    const int mtx = blockIdx.z;
    const float* src = mtx == 0 ? Wq : mtx == 1 ? Wk : mtx == 2 ? Wv : Wo;
    unsigned short* dst = mtx < 3 ? (Wqkv_t + (size_t)mtx * D_MODEL * D_MODEL) : Wo_t;
    const int n0 = blockIdx.x * 32, k0 = blockIdx.y * 32;
    const int tx = threadIdx.x, ty = threadIdx.y;
    #pragma unroll
    for (int i = 0; i < 32; i += 8)
        tile[ty + i][tx] = src[(size_t)(k0 + ty + i) * D_MODEL + n0 + tx];
    __syncthreads();
    #pragma unroll
    for (int i = 0; i < 32; i += 8)
        dst[(size_t)(n0 + ty + i) * D_MODEL + k0 + tx] = f2bf(tile[tx][ty + i]);
}

// Cs swizzled addressing: stride 128 shorts, XOR bits 3..5 of col with row&7
#define CSW(r, c) ((r) * 128 + ((c) ^ (((r) & 7) << 3)))

// ---------------- QKV GEMM: BK=64, double-buffered (prefetch t+1 during compute t) ----------------
__global__ __launch_bounds__(256) void gemm_qkv(const unsigned short* __restrict__ Xb,
                                                const unsigned short* __restrict__ Wt,
                                                const float* __restrict__ bq,
                                                const float* __restrict__ bk,
                                                const float* __restrict__ bv,
                                                unsigned short* __restrict__ Qb,
                                                unsigned short* __restrict__ Kb,
                                                unsigned short* __restrict__ Vt) {
    __shared__ unsigned short SM[32768];   // 64 KB: [buf][A 8192 | B 8192]; Cs aliases first 32 KB
    const int tid = threadIdx.x;
    const int lane = tid & 63, wid = tid >> 6;
    const int fr = lane & 15, fg = lane >> 4;
    const int wr = wid >> 1, wc = wid & 1;
    const int lin = blockIdx.x;
    const int x = lin & 7, i = lin >> 3;
    const int bxm = (x & 3) * 8 + (i & 7);
    const int byn = (x >> 2) * 12 + (i >> 3);
    const int m0 = bxm * 128, n0 = byn * 128;
    const unsigned short* Ag = Xb + (size_t)m0 * D_MODEL;
    const unsigned short* Bg = Wt + (size_t)n0 * D_MODEL;
    const int srow = tid >> 3;
    const int scol = 8 * ((tid & 7) ^ ((tid >> 3) & 7));
    f32x4 acc[4][4] = {};

#define QSTAGE(bf, kt2)                                                                   \
    {                                                                                     \
        const int kb = (kt2) * 64;                                                        \
        _Pragma("unroll")                                                                 \
        for (int j = 0; j < 4; ++j) {                                                     \
            int row = j * 32 + srow;                                                      \
            gload16(Ag + (size_t)row * D_MODEL + kb + scol, &SM[(bf) * 16384 + (j * 256 + tid) * 8]); \
            gload16(Bg + (size_t)row * D_MODEL + kb + scol, &SM[(bf) * 16384 + 8192 + (j * 256 + tid) * 8]); \
        }                                                                                 \
    }

    QSTAGE(0, 0);
    __syncthreads();
    int buf = 0;
    for (int kt = 0; kt < 16; ++kt) {
        if (kt < 15) QSTAGE(buf ^ 1, kt + 1);
        const unsigned short* As = &SM[buf * 16384];
        const unsigned short* Bs = &SM[buf * 16384 + 8192];
        #pragma unroll
        for (int ks = 0; ks < 2; ++ks) {
            bf16x8 af[4], bfv[4];
            #pragma unroll
            for (int m = 0; m < 4; ++m) {
                int row = wr * 64 + m * 16 + fr;
                af[m] = *(const bf16x8*)&As[row * 64 + ((ks * 32 + fg * 8) ^ ((row & 7) * 8))];
            }
            #pragma unroll
            for (int n = 0; n < 4; ++n) {
                int row = wc * 64 + n * 16 + fr;
                bfv[n] = *(const bf16x8*)&Bs[row * 64 + ((ks * 32 + fg * 8) ^ ((row & 7) * 8))];
            }
            __builtin_amdgcn_s_setprio(1);
            #pragma unroll
            for (int m = 0; m < 4; ++m)
                #pragma unroll
                for (int n = 0; n < 4; ++n)
                    acc[m][n] = __builtin_amdgcn_mfma_f32_16x16x32_bf16(af[m], bfv[n], acc[m][n], 0, 0, 0);
            __builtin_amdgcn_s_setprio(0);
        }
        __syncthreads();   // drains prefetch + orders reads before buf reuse
        buf ^= 1;
    }
#undef QSTAGE
    unsigned short* Cs = SM;
    const int sel = n0 >> 10;
    const int npb = n0 & 1023;
    if (sel < 2) {
        #pragma unroll
        for (int n = 0; n < 4; ++n) {
            int cn = wc * 64 + n * 16 + fr;
            float bias = (sel == 0 ? bq : bk)[npb + cn];
            #pragma unroll
            for (int m = 0; m < 4; ++m)
                #pragma unroll
                for (int r = 0; r < 4; ++r) {
                    int row = wr * 64 + m * 16 + fg * 4 + r;
                    Cs[CSW(row, cn)] = f2bf(acc[m][n][r] + bias);
                }
        }
        __syncthreads();
        unsigned short* dst = sel == 0 ? Qb : Kb;
        #pragma unroll
        for (int k = 0; k < 8; ++k) {
            int c = k * 256 + tid;
            int row = c >> 4, cc = c & 15;
            int np = npb + cc * 8;
            int h = np >> 6, d = np & 63;
            int gm = m0 + row, b = gm >> 10, s = gm & 1023;
            bf16x8 v = *(const bf16x8*)&Cs[CSW(row, cc * 8)];
            *(bf16x8*)&dst[((size_t)(b * NH + h) * SEQ + s) * DH + d] = v;
        }
    } else {
        #pragma unroll
        for (int n = 0; n < 4; ++n) {
            int cn = wc * 64 + n * 16 + fr;
            float bias = bv[npb + cn];
            #pragma unroll
            for (int m = 0; m < 4; ++m)
                #pragma unroll
                for (int r = 0; r < 4; ++r) {
                    int row = wr * 64 + m * 16 + fg * 4 + r;   // s index
                    Cs[CSW(cn, row)] = f2bf(acc[m][n][r] + bias);
                }
        }
        __syncthreads();
        #pragma unroll
        for (int k = 0; k < 8; ++k) {
            int c = k * 256 + tid;
            int dcol = c >> 4, scc = c & 15;
            int np = npb + dcol;
            int h = np >> 6, dd = np & 63;
            int gm0 = m0 + scc * 8, b = gm0 >> 10, s0 = gm0 & 1023;
            bf16x8 v = *(const bf16x8*)&Cs[CSW(dcol, scc * 8)];
            *(bf16x8*)&Vt[((size_t)(b * NH + h) * DH + dd) * SEQ + s0] = v;
        }
    }
}

// ---------------- O-proj GEMM: BK=64, double-buffered ----------------
__global__ __launch_bounds__(256) void gemm_o(const unsigned short* __restrict__ Ab,
                                              const unsigned short* __restrict__ Wt,
                                              float* __restrict__ tmp) {
    __shared__ unsigned short SM[32768];   // 64 KB dbuf
    const int tid = threadIdx.x;
    const int lane = tid & 63, wid = tid >> 6;
    const int fr = lane & 15, fg = lane >> 4;
    const int wr = wid >> 1, wc = wid & 1;
    const int lin = blockIdx.x;
    const int x = lin & 7, i = lin >> 3;
    const int bxm = (x & 3) * 8 + (i & 7);
    const int byn = (x >> 2) * 4 + (i >> 3);
    const int m0 = bxm * 128, n0 = byn * 128;
    const unsigned short* Ag = Ab + (size_t)m0 * D_MODEL;
    const unsigned short* Bg = Wt + (size_t)n0 * D_MODEL;
    const int srow = tid >> 3;
    const int scol = 8 * ((tid & 7) ^ ((tid >> 3) & 7));
    f32x4 acc[4][4] = {};

#define OSTAGE(bf, kt2)                                                                   \
    {                                                                                     \
        const int kb = (kt2) * 64;                                                        \
        _Pragma("unroll")                                                                 \
        for (int j = 0; j < 4; ++j) {                                                     \
            int row = j * 32 + srow;                                                      \
            gload16(Ag + (size_t)row * D_MODEL + kb + scol, &SM[(bf) * 16384 + (j * 256 + tid) * 8]); \
            gload16(Bg + (size_t)row * D_MODEL + kb + scol, &SM[(bf) * 16384 + 8192 + (j * 256 + tid) * 8]); \
        }                                                                                 \
    }

    OSTAGE(0, 0);
    __syncthreads();
    int buf = 0;
    for (int kt = 0; kt < 16; ++kt) {
        if (kt < 15) OSTAGE(buf ^ 1, kt + 1);
        const unsigned short* As = &SM[buf * 16384];
        const unsigned short* Bs = &SM[buf * 16384 + 8192];
        #pragma unroll
        for (int ks = 0; ks < 2; ++ks) {
            bf16x8 af[4], bfv[4];
            #pragma unroll
            for (int m = 0; m < 4; ++m) {
                int row = wr * 64 + m * 16 + fr;
                af[m] = *(const bf16x8*)&As[row * 64 + ((ks * 32 + fg * 8) ^ ((row & 7) * 8))];
            }
            #pragma unroll
            for (int n = 0; n < 4; ++n) {
                int row = wc * 64 + n * 16 + fr;
                bfv[n] = *(const bf16x8*)&Bs[row * 64 + ((ks * 32 + fg * 8) ^ ((row & 7) * 8))];
            }
            __builtin_amdgcn_s_setprio(1);
            #pragma unroll
            for (int m = 0; m < 4; ++m)
                #pragma unroll
                for (int n = 0; n < 4; ++n)
                    acc[m][n] = __builtin_amdgcn_mfma_f32_16x16x32_bf16(af[m], bfv[n], acc[m][n], 0, 0, 0);
            __builtin_amdgcn_s_setprio(0);
        }
        __syncthreads();
        buf ^= 1;
    }
#undef OSTAGE
    #pragma unroll
    for (int n = 0; n < 4; ++n) {
        int gn = n0 + wc * 64 + n * 16 + fr;
        #pragma unroll
        for (int m = 0; m < 4; ++m) {
            #pragma unroll
            for (int r = 0; r < 4; ++r) {
                int gm = m0 + wr * 64 + m * 16 + fg * 4 + r;
                tmp[(size_t)gm * D_MODEL + gn] = acc[m][n][r];
            }
        }
    }
}

// ---------------- flash attention: KVBLK=128, in-register softmax ----------------
// Mask applied as K-side bias MFMA (masked raw score -= 798720 -> exp2 underflows to 0);
// row-sum (lrun) accumulated on the matrix pipe via mfma(ones, P) running across tiles.
__global__ __launch_bounds__(256, 2) void attn_kernel(const unsigned short* __restrict__ Qb,
                                                      const unsigned short* __restrict__ Kb,
                                                      const unsigned short* __restrict__ Vt,
                                                      const unsigned long long* __restrict__ mwords,
                                                      unsigned short* __restrict__ AF) {
    __shared__ unsigned short Ks[2][128 * 64];   // [kv][d]
    __shared__ unsigned short Vts[2][64 * 128];  // [d][kv]
    const int tid = threadIdx.x, lane = tid & 63, wid = tid >> 6;
    const int l31 = lane & 31, hi = lane >> 5;
    const int lin = blockIdx.x;
    const int x = lin & 7, i = lin >> 3;
    const int qt = i & 7, bh = x * 8 + (i >> 3);
    const int b = bh >> 4;
    const unsigned short* Qh = Qb + (size_t)bh * SEQ * DH;
    const unsigned short* Kh = Kb + (size_t)bh * SEQ * DH;
    const unsigned short* Vth = Vt + (size_t)bh * DH * SEQ;
    const unsigned long long* mwb = mwords + b * 16;
    const int q0 = qt * 128 + wid * 32;

    const int k_row = wid * 32 + (lane >> 3);
    const int k_col = 8 * ((lane & 7) ^ ((lane >> 3) & 7));
    const int v_rowb = wid * 16 + (lane >> 4);

    bf16x8 qf[4];
    #pragma unroll
    for (int ks = 0; ks < 4; ++ks)
        qf[ks] = *(const bf16x8*)(Qh + (size_t)(q0 + l31) * DH + ks * 16 + hi * 8);

    union U4 { unsigned u[4]; bf16x8 v; };
    U4 ones;
    ones.u[0] = 0x3F803F80u; ones.u[1] = 0x3F803F80u;
    ones.u[2] = 0x3F803F80u; ones.u[3] = 0x3F803F80u;

    f32x16 oacc0 = {}, oacc1 = {};
    f32x16 sacc = {};                // running P row-sum (all 16 regs identical)
    float mrun = -3.0e38f;
    const float C2 = 0.18033688f;    // 0.125 * log2(e)

#define KSWZ(row, colsh) ((row) * 64 + ((colsh) ^ (((row) & 7) << 3)))
#define VSWZ(row, colsh) ((row) * 128 + ((colsh) ^ (((row) & 7) << 3)))
#define STAGE(bufi, kt2)                                                                  \
    {                                                                                     \
        const int kv0s = (kt2) * 128;                                                     \
        _Pragma("unroll")                                                                 \
        for (int j = 0; j < 4; ++j)                                                       \
            gload16(Kh + (size_t)(kv0s + k_row + j * 8) * DH + k_col,                     \
                    &Ks[bufi][wid * 2048 + j * 512]);                                     \
        _Pragma("unroll")                                                                 \
        for (int j = 0; j < 4; ++j) {                                                     \
            const int vr = v_rowb + j * 4;                                                \
            gload16(Vth + (size_t)vr * SEQ + kv0s + 8 * ((lane & 15) ^ (vr & 7)),         \
                    &Vts[bufi][wid * 2048 + j * 512]);                                    \
        }                                                                                 \
    }

    STAGE(0, 0);
    __syncthreads();
    int buf = 0;
    for (int kt = 0; kt < 8; ++kt) {
        if (kt < 7) STAGE(buf ^ 1, kt + 1);
        const unsigned long long mwA = mwb[2 * kt], mwB = mwb[2 * kt + 1];
        const unsigned mr0 = (unsigned)mwA, mr1 = (unsigned)(mwA >> 32);
        const unsigned mr2 = (unsigned)mwB, mr3 = (unsigned)(mwB >> 32);
        // QK^T over 128 kv rows
        f32x16 sA0 = {}, sA1 = {}, sB0 = {}, sB1 = {};
        __builtin_amdgcn_s_setprio(1);
        #pragma unroll
        for (int ks = 0; ks < 4; ++ks) {
            const int ch = ks * 16 + hi * 8;
            bf16x8 k0 = *(const bf16x8*)&Ks[buf][KSWZ(l31, ch)];
            bf16x8 k1 = *(const bf16x8*)&Ks[buf][KSWZ(32 + l31, ch)];
            bf16x8 k2 = *(const bf16x8*)&Ks[buf][KSWZ(64 + l31, ch)];
            bf16x8 k3 = *(const bf16x8*)&Ks[buf][KSWZ(96 + l31, ch)];
            sA0 = __builtin_amdgcn_mfma_f32_32x32x16_bf16(k0, qf[ks], sA0, 0, 0, 0);
            sA1 = __builtin_amdgcn_mfma_f32_32x32x16_bf16(k1, qf[ks], sA1, 0, 0, 0);
            sB0 = __builtin_amdgcn_mfma_f32_32x32x16_bf16(k2, qf[ks], sB0, 0, 0, 0);
            sB1 = __builtin_amdgcn_mfma_f32_32x32x16_bf16(k3, qf[ks], sB1, 0, 0, 0);
        }
        // mask bias: A[kv][0] = mask ? -798720 : 0 (bf16 0xC943), B = ones -> s += bias
        {
            U4 ab; ab.u[1] = 0; ab.u[2] = 0; ab.u[3] = 0;
            unsigned bv;
            bv = ((mr0 >> l31) & 1u) ? 0xC943u : 0u; ab.u[0] = hi ? 0u : bv;
            sA0 = __builtin_amdgcn_mfma_f32_32x32x16_bf16(ab.v, ones.v, sA0, 0, 0, 0);
            bv = ((mr1 >> l31) & 1u) ? 0xC943u : 0u; ab.u[0] = hi ? 0u : bv;
            sA1 = __builtin_amdgcn_mfma_f32_32x32x16_bf16(ab.v, ones.v, sA1, 0, 0, 0);
            bv = ((mr2 >> l31) & 1u) ? 0xC943u : 0u; ab.u[0] = hi ? 0u : bv;
            sB0 = __builtin_amdgcn_mfma_f32_32x32x16_bf16(ab.v, ones.v, sB0, 0, 0, 0);
            bv = ((mr3 >> l31) & 1u) ? 0xC943u : 0u; ab.u[0] = hi ? 0u : bv;
            sB1 = __builtin_amdgcn_mfma_f32_32x32x16_bf16(ab.v, ones.v, sB1, 0, 0, 0);
        }
        __builtin_amdgcn_s_setprio(0);
        // row max (tree; compiler fuses to max3)
        float tm[16];
        #pragma unroll
        for (int r2 = 0; r2 < 16; ++r2)
            tm[r2] = fmaxf(fmaxf(sA0[r2], sA1[r2]), fmaxf(sB0[r2], sB1[r2]));
        #pragma unroll
        for (int st = 8; st; st >>= 1)
            #pragma unroll
            for (int r2 = 0; r2 < st; ++r2)
                tm[r2] = fmaxf(tm[r2], tm[r2 + st]);
        float m = tm[0];
        m = fmaxf(m, xhalf(m, hi));
        float mt = m * C2;
        if (!__all(mt <= mrun + 11.5f)) {   // defer-max (T13)
            float newm = fmaxf(mrun, mt);
            float corr = exp2f(mrun - newm);
            #pragma unroll
            for (int r2 = 0; r2 < 16; ++r2) {
                oacc0[r2] *= corr; oacc1[r2] *= corr; sacc[r2] *= corr;
            }
            mrun = newm;
        }
        // P = exp2(s*C2 - mrun); masked entries underflow to 0
        #pragma unroll
        for (int r2 = 0; r2 < 16; ++r2) {
            sA0[r2] = exp2f(fmaf(sA0[r2], C2, -mrun));
            sA1[r2] = exp2f(fmaf(sA1[r2], C2, -mrun));
            sB0[r2] = exp2f(fmaf(sB0[r2], C2, -mrun));
            sB1[r2] = exp2f(fmaf(sB1[r2], C2, -mrun));
        }
        // P -> bf16 B-operand fragments (cvt_pk + permlane32_swap)
        unsigned cA0[8], cA1[8], cB0[8], cB1[8];
        #pragma unroll
        for (int ii = 0; ii < 8; ++ii) {
            asm volatile("v_cvt_pk_bf16_f32 %0, %1, %2" : "=v"(cA0[ii]) : "v"(sA0[2 * ii]), "v"(sA0[2 * ii + 1]));
            asm volatile("v_cvt_pk_bf16_f32 %0, %1, %2" : "=v"(cA1[ii]) : "v"(sA1[2 * ii]), "v"(sA1[2 * ii + 1]));
            asm volatile("v_cvt_pk_bf16_f32 %0, %1, %2" : "=v"(cB0[ii]) : "v"(sB0[2 * ii]), "v"(sB0[2 * ii + 1]));
            asm volatile("v_cvt_pk_bf16_f32 %0, %1, %2" : "=v"(cB1[ii]) : "v"(sB1[2 * ii]), "v"(sB1[2 * ii + 1]));
        }
        #pragma unroll
        for (int g = 0; g < 8; g += 4) {
            asm volatile("v_permlane32_swap_b32 %0, %1" : "+v"(cA0[g + 0]), "+v"(cA0[g + 2]));
            asm volatile("v_permlane32_swap_b32 %0, %1" : "+v"(cA0[g + 1]), "+v"(cA0[g + 3]));
            asm volatile("v_permlane32_swap_b32 %0, %1" : "+v"(cA1[g + 0]), "+v"(cA1[g + 2]));
            asm volatile("v_permlane32_swap_b32 %0, %1" : "+v"(cA1[g + 1]), "+v"(cA1[g + 3]));
            asm volatile("v_permlane32_swap_b32 %0, %1" : "+v"(cB0[g + 0]), "+v"(cB0[g + 2]));
            asm volatile("v_permlane32_swap_b32 %0, %1" : "+v"(cB0[g + 1]), "+v"(cB0[g + 3]));
            asm volatile("v_permlane32_swap_b32 %0, %1" : "+v"(cB1[g + 0]), "+v"(cB1[g + 2]));
            asm volatile("v_permlane32_swap_b32 %0, %1" : "+v"(cB1[g + 1]), "+v"(cB1[g + 3]));
        }
        // PV + ones-sum: 8 k-steps of 16 kv
        __builtin_amdgcn_s_setprio(1);
        #pragma unroll
        for (int t = 0; t < 8; ++t) {
            const unsigned* cp = (t < 2) ? cA0 : (t < 4) ? cA1 : (t < 6) ? cB0 : cB1;
            const int g = (t & 1) * 4;
            U4 pb;
            pb.u[0] = cp[g + 0]; pb.u[1] = cp[g + 1]; pb.u[2] = cp[g + 2]; pb.u[3] = cp[g + 3];
            const int ch = t * 16 + hi * 8;
            bf16x8 vf0 = *(const bf16x8*)&Vts[buf][VSWZ(l31, ch)];
            bf16x8 vf1 = *(const bf16x8*)&Vts[buf][VSWZ(32 + l31, ch)];
            oacc0 = __builtin_amdgcn_mfma_f32_32x32x16_bf16(vf0, pb.v, oacc0, 0, 0, 0);
            oacc1 = __builtin_amdgcn_mfma_f32_32x32x16_bf16(vf1, pb.v, oacc1, 0, 0, 0);
            sacc  = __builtin_amdgcn_mfma_f32_32x32x16_bf16(ones.v, pb.v, sacc, 0, 0, 0);
        }
        __builtin_amdgcn_s_setprio(0);
        __syncthreads();
        buf ^= 1;
    }
#undef STAGE
#undef KSWZ
#undef VSWZ
    const float rl = 1.f / sacc[0];
    const int b2 = bh & 3, h2 = bh >> 2;   // faithful-to-torch head scramble
    const size_t rowbase = ((size_t)b2 * SEQ + q0 + l31) * D_MODEL + h2 * 64 + 4 * hi;
    #pragma unroll
    for (int df = 0; df < 2; ++df) {
        const f32x16& oa = df ? oacc1 : oacc0;
        #pragma unroll
        for (int rg = 0; rg < 4; ++rg) {
            ushort4 pk;
            pk.x = f2bf(oa[rg * 4 + 0] * rl);
            pk.y = f2bf(oa[rg * 4 + 1] * rl);
            pk.z = f2bf(oa[rg * 4 + 2] * rl);
            pk.w = f2bf(oa[rg * 4 + 3] * rl);
            *(ushort4*)&AF[rowbase + 32 * df + 8 * rg] = pk;
        }
    }
}

// ---------------- residual + LayerNorm ----------------
__global__ __launch_bounds__(256) void ln_kernel(const float* __restrict__ tmp,
                                                 const float* __restrict__ inp,
                                                 const float* __restrict__ g,
                                                 const float* __restrict__ bb,
                                                 float* __restrict__ out) {
    __shared__ float red[8];
    const int row = blockIdx.x, tid = threadIdx.x;
    float4 t = ((const float4*)(tmp + (size_t)row * D_MODEL))[tid];
    float4 rr = ((const float4*)(inp + (size_t)row * D_MODEL))[tid];
    float4 y;
    y.x = t.x + rr.x; y.y = t.y + rr.y; y.z = t.z + rr.z; y.w = t.w + rr.w;
    float sum = y.x + y.y + y.z + y.w;
    float sq = y.x * y.x + y.y * y.y + y.z * y.z + y.w * y.w;
    #pragma unroll
    for (int o = 1; o < 64; o <<= 1) { sum += __shfl_xor(sum, o); sq += __shfl_xor(sq, o); }
    int wid = tid >> 6, lane = tid & 63;
    if (lane == 0) { red[wid] = sum; red[4 + wid] = sq; }
    __syncthreads();
    sum = red[0] + red[1] + red[2] + red[3];
    sq = red[4] + red[5] + red[6] + red[7];
    float mu = sum * (1.f / D_MODEL);
    float var = sq * (1.f / D_MODEL) - mu * mu;
    float rs = rsqrtf(var + 1e-5f);
    float4 gg = ((const float4*)g)[tid];
    float4 bv = ((const float4*)bb)[tid];
    float4 o4;
    o4.x = (y.x - mu) * rs * gg.x + bv.x;
    o4.y = (y.y - mu) * rs * gg.y + bv.y;
    o4.z = (y.z - mu) * rs * gg.z + bv.z;
    o4.w = (y.w - mu) * rs * gg.w + bv.w;
    ((float4*)(out + (size_t)row * D_MODEL))[tid] = o4;
}

extern "C" void kernel_launch(void* const* d_in, const int* in_sizes, int n_in,
                              void* d_out, int out_size, void* d_ws, size_t ws_size,
                              hipStream_t stream) {
    const float* inp = (const float*)d_in[0];
    const int* amask = (const int*)d_in[1];
    const float* Wq = (const float*)d_in[2];
    const float* bq = (const float*)d_in[3];
    const float* Wk = (const float*)d_in[4];
    const float* bk = (const float*)d_in[5];
    const float* Wv = (const float*)d_in[6];
    const float* bv = (const float*)d_in[7];
    const float* Wo = (const float*)d_in[8];
    const float* lg = (const float*)d_in[9];
    const float* lb = (const float*)d_in[10];
    float* out = (float*)d_out;
    char* ws = (char*)d_ws;

    unsigned short* Xb     = (unsigned short*)(ws + 0);          //  8.0 MiB
    unsigned short* Wqkv_t = (unsigned short*)(ws + 8388608);    //  6.0 MiB
    unsigned short* Wo_t   = (unsigned short*)(ws + 14680064);   //  2.0 MiB
    unsigned short* Qb     = (unsigned short*)(ws + 16777216);   //  8.0 MiB
    unsigned short* Kb     = (unsigned short*)(ws + 25165824);   //  8.0 MiB
    unsigned short* Vt     = (unsigned short*)(ws + 33554432);   //  8.0 MiB  (V^T: [bh][d][s])
    unsigned short* AF     = (unsigned short*)(ws + 41943040);   //  8.0 MiB
    float*          tmp    = (float*)(ws + 50331648);            // 16.0 MiB
    unsigned long long* mwords = (unsigned long long*)(ws + 50331648);  // aliases tmp (dead until gemm_o)

    cvt_x<<<4096, 256, 0, stream>>>(inp, Xb);
    pack_mask<<<16, 256, 0, stream>>>(amask, mwords);
    transpose_w<<<dim3(32, 32, 4), dim3(32, 8), 0, stream>>>(Wq, Wk, Wv, Wo, Wqkv_t, Wo_t);
    gemm_qkv<<<768, 256, 0, stream>>>(Xb, Wqkv_t, bq, bk, bv, Qb, Kb, Vt);
    attn_kernel<<<512, 256, 0, stream>>>(Qb, Kb, Vt, mwords, AF);
    gemm_o<<<256, 256, 0, stream>>>(AF, Wo_t, tmp);
    ln_kernel<<<4096, 256, 0, stream>>>(tmp, inp, lg, lb, out);
}

// Round 10
// 101.438 us; speedup vs baseline: 1.8855x; 1.0662x over previous
//
#include <hip/hip_runtime.h>

typedef __attribute__((ext_vector_type(8))) short bf16x8;
typedef __attribute__((ext_vector_type(4))) float f32x4;
typedef __attribute__((ext_vector_type(16))) float f32x16;

#define D_MODEL 1024
#define SEQ 1024
#define NB 4
#define NH 16
#define DH 64
#define MROWS 4096

__device__ __forceinline__ unsigned short f2bf(float f) {
    union { float f; unsigned u; } x; x.f = f;
    unsigned r = x.u + 0x7fffu + ((x.u >> 16) & 1u);
    return (unsigned short)(r >> 16);
}

__device__ __forceinline__ float bf2f(unsigned short u) {
    union { unsigned u; float f; } x; x.u = (unsigned)u << 16;
    return x.f;
}

__device__ __forceinline__ void gload16(const void* g, void* l) {
    __builtin_amdgcn_global_load_lds((const __attribute__((address_space(1))) void*)g,
                                     (__attribute__((address_space(3))) void*)l, 16, 0, 0);
}

// exchange value with lane^32 via permlane32_swap (VALU-only, no LDS)
__device__ __forceinline__ float xhalf(float x, int hi) {
    float a = x, b = x;
    asm volatile("v_permlane32_swap_b32 %0, %1" : "+v"(a), "+v"(b));
    return hi ? b : a;
}

// ---------------- fused preprocessing: cvt_x | transpose_w | pack_mask ----------------
__global__ __launch_bounds__(256) void prep(const float* __restrict__ x,
                                            unsigned short* __restrict__ Xb,
                                            const int* __restrict__ amask,
                                            unsigned long long* __restrict__ mwords,
                                            const float* __restrict__ Wq,
                                            const float* __restrict__ Wk,
                                            const float* __restrict__ Wv,
                                            const float* __restrict__ Wo,
                                            unsigned short* __restrict__ Wqkv_t,
                                            unsigned short* __restrict__ Wo_t) {
    __shared__ float tile[32][33];
    const int bid = blockIdx.x, tid = threadIdx.x;
    if (bid < 4096) {
        // cast inp f32 -> bf16
        int i = bid * 256 + tid;
        float4 v = ((const float4*)x)[i];
        ushort4 r;
        r.x = f2bf(v.x); r.y = f2bf(v.y); r.z = f2bf(v.z); r.w = f2bf(v.w);
        ((ushort4*)Xb)[i] = r;
    } else if (bid < 8192) {
        // transpose W f32 -> bf16 W^T
        int t = bid - 4096;
        const int mtx = t >> 10, t10 = t & 1023;
        const float* src = mtx == 0 ? Wq : mtx == 1 ? Wk : mtx == 2 ? Wv : Wo;
        unsigned short* dst = mtx < 3 ? (Wqkv_t + (size_t)mtx * D_MODEL * D_MODEL) : Wo_t;
        const int n0 = (t10 & 31) * 32, k0 = (t10 >> 5) * 32;
        const int tx = tid & 31, ty = tid >> 5;   // 32 x 8
        #pragma unroll
        for (int i = 0; i < 32; i += 8)
            tile[ty + i][tx] = src[(size_t)(k0 + ty + i) * D_MODEL + n0 + tx];
        __syncthreads();
        #pragma unroll
        for (int i = 0; i < 32; i += 8)
            dst[(size_t)(n0 + ty + i) * D_MODEL + k0 + tx] = f2bf(tile[tx][ty + i]);
    } else {
        // pack attn_mask -> 64-bit words per (b, 64-kv tile)
        int word = (bid - 8192) * 4 + (tid >> 6);
        int lane = tid & 63;
        unsigned long long m = __ballot(amask[word * 64 + lane] != 0);
        if (lane == 0) mwords[word] = m;
    }
}

// Cs swizzled addressing: stride 128 shorts, XOR bits 3..5 of col with row&7
#define CSW(r, c) ((r) * 128 + ((c) ^ (((r) & 7) << 3)))

// ---------------- QKV GEMM: BK=64, double-buffered (prefetch t+1 during compute t) ----------------
__global__ __launch_bounds__(256) void gemm_qkv(const unsigned short* __restrict__ Xb,
                                                const unsigned short* __restrict__ Wt,
                                                const float* __restrict__ bq,
                                                const float* __restrict__ bk,
                                                const float* __restrict__ bv,
                                                unsigned short* __restrict__ Qb,
                                                unsigned short* __restrict__ Kb,
                                                unsigned short* __restrict__ Vt) {
    __shared__ unsigned short SM[32768];   // 64 KB: [buf][A 8192 | B 8192]; Cs aliases first 32 KB
    const int tid = threadIdx.x;
    const int lane = tid & 63, wid = tid >> 6;
    const int fr = lane & 15, fg = lane >> 4;
    const int wr = wid >> 1, wc = wid & 1;
    const int lin = blockIdx.x;
    const int x = lin & 7, i = lin >> 3;
    const int bxm = (x & 3) * 8 + (i & 7);
    const int byn = (x >> 2) * 12 + (i >> 3);
    const int m0 = bxm * 128, n0 = byn * 128;
    const unsigned short* Ag = Xb + (size_t)m0 * D_MODEL;
    const unsigned short* Bg = Wt + (size_t)n0 * D_MODEL;
    const int srow = tid >> 3;
    const int scol = 8 * ((tid & 7) ^ ((tid >> 3) & 7));
    f32x4 acc[4][4] = {};

#define QSTAGE(bf, kt2)                                                                   \
    {                                                                                     \
        const int kb = (kt2) * 64;                                                        \
        _Pragma("unroll")                                                                 \
        for (int j = 0; j < 4; ++j) {                                                     \
            int row = j * 32 + srow;                                                      \
            gload16(Ag + (size_t)row * D_MODEL + kb + scol, &SM[(bf) * 16384 + (j * 256 + tid) * 8]); \
            gload16(Bg + (size_t)row * D_MODEL + kb + scol, &SM[(bf) * 16384 + 8192 + (j * 256 + tid) * 8]); \
        }                                                                                 \
    }

    QSTAGE(0, 0);
    __syncthreads();
    int buf = 0;
    for (int kt = 0; kt < 16; ++kt) {
        if (kt < 15) QSTAGE(buf ^ 1, kt + 1);
        const unsigned short* As = &SM[buf * 16384];
        const unsigned short* Bs = &SM[buf * 16384 + 8192];
        #pragma unroll
        for (int ks = 0; ks < 2; ++ks) {
            bf16x8 af[4], bfv[4];
            #pragma unroll
            for (int m = 0; m < 4; ++m) {
                int row = wr * 64 + m * 16 + fr;
                af[m] = *(const bf16x8*)&As[row * 64 + ((ks * 32 + fg * 8) ^ ((row & 7) * 8))];
            }
            #pragma unroll
            for (int n = 0; n < 4; ++n) {
                int row = wc * 64 + n * 16 + fr;
                bfv[n] = *(const bf16x8*)&Bs[row * 64 + ((ks * 32 + fg * 8) ^ ((row & 7) * 8))];
            }
            __builtin_amdgcn_s_setprio(1);
            #pragma unroll
            for (int m = 0; m < 4; ++m)
                #pragma unroll
                for (int n = 0; n < 4; ++n)
                    acc[m][n] = __builtin_amdgcn_mfma_f32_16x16x32_bf16(af[m], bfv[n], acc[m][n], 0, 0, 0);
            __builtin_amdgcn_s_setprio(0);
        }
        __syncthreads();   // drains prefetch + orders reads before buf reuse
        buf ^= 1;
    }
#undef QSTAGE
    unsigned short* Cs = SM;
    const int sel = n0 >> 10;
    const int npb = n0 & 1023;
    if (sel < 2) {
        #pragma unroll
        for (int n = 0; n < 4; ++n) {
            int cn = wc * 64 + n * 16 + fr;
            float bias = (sel == 0 ? bq : bk)[npb + cn];
            #pragma unroll
            for (int m = 0; m < 4; ++m)
                #pragma unroll
                for (int r = 0; r < 4; ++r) {
                    int row = wr * 64 + m * 16 + fg * 4 + r;
                    Cs[CSW(row, cn)] = f2bf(acc[m][n][r] + bias);
                }
        }
        __syncthreads();
        unsigned short* dst = sel == 0 ? Qb : Kb;
        #pragma unroll
        for (int k = 0; k < 8; ++k) {
            int c = k * 256 + tid;
            int row = c >> 4, cc = c & 15;
            int np = npb + cc * 8;
            int h = np >> 6, d = np & 63;
            int gm = m0 + row, b = gm >> 10, s = gm & 1023;
            bf16x8 v = *(const bf16x8*)&Cs[CSW(row, cc * 8)];
            *(bf16x8*)&dst[((size_t)(b * NH + h) * SEQ + s) * DH + d] = v;
        }
    } else {
        #pragma unroll
        for (int n = 0; n < 4; ++n) {
            int cn = wc * 64 + n * 16 + fr;
            float bias = bv[npb + cn];
            #pragma unroll
            for (int m = 0; m < 4; ++m)
                #pragma unroll
                for (int r = 0; r < 4; ++r) {
                    int row = wr * 64 + m * 16 + fg * 4 + r;   // s index
                    Cs[CSW(cn, row)] = f2bf(acc[m][n][r] + bias);
                }
        }
        __syncthreads();
        #pragma unroll
        for (int k = 0; k < 8; ++k) {
            int c = k * 256 + tid;
            int dcol = c >> 4, scc = c & 15;
            int np = npb + dcol;
            int h = np >> 6, dd = np & 63;
            int gm0 = m0 + scc * 8, b = gm0 >> 10, s0 = gm0 & 1023;
            bf16x8 v = *(const bf16x8*)&Cs[CSW(dcol, scc * 8)];
            *(bf16x8*)&Vt[((size_t)(b * NH + h) * DH + dd) * SEQ + s0] = v;
        }
    }
}

// ---------------- O-proj GEMM: BK=64, double-buffered, bf16 output via swizzled Cs ----------------
__global__ __launch_bounds__(256) void gemm_o(const unsigned short* __restrict__ Ab,
                                              const unsigned short* __restrict__ Wt,
                                              unsigned short* __restrict__ tmpb) {
    __shared__ unsigned short SM[32768];   // 64 KB dbuf; Cs aliases first 32 KB
    const int tid = threadIdx.x;
    const int lane = tid & 63, wid = tid >> 6;
    const int fr = lane & 15, fg = lane >> 4;
    const int wr = wid >> 1, wc = wid & 1;
    const int lin = blockIdx.x;
    const int x = lin & 7, i = lin >> 3;
    const int bxm = (x & 3) * 8 + (i & 7);
    const int byn = (x >> 2) * 4 + (i >> 3);
    const int m0 = bxm * 128, n0 = byn * 128;
    const unsigned short* Ag = Ab + (size_t)m0 * D_MODEL;
    const unsigned short* Bg = Wt + (size_t)n0 * D_MODEL;
    const int srow = tid >> 3;
    const int scol = 8 * ((tid & 7) ^ ((tid >> 3) & 7));
    f32x4 acc[4][4] = {};

#define OSTAGE(bf, kt2)                                                                   \
    {                                                                                     \
        const int kb = (kt2) * 64;                                                        \
        _Pragma("unroll")                                                                 \
        for (int j = 0; j < 4; ++j) {                                                     \
            int row = j * 32 + srow;                                                      \
            gload16(Ag + (size_t)row * D_MODEL + kb + scol, &SM[(bf) * 16384 + (j * 256 + tid) * 8]); \
            gload16(Bg + (size_t)row * D_MODEL + kb + scol, &SM[(bf) * 16384 + 8192 + (j * 256 + tid) * 8]); \
        }                                                                                 \
    }

    OSTAGE(0, 0);
    __syncthreads();
    int buf = 0;
    for (int kt = 0; kt < 16; ++kt) {
        if (kt < 15) OSTAGE(buf ^ 1, kt + 1);
        const unsigned short* As = &SM[buf * 16384];
        const unsigned short* Bs = &SM[buf * 16384 + 8192];
        #pragma unroll
        for (int ks = 0; ks < 2; ++ks) {
            bf16x8 af[4], bfv[4];
            #pragma unroll
            for (int m = 0; m < 4; ++m) {
                int row = wr * 64 + m * 16 + fr;
                af[m] = *(const bf16x8*)&As[row * 64 + ((ks * 32 + fg * 8) ^ ((row & 7) * 8))];
            }
            #pragma unroll
            for (int n = 0; n < 4; ++n) {
                int row = wc * 64 + n * 16 + fr;
                bfv[n] = *(const bf16x8*)&Bs[row * 64 + ((ks * 32 + fg * 8) ^ ((row & 7) * 8))];
            }
            __builtin_amdgcn_s_setprio(1);
            #pragma unroll
            for (int m = 0; m < 4; ++m)
                #pragma unroll
                for (int n = 0; n < 4; ++n)
                    acc[m][n] = __builtin_amdgcn_mfma_f32_16x16x32_bf16(af[m], bfv[n], acc[m][n], 0, 0, 0);
            __builtin_amdgcn_s_setprio(0);
        }
        __syncthreads();
        buf ^= 1;
    }
#undef OSTAGE
    // bf16 epilogue through swizzled Cs -> coalesced 16B stores
    unsigned short* Cs = SM;
    #pragma unroll
    for (int n = 0; n < 4; ++n) {
        int cn = wc * 64 + n * 16 + fr;
        #pragma unroll
        for (int m = 0; m < 4; ++m)
            #pragma unroll
            for (int r = 0; r < 4; ++r) {
                int row = wr * 64 + m * 16 + fg * 4 + r;
                Cs[CSW(row, cn)] = f2bf(acc[m][n][r]);
            }
    }
    __syncthreads();
    #pragma unroll
    for (int k = 0; k < 8; ++k) {
        int c = k * 256 + tid;
        int row = c >> 4, cc = c & 15;
        bf16x8 v = *(const bf16x8*)&Cs[CSW(row, cc * 8)];
        *(bf16x8*)&tmpb[(size_t)(m0 + row) * D_MODEL + n0 + cc * 8] = v;
    }
}

// ---------------- flash attention: KVBLK=128, in-register softmax ----------------
// Mask applied as K-side bias MFMA (masked raw score -= 798720 -> exp2 underflows to 0);
// row-sum (lrun) accumulated on the matrix pipe via mfma(ones, P) running across tiles.
__global__ __launch_bounds__(256, 2) void attn_kernel(const unsigned short* __restrict__ Qb,
                                                      const unsigned short* __restrict__ Kb,
                                                      const unsigned short* __restrict__ Vt,
                                                      const unsigned long long* __restrict__ mwords,
                                                      unsigned short* __restrict__ AF) {
    __shared__ unsigned short Ks[2][128 * 64];   // [kv][d]
    __shared__ unsigned short Vts[2][64 * 128];  // [d][kv]
    const int tid = threadIdx.x, lane = tid & 63, wid = tid >> 6;
    const int l31 = lane & 31, hi = lane >> 5;
    const int lin = blockIdx.x;
    const int x = lin & 7, i = lin >> 3;
    const int qt = i & 7, bh = x * 8 + (i >> 3);
    const int b = bh >> 4;
    const unsigned short* Qh = Qb + (size_t)bh * SEQ * DH;
    const unsigned short* Kh = Kb + (size_t)bh * SEQ * DH;
    const unsigned short* Vth = Vt + (size_t)bh * DH * SEQ;
    const unsigned long long* mwb = mwords + b * 16;
    const int q0 = qt * 128 + wid * 32;

    const int k_row = wid * 32 + (lane >> 3);
    const int k_col = 8 * ((lane & 7) ^ ((lane >> 3) & 7));
    const int v_rowb = wid * 16 + (lane >> 4);

    bf16x8 qf[4];
    #pragma unroll
    for (int ks = 0; ks < 4; ++ks)
        qf[ks] = *(const bf16x8*)(Qh + (size_t)(q0 + l31) * DH + ks * 16 + hi * 8);

    union U4 { unsigned u[4]; bf16x8 v; };
    U4 ones;
    ones.u[0] = 0x3F803F80u; ones.u[1] = 0x3F803F80u;
    ones.u[2] = 0x3F803F80u; ones.u[3] = 0x3F803F80u;

    f32x16 oacc0 = {}, oacc1 = {};
    f32x16 sacc = {};                // running P row-sum (all 16 regs identical)
    float mrun = -3.0e38f;
    const float C2 = 0.18033688f;    // 0.125 * log2(e)

#define KSWZ(row, colsh) ((row) * 64 + ((colsh) ^ (((row) & 7) << 3)))
#define VSWZ(row, colsh) ((row) * 128 + ((colsh) ^ (((row) & 7) << 3)))
#define STAGE(bufi, kt2)                                                                  \
    {                                                                                     \
        const int kv0s = (kt2) * 128;                                                     \
        _Pragma("unroll")                                                                 \
        for (int j = 0; j < 4; ++j)                                                       \
            gload16(Kh + (size_t)(kv0s + k_row + j * 8) * DH + k_col,                     \
                    &Ks[bufi][wid * 2048 + j * 512]);                                     \
        _Pragma("unroll")                                                                 \
        for (int j = 0; j < 4; ++j) {                                                     \
            const int vr = v_rowb + j * 4;                                                \
            gload16(Vth + (size_t)vr * SEQ + kv0s + 8 * ((lane & 15) ^ (vr & 7)),         \
                    &Vts[bufi][wid * 2048 + j * 512]);                                    \
        }                                                                                 \
    }

    STAGE(0, 0);
    __syncthreads();
    int buf = 0;
    for (int kt = 0; kt < 8; ++kt) {
        if (kt < 7) STAGE(buf ^ 1, kt + 1);
        const unsigned long long mwA = mwb[2 * kt], mwB = mwb[2 * kt + 1];
        const unsigned mr0 = (unsigned)mwA, mr1 = (unsigned)(mwA >> 32);
        const unsigned mr2 = (unsigned)mwB, mr3 = (unsigned)(mwB >> 32);
        // QK^T over 128 kv rows
        f32x16 sA0 = {}, sA1 = {}, sB0 = {}, sB1 = {};
        __builtin_amdgcn_s_setprio(1);
        #pragma unroll
        for (int ks = 0; ks < 4; ++ks) {
            const int ch = ks * 16 + hi * 8;
            bf16x8 k0 = *(const bf16x8*)&Ks[buf][KSWZ(l31, ch)];
            bf16x8 k1 = *(const bf16x8*)&Ks[buf][KSWZ(32 + l31, ch)];
            bf16x8 k2 = *(const bf16x8*)&Ks[buf][KSWZ(64 + l31, ch)];
            bf16x8 k3 = *(const bf16x8*)&Ks[buf][KSWZ(96 + l31, ch)];
            sA0 = __builtin_amdgcn_mfma_f32_32x32x16_bf16(k0, qf[ks], sA0, 0, 0, 0);
            sA1 = __builtin_amdgcn_mfma_f32_32x32x16_bf16(k1, qf[ks], sA1, 0, 0, 0);
            sB0 = __builtin_amdgcn_mfma_f32_32x32x16_bf16(k2, qf[ks], sB0, 0, 0, 0);
            sB1 = __builtin_amdgcn_mfma_f32_32x32x16_bf16(k3, qf[ks], sB1, 0, 0, 0);
        }
        // mask bias: A[kv][0] = mask ? -798720 : 0 (bf16 0xC943), B = ones -> s += bias
        {
            U4 ab; ab.u[1] = 0; ab.u[2] = 0; ab.u[3] = 0;
            unsigned bv;
            bv = ((mr0 >> l31) & 1u) ? 0xC943u : 0u; ab.u[0] = hi ? 0u : bv;
            sA0 = __builtin_amdgcn_mfma_f32_32x32x16_bf16(ab.v, ones.v, sA0, 0, 0, 0);
            bv = ((mr1 >> l31) & 1u) ? 0xC943u : 0u; ab.u[0] = hi ? 0u : bv;
            sA1 = __builtin_amdgcn_mfma_f32_32x32x16_bf16(ab.v, ones.v, sA1, 0, 0, 0);
            bv = ((mr2 >> l31) & 1u) ? 0xC943u : 0u; ab.u[0] = hi ? 0u : bv;
            sB0 = __builtin_amdgcn_mfma_f32_32x32x16_bf16(ab.v, ones.v, sB0, 0, 0, 0);
            bv = ((mr3 >> l31) & 1u) ? 0xC943u : 0u; ab.u[0] = hi ? 0u : bv;
            sB1 = __builtin_amdgcn_mfma_f32_32x32x16_bf16(ab.v, ones.v, sB1, 0, 0, 0);
        }
        __builtin_amdgcn_s_setprio(0);
        // row max (tree; compiler fuses to max3)
        float tm[16];
        #pragma unroll
        for (int r2 = 0; r2 < 16; ++r2)
            tm[r2] = fmaxf(fmaxf(sA0[r2], sA1[r2]), fmaxf(sB0[r2], sB1[r2]));
        #pragma unroll
        for (int st = 8; st; st >>= 1)
            #pragma unroll
            for (int r2 = 0; r2 < st; ++r2)
                tm[r2] = fmaxf(tm[r2], tm[r2 + st]);
        float m = tm[0];
        m = fmaxf(m, xhalf(m, hi));
        float mt = m * C2;
        if (!__all(mt <= mrun + 11.5f)) {   // defer-max (T13)
            float newm = fmaxf(mrun, mt);
            float corr = exp2f(mrun - newm);
            #pragma unroll
            for (int r2 = 0; r2 < 16; ++r2) {
                oacc0[r2] *= corr; oacc1[r2] *= corr; sacc[r2] *= corr;
            }
            mrun = newm;
        }
        // P = exp2(s*C2 - mrun); masked entries underflow to 0
        #pragma unroll
        for (int r2 = 0; r2 < 16; ++r2) {
            sA0[r2] = exp2f(fmaf(sA0[r2], C2, -mrun));
            sA1[r2] = exp2f(fmaf(sA1[r2], C2, -mrun));
            sB0[r2] = exp2f(fmaf(sB0[r2], C2, -mrun));
            sB1[r2] = exp2f(fmaf(sB1[r2], C2, -mrun));
        }
        // P -> bf16 B-operand fragments (cvt_pk + permlane32_swap)
        unsigned cA0[8], cA1[8], cB0[8], cB1[8];
        #pragma unroll
        for (int ii = 0; ii < 8; ++ii) {
            asm volatile("v_cvt_pk_bf16_f32 %0, %1, %2" : "=v"(cA0[ii]) : "v"(sA0[2 * ii]), "v"(sA0[2 * ii + 1]));
            asm volatile("v_cvt_pk_bf16_f32 %0, %1, %2" : "=v"(cA1[ii]) : "v"(sA1[2 * ii]), "v"(sA1[2 * ii + 1]));
            asm volatile("v_cvt_pk_bf16_f32 %0, %1, %2" : "=v"(cB0[ii]) : "v"(sB0[2 * ii]), "v"(sB0[2 * ii + 1]));
            asm volatile("v_cvt_pk_bf16_f32 %0, %1, %2" : "=v"(cB1[ii]) : "v"(sB1[2 * ii]), "v"(sB1[2 * ii + 1]));
        }
        #pragma unroll
        for (int g = 0; g < 8; g += 4) {
            asm volatile("v_permlane32_swap_b32 %0, %1" : "+v"(cA0[g + 0]), "+v"(cA0[g + 2]));
            asm volatile("v_permlane32_swap_b32 %0, %1" : "+v"(cA0[g + 1]), "+v"(cA0[g + 3]));
            asm volatile("v_permlane32_swap_b32 %0, %1" : "+v"(cA1[g + 0]), "+v"(cA1[g + 2]));
            asm volatile("v_permlane32_swap_b32 %0, %1" : "+v"(cA1[g + 1]), "+v"(cA1[g + 3]));
            asm volatile("v_permlane32_swap_b32 %0, %1" : "+v"(cB0[g + 0]), "+v"(cB0[g + 2]));
            asm volatile("v_permlane32_swap_b32 %0, %1" : "+v"(cB0[g + 1]), "+v"(cB0[g + 3]));
            asm volatile("v_permlane32_swap_b32 %0, %1" : "+v"(cB1[g + 0]), "+v"(cB1[g + 2]));
            asm volatile("v_permlane32_swap_b32 %0, %1" : "+v"(cB1[g + 1]), "+v"(cB1[g + 3]));
        }
        // PV + ones-sum: 8 k-steps of 16 kv
        __builtin_amdgcn_s_setprio(1);
        #pragma unroll
        for (int t = 0; t < 8; ++t) {
            const unsigned* cp = (t < 2) ? cA0 : (t < 4) ? cA1 : (t < 6) ? cB0 : cB1;
            const int g = (t & 1) * 4;
            U4 pb;
            pb.u[0] = cp[g + 0]; pb.u[1] = cp[g + 1]; pb.u[2] = cp[g + 2]; pb.u[3] = cp[g + 3];
            const int ch = t * 16 + hi * 8;
            bf16x8 vf0 = *(const bf16x8*)&Vts[buf][VSWZ(l31, ch)];
            bf16x8 vf1 = *(const bf16x8*)&Vts[buf][VSWZ(32 + l31, ch)];
            oacc0 = __builtin_amdgcn_mfma_f32_32x32x16_bf16(vf0, pb.v, oacc0, 0, 0, 0);
            oacc1 = __builtin_amdgcn_mfma_f32_32x32x16_bf16(vf1, pb.v, oacc1, 0, 0, 0);
            sacc  = __builtin_amdgcn_mfma_f32_32x32x16_bf16(ones.v, pb.v, sacc, 0, 0, 0);
        }
        __builtin_amdgcn_s_setprio(0);
        __syncthreads();
        buf ^= 1;
    }
#undef STAGE
#undef KSWZ
#undef VSWZ
    const float rl = 1.f / sacc[0];
    const int b2 = bh & 3, h2 = bh >> 2;   // faithful-to-torch head scramble
    const size_t rowbase = ((size_t)b2 * SEQ + q0 + l31) * D_MODEL + h2 * 64 + 4 * hi;
    #pragma unroll
    for (int df = 0; df < 2; ++df) {
        const f32x16& oa = df ? oacc1 : oacc0;
        #pragma unroll
        for (int rg = 0; rg < 4; ++rg) {
            ushort4 pk;
            pk.x = f2bf(oa[rg * 4 + 0] * rl);
            pk.y = f2bf(oa[rg * 4 + 1] * rl);
            pk.z = f2bf(oa[rg * 4 + 2] * rl);
            pk.w = f2bf(oa[rg * 4 + 3] * rl);
            *(ushort4*)&AF[rowbase + 32 * df + 8 * rg] = pk;
        }
    }
}

// ---------------- residual + LayerNorm (bf16 attn_out + f32 residual) ----------------
__global__ __launch_bounds__(256) void ln_kernel(const unsigned short* __restrict__ tmpb,
                                                 const float* __restrict__ inp,
                                                 const float* __restrict__ g,
                                                 const float* __restrict__ bb,
                                                 float* __restrict__ out) {
    __shared__ float red[8];
    const int row = blockIdx.x, tid = threadIdx.x;
    ushort4 t4 = ((const ushort4*)(tmpb + (size_t)row * D_MODEL))[tid];
    float4 rr = ((const float4*)(inp + (size_t)row * D_MODEL))[tid];
    float4 y;
    y.x = bf2f(t4.x) + rr.x; y.y = bf2f(t4.y) + rr.y;
    y.z = bf2f(t4.z) + rr.z; y.w = bf2f(t4.w) + rr.w;
    float sum = y.x + y.y + y.z + y.w;
    float sq = y.x * y.x + y.y * y.y + y.z * y.z + y.w * y.w;
    #pragma unroll
    for (int o = 1; o < 64; o <<= 1) { sum += __shfl_xor(sum, o); sq += __shfl_xor(sq, o); }
    int wid = tid >> 6, lane = tid & 63;
    if (lane == 0) { red[wid] = sum; red[4 + wid] = sq; }
    __syncthreads();
    sum = red[0] + red[1] + red[2] + red[3];
    sq = red[4] + red[5] + red[6] + red[7];
    float mu = sum * (1.f / D_MODEL);
    float var = sq * (1.f / D_MODEL) - mu * mu;
    float rs = rsqrtf(var + 1e-5f);
    float4 gg = ((const float4*)g)[tid];
    float4 bv = ((const float4*)bb)[tid];
    float4 o4;
    o4.x = (y.x - mu) * rs * gg.x + bv.x;
    o4.y = (y.y - mu) * rs * gg.y + bv.y;
    o4.z = (y.z - mu) * rs * gg.z + bv.z;
    o4.w = (y.w - mu) * rs * gg.w + bv.w;
    ((float4*)(out + (size_t)row * D_MODEL))[tid] = o4;
}

extern "C" void kernel_launch(void* const* d_in, const int* in_sizes, int n_in,
                              void* d_out, int out_size, void* d_ws, size_t ws_size,
                              hipStream_t stream) {
    const float* inp = (const float*)d_in[0];
    const int* amask = (const int*)d_in[1];
    const float* Wq = (const float*)d_in[2];
    const float* bq = (const float*)d_in[3];
    const float* Wk = (const float*)d_in[4];
    const float* bk = (const float*)d_in[5];
    const float* Wv = (const float*)d_in[6];
    const float* bv = (const float*)d_in[7];
    const float* Wo = (const float*)d_in[8];
    const float* lg = (const float*)d_in[9];
    const float* lb = (const float*)d_in[10];
    float* out = (float*)d_out;
    char* ws = (char*)d_ws;

    unsigned short* Xb     = (unsigned short*)(ws + 0);          //  8.0 MiB
    unsigned short* Wqkv_t = (unsigned short*)(ws + 8388608);    //  6.0 MiB
    unsigned short* Wo_t   = (unsigned short*)(ws + 14680064);   //  2.0 MiB
    unsigned short* Qb     = (unsigned short*)(ws + 16777216);   //  8.0 MiB
    unsigned short* Kb     = (unsigned short*)(ws + 25165824);   //  8.0 MiB
    unsigned short* Vt     = (unsigned short*)(ws + 33554432);   //  8.0 MiB  (V^T: [bh][d][s])
    unsigned short* AF     = (unsigned short*)(ws + 41943040);   //  8.0 MiB
    unsigned short* tmpb   = (unsigned short*)(ws + 50331648);   //  8.0 MiB  (bf16 attn_out @ Wo)
    unsigned long long* mwords = (unsigned long long*)(ws + 58720256);  // 512 B

    prep<<<8208, 256, 0, stream>>>(inp, Xb, amask, mwords, Wq, Wk, Wv, Wo, Wqkv_t, Wo_t);
    gemm_qkv<<<768, 256, 0, stream>>>(Xb, Wqkv_t, bq, bk, bv, Qb, Kb, Vt);
    attn_kernel<<<512, 256, 0, stream>>>(Qb, Kb, Vt, mwords, AF);
    gemm_o<<<256, 256, 0, stream>>>(AF, Wo_t, tmpb);
    ln_kernel<<<4096, 256, 0, stream>>>(tmpb, inp, lg, lb, out);
}